// Round 1
// 1737.177 us; speedup vs baseline: 1.0834x; 1.0834x over previous
//
#include <hip/hip_runtime.h>
#include <hip/hip_bf16.h>
#include <math.h>

#define N_SIMP 400000
#define E_NNZ  2400000
#define FIN    32
#define HDIM   64
#define KAPPA  3
#define G_NUM  512
#define NOUT   8
#define BN_EPS 1e-5

typedef __hip_bfloat16 bf16;
typedef _Float16 f16;
typedef short s8v __attribute__((ext_vector_type(8)));    // 8 bf16 in 4 VGPRs
typedef ushort u8v __attribute__((ext_vector_type(8)));   // 8 bf16 raw
typedef float f4v __attribute__((ext_vector_type(4)));

__device__ __forceinline__ float elu_f(float x) {
    return x > 0.f ? x : expm1f(x);
}
__device__ __forceinline__ float bf2f(ushort u) {
    return __uint_as_float(((unsigned int)u) << 16);
}
__device__ __forceinline__ ushort f2bf(float f) {
    bf16 h = (bf16)f;
    return *(ushort*)&h;
}

// ---------------- CSR build ----------------

// histogram + per-edge rank capture (rank = old count). Removes the
// atomic-with-return from the scatter's critical path.
__global__ void hist2_kernel(const int* __restrict__ eiL, const int* __restrict__ eiU,
                             int* __restrict__ rpL, int* __restrict__ rpU,
                             int* __restrict__ rankL, int* __restrict__ rankU) {
    int idx = blockIdx.x * 256 + threadIdx.x;
    if (idx < E_NNZ) {
        rankL[idx] = atomicAdd(&rpL[eiL[idx]], 1);
    } else {
        int e = idx - E_NNZ;
        if (e < E_NNZ) rankU[e] = atomicAdd(&rpU[eiU[e]], 1);
    }
}

__global__ void scan_block_kernel(int* __restrict__ data, int* __restrict__ bsum, int n) {
    __shared__ int sdata[256];
    int t = threadIdx.x;
    int base = blockIdx.x * 1024 + t * 4;
    int v0 = (base + 0 < n) ? data[base + 0] : 0;
    int v1 = (base + 1 < n) ? data[base + 1] : 0;
    int v2 = (base + 2 < n) ? data[base + 2] : 0;
    int v3 = (base + 3 < n) ? data[base + 3] : 0;
    int tsum = v0 + v1 + v2 + v3;
    sdata[t] = tsum;
    __syncthreads();
    for (int off = 1; off < 256; off <<= 1) {
        int val = (t >= off) ? sdata[t - off] : 0;
        __syncthreads();
        sdata[t] += val;
        __syncthreads();
    }
    if (t == 255) bsum[blockIdx.x] = sdata[255];
    int run = sdata[t] - tsum;
    if (base + 0 < n) { data[base + 0] = run; } run += v0;
    if (base + 1 < n) { data[base + 1] = run; } run += v1;
    if (base + 2 < n) { data[base + 2] = run; } run += v2;
    if (base + 3 < n) { data[base + 3] = run; }
}

// parallel exclusive scan of block sums (nb <= 512), one block of 512 threads
__global__ void scan_top_kernel(int* __restrict__ bsum, int nb) {
    __shared__ int sd[512];
    int t = threadIdx.x;
    int v = (t < nb) ? bsum[t] : 0;
    sd[t] = v;
    __syncthreads();
    for (int off = 1; off < 512; off <<= 1) {
        int x = (t >= off) ? sd[t - off] : 0;
        __syncthreads();
        sd[t] += x;
        __syncthreads();
    }
    if (t < nb) bsum[t] = sd[t] - v;   // exclusive
}

__global__ void add_off_kernel(int* __restrict__ rp, const int* __restrict__ bsum) {
    int i = blockIdx.x * 256 + threadIdx.x;
    if (i >= N_SIMP) return;
    rp[i] += bsum[i >> 10];
}

// atomic-free scatter: pos = rp[row] (exclusive start, read-only cached) + rank
__global__ void scatter2_kernel(const int* __restrict__ eiL, const float* __restrict__ valL,
                                const int* __restrict__ eiU, const float* __restrict__ valU,
                                const int* __restrict__ rpL, const int* __restrict__ rpU,
                                const int* __restrict__ rankL, const int* __restrict__ rankU,
                                int2* __restrict__ edgeL, int2* __restrict__ edgeU) {
    int idx = blockIdx.x * 256 + threadIdx.x;
    if (idx < E_NNZ) {
        int r = eiL[idx];
        int pos = rpL[r] + rankL[idx];
        edgeL[pos] = make_int2(eiL[E_NNZ + idx], __float_as_int(valL[idx]));
    } else {
        int e = idx - E_NNZ;
        if (e < E_NNZ) {
            int r = eiU[e];
            int pos = rpU[r] + rankU[e];
            edgeU[pos] = make_int2(eiU[E_NNZ + e], __float_as_int(valU[e]));
        }
    }
}

// ---------------- small prep kernels ----------------

__global__ void combine_bias_kernel(const float* __restrict__ bh,
                                    const float* __restrict__ bl,
                                    const float* __restrict__ bu,
                                    float* __restrict__ out) {
    int h = threadIdx.x;
    float acc = bh[h];
    for (int k = 0; k < KAPPA; ++k) acc += bl[k * HDIM + h] + bu[k * HDIM + h];
    out[h] = acc;
}

__global__ void f32_to_bf16_kernel(const float* __restrict__ in, bf16* __restrict__ out) {
    int idx = blockIdx.x * 256 + threadIdx.x;
    out[idx] = (bf16)in[idx];
}

// all 6 weight transposes in one dispatch; wt layout fixed (offsets in ushorts)
__global__ void wtrans_all_kernel(const float* __restrict__ s0, const float* __restrict__ s1,
                                  const float* __restrict__ s2, const float* __restrict__ s3,
                                  const float* __restrict__ s4, const float* __restrict__ s5,
                                  ushort* __restrict__ wt) {
    int idx = blockIdx.x * 256 + threadIdx.x;   // 0..43007
    const float* src; int Ktot, off;
    if (idx < 2048)       { src = s0; Ktot = 32;  off = 0; }
    else if (idx < 6144)  { src = s1; Ktot = 64;  off = 2048; }
    else if (idx < 12288) { src = s2; Ktot = 96;  off = 6144; }
    else if (idx < 18432) { src = s3; Ktot = 96;  off = 12288; }
    else if (idx < 30720) { src = s4; Ktot = 192; off = 18432; }
    else                  { src = s5; Ktot = 192; off = 30720; }
    int rel = idx - off;
    int n = rel / Ktot, kk = rel - n * Ktot;
    wt[idx] = f2bf(src[kk * 64 + n]);
}

// ---------------- SpMM (CSR gather; max per-wave concurrency, 16B lanes) --------
// rp holds EXCLUSIVE row starts: s = rp[row], e = rp[row+1] (guarded at N-1)

// 32-wide: 4 lanes/row (8 ch each), 16 rows/wave, 64 rows/block
__global__ void spmm32_kernel(const int* __restrict__ rp, const int2* __restrict__ edge,
                              const bf16* __restrict__ srcb, int src_stride,
                              bf16* __restrict__ dstb) {
    const ushort* src = (const ushort*)srcb;
    ushort* dst = (ushort*)dstb;
    int tid = threadIdx.x;
    int lane = tid & 63;
    int wv = tid >> 6;
    int grp = lane >> 2;      // 0..15: row within wave
    int li = lane & 3;        // channels li*8 .. li*8+7
    int row = blockIdx.x * 64 + wv * 16 + grp;
    int s = rp[row];
    int e = (row == N_SIMP - 1) ? E_NNZ : rp[row + 1];
    int deg = e - s;
    float a[8] = {0.f, 0.f, 0.f, 0.f, 0.f, 0.f, 0.f, 0.f};
    if (deg > 0) {
        int2 ed[8];
#pragma unroll
        for (int t = 0; t < 8; ++t) {
            int j = s + t;
            ed[t] = edge[(j < e) ? j : (e - 1)];
        }
        u8v xs[8];
#pragma unroll
        for (int t = 0; t < 8; ++t)
            xs[t] = *(const u8v*)(src + (size_t)ed[t].x * src_stride + li * 8);
#pragma unroll
        for (int t = 0; t < 8; ++t) {
            float v = (t < deg) ? __int_as_float(ed[t].y) : 0.f;
#pragma unroll
            for (int c = 0; c < 8; ++c) a[c] += v * bf2f(xs[t][c]);
        }
        for (int j = s + 8; j < e; j += 4) {
            int2 e2[4];
#pragma unroll
            for (int t = 0; t < 4; ++t) {
                int jj = j + t;
                e2[t] = edge[(jj < e) ? jj : (e - 1)];
            }
            u8v x2[4];
#pragma unroll
            for (int t = 0; t < 4; ++t)
                x2[t] = *(const u8v*)(src + (size_t)e2[t].x * src_stride + li * 8);
#pragma unroll
            for (int t = 0; t < 4; ++t) {
                float v = (j + t < e) ? __int_as_float(e2[t].y) : 0.f;
#pragma unroll
                for (int c = 0; c < 8; ++c) a[c] += v * bf2f(x2[t][c]);
            }
        }
    }
    u8v w;
#pragma unroll
    for (int c = 0; c < 8; ++c) w[c] = f2bf(a[c]);
    *(u8v*)(dst + (size_t)row * 32 + li * 8) = w;
}

// 64-wide: 8 lanes/row (8 ch each), 8 rows/wave, 32 rows/block; stride 64
__global__ void spmm64_kernel(const int* __restrict__ rp, const int2* __restrict__ edge,
                              const bf16* __restrict__ srcb, bf16* __restrict__ dstb) {
    const ushort* src = (const ushort*)srcb;
    ushort* dst = (ushort*)dstb;
    int tid = threadIdx.x;
    int lane = tid & 63;
    int wv = tid >> 6;
    int grp = lane >> 3;      // 0..7: row within wave
    int li = lane & 7;        // channels li*8 .. li*8+7
    int row = blockIdx.x * 32 + wv * 8 + grp;
    int s = rp[row];
    int e = (row == N_SIMP - 1) ? E_NNZ : rp[row + 1];
    int deg = e - s;
    float a[8] = {0.f, 0.f, 0.f, 0.f, 0.f, 0.f, 0.f, 0.f};
    if (deg > 0) {
        int2 ed[8];
#pragma unroll
        for (int t = 0; t < 8; ++t) {
            int j = s + t;
            ed[t] = edge[(j < e) ? j : (e - 1)];
        }
        u8v xs[8];
#pragma unroll
        for (int t = 0; t < 8; ++t)
            xs[t] = *(const u8v*)(src + (size_t)ed[t].x * 64 + li * 8);
#pragma unroll
        for (int t = 0; t < 8; ++t) {
            float v = (t < deg) ? __int_as_float(ed[t].y) : 0.f;
#pragma unroll
            for (int c = 0; c < 8; ++c) a[c] += v * bf2f(xs[t][c]);
        }
        for (int j = s + 8; j < e; j += 4) {
            int2 e2[4];
#pragma unroll
            for (int t = 0; t < 4; ++t) {
                int jj = j + t;
                e2[t] = edge[(jj < e) ? jj : (e - 1)];
            }
            u8v x2[4];
#pragma unroll
            for (int t = 0; t < 4; ++t)
                x2[t] = *(const u8v*)(src + (size_t)e2[t].x * 64 + li * 8);
#pragma unroll
            for (int t = 0; t < 4; ++t) {
                float v = (j + t < e) ? __int_as_float(e2[t].y) : 0.f;
#pragma unroll
                for (int c = 0; c < 8; ++c) a[c] += v * bf2f(x2[t][c]);
            }
        }
    }
    u8v w;
#pragma unroll
    for (int c = 0; c < 8; ++c) w[c] = f2bf(a[c]);
    *(u8v*)(dst + (size_t)row * 64 + li * 8) = w;
}

// ---------------- MFMA GEMM: z[N,64] (fp16) (=bias+ / +=) A[N, NCH*32] @ W -------

template <int NCH, bool INIT>
__global__ __launch_bounds__(256) void mfma_gemm_kernel(
        const ushort* __restrict__ s0, int st0,
        const ushort* __restrict__ s1, int st1,
        const ushort* __restrict__ s2, int st2,
        const ushort* __restrict__ s3, int st3,
        const ushort* __restrict__ Wt, int Kstride,
        const float* __restrict__ bias,
        f16* __restrict__ z) {
    int tid = threadIdx.x;
    int wv = tid >> 6, lane = tid & 63;
    int quad = lane >> 4, n = lane & 15;
    int rowbase = blockIdx.x * 64 + wv * 16;
    int arow = rowbase + n;  // A-operand row m = lane&15

    f4v acc0 = {0.f, 0.f, 0.f, 0.f};
    f4v acc1 = {0.f, 0.f, 0.f, 0.f};
    f4v acc2 = {0.f, 0.f, 0.f, 0.f};
    f4v acc3 = {0.f, 0.f, 0.f, 0.f};

#pragma unroll
    for (int ch = 0; ch < NCH; ++ch) {
        const ushort* sp = (ch == 0) ? s0 : (ch == 1) ? s1 : (ch == 2) ? s2 : s3;
        int st = (ch == 0) ? st0 : (ch == 1) ? st1 : (ch == 2) ? st2 : st3;
        s8v a = *(const s8v*)(sp + (size_t)arow * st + quad * 8);
        const ushort* wb = Wt + ch * 32 + quad * 8;
        s8v b0 = *(const s8v*)(wb + (size_t)(0 * 16 + n) * Kstride);
        s8v b1 = *(const s8v*)(wb + (size_t)(1 * 16 + n) * Kstride);
        s8v b2 = *(const s8v*)(wb + (size_t)(2 * 16 + n) * Kstride);
        s8v b3 = *(const s8v*)(wb + (size_t)(3 * 16 + n) * Kstride);
        acc0 = __builtin_amdgcn_mfma_f32_16x16x32_bf16(a, b0, acc0, 0, 0, 0);
        acc1 = __builtin_amdgcn_mfma_f32_16x16x32_bf16(a, b1, acc1, 0, 0, 0);
        acc2 = __builtin_amdgcn_mfma_f32_16x16x32_bf16(a, b2, acc2, 0, 0, 0);
        acc3 = __builtin_amdgcn_mfma_f32_16x16x32_bf16(a, b3, acc3, 0, 0, 0);
    }
    // C/D layout: col = lane&15, row = quad*4 + reg
#pragma unroll
    for (int r = 0; r < 4; ++r) {
        int orow = rowbase + quad * 4 + r;
        f16* zp = z + (size_t)orow * 64 + n;
        if (INIT) {
            zp[0]  = (f16)(bias[n]      + acc0[r]);
            zp[16] = (f16)(bias[16 + n] + acc1[r]);
            zp[32] = (f16)(bias[32 + n] + acc2[r]);
            zp[48] = (f16)(bias[48 + n] + acc3[r]);
        } else {
            zp[0]  = (f16)((float)zp[0]  + acc0[r]);
            zp[16] = (f16)((float)zp[16] + acc1[r]);
            zp[32] = (f16)((float)zp[32] + acc2[r]);
            zp[48] = (f16)((float)zp[48] + acc3[r]);
        }
    }
}

// ---------------- BN / pool / MLP ----------------

__global__ void bn_stats_kernel(const f16* __restrict__ z, double* __restrict__ stats) {
    __shared__ double s1[256], s2[256];
    int tid = threadIdx.x;
    const long long total = (long long)N_SIMP * HDIM;
    double sum = 0.0, sq = 0.0;
    for (long long idx = (long long)blockIdx.x * 256 + tid; idx < total;
         idx += (long long)gridDim.x * 256) {
        float v = (float)z[idx];
        sum += v;
        sq += (double)v * v;
    }
    s1[tid] = sum; s2[tid] = sq;
    __syncthreads();
    if (tid < 64) {
        double a = s1[tid] + s1[tid + 64] + s1[tid + 128] + s1[tid + 192];
        double b = s2[tid] + s2[tid + 64] + s2[tid + 128] + s2[tid + 192];
        atomicAdd(&stats[tid], a);
        atomicAdd(&stats[64 + tid], b);
    }
}

// layer-0: h0bf = bf16(elu(bn(z)))
__global__ void bn_elu_bf16_kernel(const f16* __restrict__ z, const double* __restrict__ stats,
                                   const float* __restrict__ gamma, const float* __restrict__ beta,
                                   bf16* __restrict__ out) {
    __shared__ float scale_s[64], shift_s[64];
    int tid = threadIdx.x;
    if (tid < 64) {
        double mean = stats[tid] / (double)N_SIMP;
        double var = stats[64 + tid] / (double)N_SIMP - mean * mean;
        double sc = (double)gamma[tid] / sqrt(var + BN_EPS);
        scale_s[tid] = (float)sc;
        shift_s[tid] = (float)((double)beta[tid] - mean * sc);
    }
    __syncthreads();
    const long long total = (long long)N_SIMP * HDIM;
    for (long long idx = (long long)blockIdx.x * 256 + tid; idx < total;
         idx += (long long)gridDim.x * 256) {
        int h = (int)(idx & 63);
        out[idx] = (bf16)elu_f((float)z[idx] * scale_s[h] + shift_s[h]);
    }
}

// layer-1: z = elu(bn(z)) in place (fp16)
__global__ void bn_elu_f16_kernel(f16* __restrict__ z, const double* __restrict__ stats,
                                  const float* __restrict__ gamma, const float* __restrict__ beta) {
    __shared__ float scale_s[64], shift_s[64];
    int tid = threadIdx.x;
    if (tid < 64) {
        double mean = stats[tid] / (double)N_SIMP;
        double var = stats[64 + tid] / (double)N_SIMP - mean * mean;
        double sc = (double)gamma[tid] / sqrt(var + BN_EPS);
        scale_s[tid] = (float)sc;
        shift_s[tid] = (float)((double)beta[tid] - mean * sc);
    }
    __syncthreads();
    const long long total = (long long)N_SIMP * HDIM;
    for (long long idx = (long long)blockIdx.x * 256 + tid; idx < total;
         idx += (long long)gridDim.x * 256) {
        int h = (int)(idx & 63);
        z[idx] = (f16)elu_f((float)z[idx] * scale_s[h] + shift_s[h]);
    }
}

__global__ void pool_kernel(const f16* __restrict__ hbuf, const int* __restrict__ bidx,
                            float* __restrict__ gbuf) {
    __shared__ float smax[256], ssum[256];
    int g = blockIdx.x;
    int tid = threadIdx.x;
    int lo = 0, hi = N_SIMP;
    while (lo < hi) { int mid = (lo + hi) >> 1; if (bidx[mid] < g) lo = mid + 1; else hi = mid; }
    int start = lo;
    hi = N_SIMP;
    while (lo < hi) { int mid = (lo + hi) >> 1; if (bidx[mid] < g + 1) lo = mid + 1; else hi = mid; }
    int end = lo;
    int h = tid & 63, rep = tid >> 6;
    float mx = -INFINITY, sm = 0.f;
    for (int i = start + rep; i < end; i += 4) {
        float v = (float)hbuf[(size_t)i * HDIM + h];
        mx = fmaxf(mx, v);
        sm += v;
    }
    smax[tid] = mx; ssum[tid] = sm;
    __syncthreads();
    if (tid < 64) {
        float m = fmaxf(fmaxf(smax[tid], smax[tid + 64]), fmaxf(smax[tid + 128], smax[tid + 192]));
        float s = ssum[tid] + ssum[tid + 64] + ssum[tid + 128] + ssum[tid + 192];
        int cnt = end - start;
        float mean = s / fmaxf((float)cnt, 1.f);
        gbuf[g * 128 + tid] = elu_f(m);
        gbuf[g * 128 + 64 + tid] = elu_f(mean);
    }
}

__global__ void mlp_kernel(const float* __restrict__ gbuf, const float* __restrict__ W1,
                           const float* __restrict__ b1, const float* __restrict__ W2,
                           const float* __restrict__ b2, float* __restrict__ out) {
    __shared__ float gs[128];
    __shared__ float hs[64];
    int g = blockIdx.x, tid = threadIdx.x;
    gs[tid] = gbuf[g * 128 + tid];
    gs[64 + tid] = gbuf[g * 128 + 64 + tid];
    __syncthreads();
    float acc = b1[tid];
#pragma unroll
    for (int k = 0; k < 128; ++k) acc += gs[k] * W1[k * 64 + tid];
    hs[tid] = fmaxf(acc, 0.f);
    __syncthreads();
    if (tid < 8) {
        float o = b2[tid];
#pragma unroll
        for (int k = 0; k < 64; ++k) o += hs[k] * W2[k * 8 + tid];
        out[g * 8 + tid] = o;
    }
}

// ---------------- host side ----------------

extern "C" void kernel_launch(void* const* d_in, const int* in_sizes, int n_in,
                              void* d_out, int out_size, void* d_ws, size_t ws_size,
                              hipStream_t stream) {
    const float* x     = (const float*)d_in[0];
    const int*   li    = (const int*)d_in[1];
    const float* lv    = (const float*)d_in[2];
    const int*   ui    = (const int*)d_in[3];
    const float* uv    = (const float*)d_in[4];
    const int*   bidx  = (const int*)d_in[5];
    const float* l0_Wl = (const float*)d_in[6];
    const float* l0_bl = (const float*)d_in[7];
    const float* l0_Wu = (const float*)d_in[8];
    const float* l0_bu = (const float*)d_in[9];
    const float* l0_Wh = (const float*)d_in[10];
    const float* l0_bh = (const float*)d_in[11];
    const float* l1_Wl = (const float*)d_in[12];
    const float* l1_bl = (const float*)d_in[13];
    const float* l1_Wu = (const float*)d_in[14];
    const float* l1_bu = (const float*)d_in[15];
    const float* l1_Wh = (const float*)d_in[16];
    const float* l1_bh = (const float*)d_in[17];
    const float* bn0_g = (const float*)d_in[18];
    const float* bn0_b = (const float*)d_in[19];
    const float* bn1_g = (const float*)d_in[20];
    const float* bn1_b = (const float*)d_in[21];
    const float* mW1   = (const float*)d_in[22];
    const float* mb1   = (const float*)d_in[23];
    const float* mW2   = (const float*)d_in[24];
    const float* mb2   = (const float*)d_in[25];
    float* out = (float*)d_out;

    // ---- workspace layout (total ~246.8 MB <= 256 MiB) ----
    char* base = (char*)d_ws;
    f16*   z     = (f16*)base;                                    //  51,200,000
    bf16*  h0bf  = (bf16*)(base + 51200000ull);                   //  51,200,000
    bf16*  g1    = (bf16*)(base + 102400000ull);                  //  51,200,000
    bf16*  g2    = (bf16*)(base + 153600000ull);                  //  51,200,000
    int2*  edgeL = (int2*)(base + 204800000ull);                  //  19,200,000
    int2*  edgeU = (int2*)(base + 224000000ull);                  //  19,200,000
    int*   rpL   = (int*)(base + 243200000ull);                   //   1,600,032
    int*   rpU   = (int*)(base + 244800032ull);                   //   1,600,032
    int*   bsum  = (int*)(base + 246400064ull);                   //   4 KB
    double* stats = (double*)(base + 246404160ull);               //   1 KB
    float* cbias  = (float*)(base + 246405184ull);                //   256 B
    float* gbuf   = (float*)(base + 246405440ull);                //   262,144
    ushort* wt    = (ushort*)(base + 246667584ull);               //   86,016

    // rank scratch lives inside z: z is dead until the first GEMM (after CSR build)
    int* rankL = (int*)base;                    //  9,600,000 (within z region)
    int* rankU = rankL + E_NNZ;                 //  9,600,000 (within z region)

    // layer-0 scratch: 4 slots of N*32 bf16 inside g1/g2
    bf16* xbf = g1;
    bf16* cA  = g1 + (size_t)N_SIMP * 32;
    bf16* cB  = g2;
    bf16* cC  = g2 + (size_t)N_SIMP * 32;

    // weight-transpose sub-buffers (ushort elements; offsets match wtrans_all_kernel)
    ushort* wt_l0h = wt;            // 64 x 32
    ushort* wt_l1h = wt + 2048;     // 64 x 64
    ushort* wt_l0l = wt + 6144;     // 64 x 96
    ushort* wt_l0u = wt + 12288;    // 64 x 96
    ushort* wt_l1l = wt + 18432;    // 64 x 192
    ushort* wt_l1u = wt + 30720;    // 64 x 192

    const int SP32_BLOCKS = N_SIMP / 64;   // 6,250
    const int SP64_BLOCKS = N_SIMP / 32;   // 12,500
    const int MF_BLOCKS   = N_SIMP / 64;   // 6,250
    const int EB = (E_NNZ + 255) / 256;
    const int NB1024 = (N_SIMP + 1023) / 1024;
    const int NB256 = (N_SIMP + 255) / 256;

    // ---- prep: weight transposes (one dispatch) + x->bf16 ----
    wtrans_all_kernel<<<168, 256, 0, stream>>>(l0_Wh, l1_Wh, l0_Wl, l0_Wu, l1_Wl, l1_Wu, wt);
    f32_to_bf16_kernel<<<N_SIMP * 32 / 256, 256, 0, stream>>>(x, xbf);

    // ---- CSR builds (both Laplacians; rank-based, atomic-free scatter) ----
    (void)hipMemsetAsync(rpL, 0, 3200064ull, stream);
    hist2_kernel<<<2 * EB, 256, 0, stream>>>(li, ui, rpL, rpU, rankL, rankU);
    scan_block_kernel<<<NB1024, 256, 0, stream>>>(rpL, bsum, N_SIMP);
    scan_top_kernel<<<1, 512, 0, stream>>>(bsum, NB1024);
    add_off_kernel<<<NB256, 256, 0, stream>>>(rpL, bsum);
    scan_block_kernel<<<NB1024, 256, 0, stream>>>(rpU, bsum, N_SIMP);
    scan_top_kernel<<<1, 512, 0, stream>>>(bsum, NB1024);
    add_off_kernel<<<NB256, 256, 0, stream>>>(rpU, bsum);
    scatter2_kernel<<<2 * EB, 256, 0, stream>>>(li, lv, ui, uv, rpL, rpU,
                                                rankL, rankU, edgeL, edgeU);

    const ushort* xbfu = (const ushort*)xbf;
    const ushort* h0u  = (const ushort*)h0bf;
    const ushort* g1u  = (const ushort*)g1;
    const ushort* g2u  = (const ushort*)g2;

    // ---------------- layer 0 (F_IN=32 -> H=64), 32-wide chains ----------------
    combine_bias_kernel<<<1, 64, 0, stream>>>(l0_bh, l0_bl, l0_bu, cbias);
    mfma_gemm_kernel<1, true><<<MF_BLOCKS, 256, 0, stream>>>(
        xbfu, 32, nullptr, 0, nullptr, 0, nullptr, 0, wt_l0h, 32, cbias, z);

    // lower chain
    spmm32_kernel<<<SP32_BLOCKS, 256, 0, stream>>>(rpL, edgeL, xbf, 32, cA);
    spmm32_kernel<<<SP32_BLOCKS, 256, 0, stream>>>(rpL, edgeL, cA, 32, cB);
    spmm32_kernel<<<SP32_BLOCKS, 256, 0, stream>>>(rpL, edgeL, cB, 32, cC);
    mfma_gemm_kernel<3, false><<<MF_BLOCKS, 256, 0, stream>>>(
        (const ushort*)cA, 32, (const ushort*)cB, 32, (const ushort*)cC, 32,
        nullptr, 0, wt_l0l, 96, nullptr, z);
    // upper chain
    spmm32_kernel<<<SP32_BLOCKS, 256, 0, stream>>>(rpU, edgeU, xbf, 32, cA);
    spmm32_kernel<<<SP32_BLOCKS, 256, 0, stream>>>(rpU, edgeU, cA, 32, cB);
    spmm32_kernel<<<SP32_BLOCKS, 256, 0, stream>>>(rpU, edgeU, cB, 32, cC);
    mfma_gemm_kernel<3, false><<<MF_BLOCKS, 256, 0, stream>>>(
        (const ushort*)cA, 32, (const ushort*)cB, 32, (const ushort*)cC, 32,
        nullptr, 0, wt_l0u, 96, nullptr, z);

    (void)hipMemsetAsync(stats, 0, 128 * sizeof(double), stream);
    bn_stats_kernel<<<1024, 256, 0, stream>>>(z, stats);
    bn_elu_bf16_kernel<<<2048, 256, 0, stream>>>(z, stats, bn0_g, bn0_b, h0bf);

    // ---------------- layer 1 (H=64 -> H=64), 64-wide chains ----------------
    combine_bias_kernel<<<1, 64, 0, stream>>>(l1_bh, l1_bl, l1_bu, cbias);
    mfma_gemm_kernel<2, true><<<MF_BLOCKS, 256, 0, stream>>>(
        h0u, 64, h0u + 32, 64, nullptr, 0, nullptr, 0, wt_l1h, 64, cbias, z);

    {
        const int*  rps[2]   = {rpL, rpU};
        const int2* edges[2] = {edgeL, edgeU};
        ushort*     wts[2]   = {wt_l1l, wt_l1u};
        for (int lap = 0; lap < 2; ++lap) {
            spmm64_kernel<<<SP64_BLOCKS, 256, 0, stream>>>(rps[lap], edges[lap], h0bf, g1);
            spmm64_kernel<<<SP64_BLOCKS, 256, 0, stream>>>(rps[lap], edges[lap], g1, g2);
            mfma_gemm_kernel<4, false><<<MF_BLOCKS, 256, 0, stream>>>(
                g1u, 64, g1u + 32, 64, g2u, 64, g2u + 32, 64, wts[lap], 192, nullptr, z);
            spmm64_kernel<<<SP64_BLOCKS, 256, 0, stream>>>(rps[lap], edges[lap], g2, g1);
            mfma_gemm_kernel<2, false><<<MF_BLOCKS, 256, 0, stream>>>(
                g1u, 64, g1u + 32, 64, nullptr, 0, nullptr, 0, wts[lap] + 128, 192, nullptr, z);
        }
    }

    (void)hipMemsetAsync(stats, 0, 128 * sizeof(double), stream);
    bn_stats_kernel<<<1024, 256, 0, stream>>>(z, stats);
    bn_elu_f16_kernel<<<2048, 256, 0, stream>>>(z, stats, bn1_g, bn1_b);

    // ---------------- pool + MLP ----------------
    pool_kernel<<<G_NUM, 256, 0, stream>>>(z, bidx, gbuf);
    mlp_kernel<<<G_NUM, 64, 0, stream>>>(gbuf, mW1, mb1, mW2, mb2, out);
}

// Round 2
// 1606.595 us; speedup vs baseline: 1.1714x; 1.0813x over previous
//
#include <hip/hip_runtime.h>
#include <hip/hip_bf16.h>
#include <math.h>

#define N_SIMP 400000
#define E_NNZ  2400000
#define FIN    32
#define HDIM   64
#define KAPPA  3
#define G_NUM  512
#define NOUT   8
#define BN_EPS 1e-5

// ---- CSR build (two-level LDS counting sort) ----
#define NDIG_HALF 1563            // ceil(400000/256) coarse buckets per matrix
#define NDIG      3126            // L + U
#define P1_EDGES  4096            // edges per pass-1 block (16/thread)
#define P1_BLOCKS 1172            // ceil(4.8M / 4096)
#define CHUNKS    4
#define CHUNK_B   293             // P1_BLOCKS / CHUNKS (exact)
#define P2_CAP    3072            // bucket capacity (avg 1536, +26 sigma headroom)

typedef __hip_bfloat16 bf16;
typedef _Float16 f16;
typedef short s8v __attribute__((ext_vector_type(8)));    // 8 bf16 in 4 VGPRs
typedef ushort u8v __attribute__((ext_vector_type(8)));   // 8 bf16 raw
typedef float f4v __attribute__((ext_vector_type(4)));

__device__ __forceinline__ float elu_f(float x) {
    return x > 0.f ? x : expm1f(x);
}
__device__ __forceinline__ float bf2f(ushort u) {
    return __uint_as_float(((unsigned int)u) << 16);
}
__device__ __forceinline__ ushort f2bf(float f) {
    bf16 h = (bf16)f;
    return *(ushort*)&h;
}

// ---------------- CSR build: pass 1 (coarse bucketing, LDS hist) ----------------

__global__ __launch_bounds__(256) void p1_hist_kernel(const int* __restrict__ eiL,
                                                      const int* __restrict__ eiU,
                                                      int* __restrict__ cnt) {
    __shared__ int h[NDIG];
    int t = threadIdx.x;
    for (int j = t; j < NDIG; j += 256) h[j] = 0;
    __syncthreads();
    int base_i = blockIdx.x * P1_EDGES;
#pragma unroll
    for (int k = 0; k < P1_EDGES / 256; ++k) {
        int i = base_i + k * 256 + t;
        if (i < 2 * E_NNZ) {
            int dd;
            if (i < E_NNZ) dd = eiL[i] >> 8;
            else           dd = NDIG_HALF + (eiU[i - E_NNZ] >> 8);
            atomicAdd(&h[dd], 1);
        }
    }
    __syncthreads();
    for (int j = t; j < NDIG; j += 256) cnt[blockIdx.x * NDIG + j] = h[j];
}

// per-(chunk,digit) running prefix over that chunk's blocks; cnt becomes
// within-chunk exclusive prefix; chunkpart[c][d] = chunk total
__global__ void col_prefix_kernel(int* __restrict__ cnt, int* __restrict__ chunkpart) {
    int gid = blockIdx.x * 256 + threadIdx.x;
    if (gid >= CHUNKS * NDIG) return;
    int c = gid / NDIG, d = gid - c * NDIG;
    int run = 0;
#pragma unroll 8
    for (int b = c * CHUNK_B; b < (c + 1) * CHUNK_B; ++b) {
        int idx = b * NDIG + d;
        int v = cnt[idx];
        cnt[idx] = run;
        run += v;
    }
    chunkpart[c * NDIG + d] = run;
}

// per-digit: exclusive scan across the 4 chunks; tot[d] = digit total
__global__ void chunk_scan_kernel(int* __restrict__ chunkpart, int* __restrict__ tot) {
    int d = blockIdx.x * 256 + threadIdx.x;
    if (d >= NDIG) return;
    int run = 0;
#pragma unroll
    for (int c = 0; c < CHUNKS; ++c) {
        int v = chunkpart[c * NDIG + d];
        chunkpart[c * NDIG + d] = run;
        run += v;
    }
    tot[d] = run;
}

// exclusive scan of tot[NDIG] in place (becomes digit base), sentinel at [NDIG]
__global__ __launch_bounds__(1024) void scan_base_kernel(int* __restrict__ tot) {
    __shared__ int s[1024];
    int t = threadIdx.x;
    int v[4];
    int sum = 0;
#pragma unroll
    for (int k = 0; k < 4; ++k) {
        int d = t * 4 + k;
        v[k] = (d < NDIG) ? tot[d] : 0;
        sum += v[k];
    }
    s[t] = sum;
    __syncthreads();
    for (int off = 1; off < 1024; off <<= 1) {
        int x = (t >= off) ? s[t - off] : 0;
        __syncthreads();
        s[t] += x;
        __syncthreads();
    }
    int run = s[t] - sum;
#pragma unroll
    for (int k = 0; k < 4; ++k) {
        int d = t * 4 + k;
        if (d < NDIG) tot[d] = run;
        run += v[k];
    }
    if (t == 1023) tot[NDIG] = s[1023];   // = 2*E_NNZ
}

// scatter records into digit-grouped coarse array; rank from LDS hist replay
__global__ __launch_bounds__(256) void p1_scatter_kernel(
        const int* __restrict__ eiL, const float* __restrict__ lv,
        const int* __restrict__ eiU, const float* __restrict__ uv,
        const int* __restrict__ cnt, const int* __restrict__ chunkpart,
        const int* __restrict__ basev, int2* __restrict__ coarse) {
    __shared__ int h[NDIG];
    int t = threadIdx.x;
    for (int j = t; j < NDIG; j += 256) h[j] = 0;
    __syncthreads();
    int base_i = blockIdx.x * P1_EDGES;
    int cbase = blockIdx.x * NDIG;
    int chbase = (blockIdx.x / CHUNK_B) * NDIG;
#pragma unroll
    for (int k = 0; k < P1_EDGES / 256; ++k) {
        int i = base_i + k * 256 + t;
        if (i < 2 * E_NNZ) {
            int row, col, dd;
            float val;
            if (i < E_NNZ) {
                row = eiL[i]; col = eiL[E_NNZ + i]; val = lv[i];
                dd = row >> 8;
            } else {
                int e = i - E_NNZ;
                row = eiU[e]; col = eiU[E_NNZ + e]; val = uv[e];
                dd = NDIG_HALF + (row >> 8);
            }
            int rank = atomicAdd(&h[dd], 1);
            int pos = basev[dd] + chunkpart[chbase + dd] + cnt[cbase + dd] + rank;
            coarse[pos] = make_int2(((row & 255) << 24) | col, __float_as_int(val));
        }
    }
}

// ---------------- CSR build: pass 2 (per-bucket LDS counting sort) ----------------

__global__ __launch_bounds__(256) void p2_build_kernel(
        const int2* __restrict__ coarse, const int* __restrict__ basev,
        int* __restrict__ rpL, int* __restrict__ rpU,
        int2* __restrict__ edgeL, int2* __restrict__ edgeU) {
    __shared__ int pk[P2_CAP];
    __shared__ int vl[P2_CAP];
    __shared__ int hist[256];
    __shared__ int sc[256];
    int d = blockIdx.x;
    int t = threadIdx.x;
    int start = basev[d], end = basev[d + 1];
    int sz = end - start;
    if (sz > P2_CAP) sz = P2_CAP;   // never expected (avg 1536)
    for (int j = t; j < sz; j += 256) {
        int2 r = coarse[start + j];
        pk[j] = r.x;
        vl[j] = r.y;
    }
    hist[t] = 0;
    __syncthreads();
    int myrank[P2_CAP / 256];
#pragma unroll
    for (int k = 0; k < P2_CAP / 256; ++k) {
        int j = k * 256 + t;
        myrank[k] = (j < sz) ? atomicAdd(&hist[((unsigned)pk[j]) >> 24], 1) : 0;
    }
    __syncthreads();
    sc[t] = hist[t];
    __syncthreads();
    for (int off = 1; off < 256; off <<= 1) {
        int x = (t >= off) ? sc[t - off] : 0;
        __syncthreads();
        sc[t] += x;
        __syncthreads();
    }
    int offx = sc[t] - hist[t];   // exclusive prefix for bin t
    __syncthreads();
    hist[t] = offx;               // reuse hist as bin offsets
    __syncthreads();
    int which = (d >= NDIG_HALF);
    int lbase = start - (which ? E_NNZ : 0);
    int rowbase = (which ? d - NDIG_HALF : d) << 8;
    int row = rowbase + t;
    if (row < N_SIMP) {
        if (which) rpU[row] = lbase + offx;
        else       rpL[row] = lbase + offx;
    }
    int2* eout = which ? edgeU : edgeL;
#pragma unroll
    for (int k = 0; k < P2_CAP / 256; ++k) {
        int j = k * 256 + t;
        if (j < sz) {
            unsigned p = (unsigned)pk[j];
            int bin = p >> 24;
            int pos = lbase + hist[bin] + myrank[k];
            eout[pos] = make_int2((int)(p & 0xFFFFFFu), vl[j]);
        }
    }
}

// ---------------- small prep kernels ----------------

__global__ void combine_bias_kernel(const float* __restrict__ bh,
                                    const float* __restrict__ bl,
                                    const float* __restrict__ bu,
                                    float* __restrict__ out) {
    int h = threadIdx.x;
    float acc = bh[h];
    for (int k = 0; k < KAPPA; ++k) acc += bl[k * HDIM + h] + bu[k * HDIM + h];
    out[h] = acc;
}

__global__ void f32_to_bf16_kernel(const float* __restrict__ in, bf16* __restrict__ out) {
    int idx = blockIdx.x * 256 + threadIdx.x;
    out[idx] = (bf16)in[idx];
}

// all 6 weight transposes in one dispatch; wt layout fixed (offsets in ushorts)
__global__ void wtrans_all_kernel(const float* __restrict__ s0, const float* __restrict__ s1,
                                  const float* __restrict__ s2, const float* __restrict__ s3,
                                  const float* __restrict__ s4, const float* __restrict__ s5,
                                  ushort* __restrict__ wt) {
    int idx = blockIdx.x * 256 + threadIdx.x;   // 0..43007
    const float* src; int Ktot, off;
    if (idx < 2048)       { src = s0; Ktot = 32;  off = 0; }
    else if (idx < 6144)  { src = s1; Ktot = 64;  off = 2048; }
    else if (idx < 12288) { src = s2; Ktot = 96;  off = 6144; }
    else if (idx < 18432) { src = s3; Ktot = 96;  off = 12288; }
    else if (idx < 30720) { src = s4; Ktot = 192; off = 18432; }
    else                  { src = s5; Ktot = 192; off = 30720; }
    int rel = idx - off;
    int n = rel / Ktot, kk = rel - n * Ktot;
    wt[idx] = f2bf(src[kk * 64 + n]);
}

// ---------------- SpMM (CSR gather; max per-wave concurrency, 16B lanes) --------
// rp holds EXCLUSIVE row starts: s = rp[row], e = rp[row+1] (guarded at N-1)

// 32-wide: 4 lanes/row (8 ch each), 16 rows/wave, 64 rows/block
__global__ void spmm32_kernel(const int* __restrict__ rp, const int2* __restrict__ edge,
                              const bf16* __restrict__ srcb, int src_stride,
                              bf16* __restrict__ dstb) {
    const ushort* src = (const ushort*)srcb;
    ushort* dst = (ushort*)dstb;
    int tid = threadIdx.x;
    int lane = tid & 63;
    int wv = tid >> 6;
    int grp = lane >> 2;      // 0..15: row within wave
    int li = lane & 3;        // channels li*8 .. li*8+7
    int row = blockIdx.x * 64 + wv * 16 + grp;
    int s = rp[row];
    int e = (row == N_SIMP - 1) ? E_NNZ : rp[row + 1];
    int deg = e - s;
    float a[8] = {0.f, 0.f, 0.f, 0.f, 0.f, 0.f, 0.f, 0.f};
    if (deg > 0) {
        int2 ed[8];
#pragma unroll
        for (int t = 0; t < 8; ++t) {
            int j = s + t;
            ed[t] = edge[(j < e) ? j : (e - 1)];
        }
        u8v xs[8];
#pragma unroll
        for (int t = 0; t < 8; ++t)
            xs[t] = *(const u8v*)(src + (size_t)ed[t].x * src_stride + li * 8);
#pragma unroll
        for (int t = 0; t < 8; ++t) {
            float v = (t < deg) ? __int_as_float(ed[t].y) : 0.f;
#pragma unroll
            for (int c = 0; c < 8; ++c) a[c] += v * bf2f(xs[t][c]);
        }
        for (int j = s + 8; j < e; j += 4) {
            int2 e2[4];
#pragma unroll
            for (int t = 0; t < 4; ++t) {
                int jj = j + t;
                e2[t] = edge[(jj < e) ? jj : (e - 1)];
            }
            u8v x2[4];
#pragma unroll
            for (int t = 0; t < 4; ++t)
                x2[t] = *(const u8v*)(src + (size_t)e2[t].x * src_stride + li * 8);
#pragma unroll
            for (int t = 0; t < 4; ++t) {
                float v = (j + t < e) ? __int_as_float(e2[t].y) : 0.f;
#pragma unroll
                for (int c = 0; c < 8; ++c) a[c] += v * bf2f(x2[t][c]);
            }
        }
    }
    u8v w;
#pragma unroll
    for (int c = 0; c < 8; ++c) w[c] = f2bf(a[c]);
    *(u8v*)(dst + (size_t)row * 32 + li * 8) = w;
}

// 64-wide: 8 lanes/row (8 ch each), 8 rows/wave, 32 rows/block; stride 64
__global__ void spmm64_kernel(const int* __restrict__ rp, const int2* __restrict__ edge,
                              const bf16* __restrict__ srcb, bf16* __restrict__ dstb) {
    const ushort* src = (const ushort*)srcb;
    ushort* dst = (ushort*)dstb;
    int tid = threadIdx.x;
    int lane = tid & 63;
    int wv = tid >> 6;
    int grp = lane >> 3;      // 0..7: row within wave
    int li = lane & 7;        // channels li*8 .. li*8+7
    int row = blockIdx.x * 32 + wv * 8 + grp;
    int s = rp[row];
    int e = (row == N_SIMP - 1) ? E_NNZ : rp[row + 1];
    int deg = e - s;
    float a[8] = {0.f, 0.f, 0.f, 0.f, 0.f, 0.f, 0.f, 0.f};
    if (deg > 0) {
        int2 ed[8];
#pragma unroll
        for (int t = 0; t < 8; ++t) {
            int j = s + t;
            ed[t] = edge[(j < e) ? j : (e - 1)];
        }
        u8v xs[8];
#pragma unroll
        for (int t = 0; t < 8; ++t)
            xs[t] = *(const u8v*)(src + (size_t)ed[t].x * 64 + li * 8);
#pragma unroll
        for (int t = 0; t < 8; ++t) {
            float v = (t < deg) ? __int_as_float(ed[t].y) : 0.f;
#pragma unroll
            for (int c = 0; c < 8; ++c) a[c] += v * bf2f(xs[t][c]);
        }
        for (int j = s + 8; j < e; j += 4) {
            int2 e2[4];
#pragma unroll
            for (int t = 0; t < 4; ++t) {
                int jj = j + t;
                e2[t] = edge[(jj < e) ? jj : (e - 1)];
            }
            u8v x2[4];
#pragma unroll
            for (int t = 0; t < 4; ++t)
                x2[t] = *(const u8v*)(src + (size_t)e2[t].x * 64 + li * 8);
#pragma unroll
            for (int t = 0; t < 4; ++t) {
                float v = (j + t < e) ? __int_as_float(e2[t].y) : 0.f;
#pragma unroll
                for (int c = 0; c < 8; ++c) a[c] += v * bf2f(x2[t][c]);
            }
        }
    }
    u8v w;
#pragma unroll
    for (int c = 0; c < 8; ++c) w[c] = f2bf(a[c]);
    *(u8v*)(dst + (size_t)row * 64 + li * 8) = w;
}

// ---------------- MFMA GEMM: z[N,64] (fp16) (=bias+ / +=) A[N, NCH*32] @ W -------

template <int NCH, bool INIT>
__global__ __launch_bounds__(256) void mfma_gemm_kernel(
        const ushort* __restrict__ s0, int st0,
        const ushort* __restrict__ s1, int st1,
        const ushort* __restrict__ s2, int st2,
        const ushort* __restrict__ s3, int st3,
        const ushort* __restrict__ Wt, int Kstride,
        const float* __restrict__ bias,
        f16* __restrict__ z) {
    int tid = threadIdx.x;
    int wv = tid >> 6, lane = tid & 63;
    int quad = lane >> 4, n = lane & 15;
    int rowbase = blockIdx.x * 64 + wv * 16;
    int arow = rowbase + n;  // A-operand row m = lane&15

    f4v acc0 = {0.f, 0.f, 0.f, 0.f};
    f4v acc1 = {0.f, 0.f, 0.f, 0.f};
    f4v acc2 = {0.f, 0.f, 0.f, 0.f};
    f4v acc3 = {0.f, 0.f, 0.f, 0.f};

#pragma unroll
    for (int ch = 0; ch < NCH; ++ch) {
        const ushort* sp = (ch == 0) ? s0 : (ch == 1) ? s1 : (ch == 2) ? s2 : s3;
        int st = (ch == 0) ? st0 : (ch == 1) ? st1 : (ch == 2) ? st2 : st3;
        s8v a = *(const s8v*)(sp + (size_t)arow * st + quad * 8);
        const ushort* wb = Wt + ch * 32 + quad * 8;
        s8v b0 = *(const s8v*)(wb + (size_t)(0 * 16 + n) * Kstride);
        s8v b1 = *(const s8v*)(wb + (size_t)(1 * 16 + n) * Kstride);
        s8v b2 = *(const s8v*)(wb + (size_t)(2 * 16 + n) * Kstride);
        s8v b3 = *(const s8v*)(wb + (size_t)(3 * 16 + n) * Kstride);
        acc0 = __builtin_amdgcn_mfma_f32_16x16x32_bf16(a, b0, acc0, 0, 0, 0);
        acc1 = __builtin_amdgcn_mfma_f32_16x16x32_bf16(a, b1, acc1, 0, 0, 0);
        acc2 = __builtin_amdgcn_mfma_f32_16x16x32_bf16(a, b2, acc2, 0, 0, 0);
        acc3 = __builtin_amdgcn_mfma_f32_16x16x32_bf16(a, b3, acc3, 0, 0, 0);
    }
    // C/D layout: col = lane&15, row = quad*4 + reg
#pragma unroll
    for (int r = 0; r < 4; ++r) {
        int orow = rowbase + quad * 4 + r;
        f16* zp = z + (size_t)orow * 64 + n;
        if (INIT) {
            zp[0]  = (f16)(bias[n]      + acc0[r]);
            zp[16] = (f16)(bias[16 + n] + acc1[r]);
            zp[32] = (f16)(bias[32 + n] + acc2[r]);
            zp[48] = (f16)(bias[48 + n] + acc3[r]);
        } else {
            zp[0]  = (f16)((float)zp[0]  + acc0[r]);
            zp[16] = (f16)((float)zp[16] + acc1[r]);
            zp[32] = (f16)((float)zp[32] + acc2[r]);
            zp[48] = (f16)((float)zp[48] + acc3[r]);
        }
    }
}

// ---------------- BN / pool / MLP ----------------

__global__ void bn_stats_kernel(const f16* __restrict__ z, double* __restrict__ stats) {
    __shared__ double s1[256], s2[256];
    int tid = threadIdx.x;
    const long long total = (long long)N_SIMP * HDIM;
    double sum = 0.0, sq = 0.0;
    for (long long idx = (long long)blockIdx.x * 256 + tid; idx < total;
         idx += (long long)gridDim.x * 256) {
        float v = (float)z[idx];
        sum += v;
        sq += (double)v * v;
    }
    s1[tid] = sum; s2[tid] = sq;
    __syncthreads();
    if (tid < 64) {
        double a = s1[tid] + s1[tid + 64] + s1[tid + 128] + s1[tid + 192];
        double b = s2[tid] + s2[tid + 64] + s2[tid + 128] + s2[tid + 192];
        atomicAdd(&stats[tid], a);
        atomicAdd(&stats[64 + tid], b);
    }
}

// layer-0: h0bf = bf16(elu(bn(z)))
__global__ void bn_elu_bf16_kernel(const f16* __restrict__ z, const double* __restrict__ stats,
                                   const float* __restrict__ gamma, const float* __restrict__ beta,
                                   bf16* __restrict__ out) {
    __shared__ float scale_s[64], shift_s[64];
    int tid = threadIdx.x;
    if (tid < 64) {
        double mean = stats[tid] / (double)N_SIMP;
        double var = stats[64 + tid] / (double)N_SIMP - mean * mean;
        double sc = (double)gamma[tid] / sqrt(var + BN_EPS);
        scale_s[tid] = (float)sc;
        shift_s[tid] = (float)((double)beta[tid] - mean * sc);
    }
    __syncthreads();
    const long long total = (long long)N_SIMP * HDIM;
    for (long long idx = (long long)blockIdx.x * 256 + tid; idx < total;
         idx += (long long)gridDim.x * 256) {
        int h = (int)(idx & 63);
        out[idx] = (bf16)elu_f((float)z[idx] * scale_s[h] + shift_s[h]);
    }
}

// layer-1: z = elu(bn(z)) in place (fp16)
__global__ void bn_elu_f16_kernel(f16* __restrict__ z, const double* __restrict__ stats,
                                  const float* __restrict__ gamma, const float* __restrict__ beta) {
    __shared__ float scale_s[64], shift_s[64];
    int tid = threadIdx.x;
    if (tid < 64) {
        double mean = stats[tid] / (double)N_SIMP;
        double var = stats[64 + tid] / (double)N_SIMP - mean * mean;
        double sc = (double)gamma[tid] / sqrt(var + BN_EPS);
        scale_s[tid] = (float)sc;
        shift_s[tid] = (float)((double)beta[tid] - mean * sc);
    }
    __syncthreads();
    const long long total = (long long)N_SIMP * HDIM;
    for (long long idx = (long long)blockIdx.x * 256 + tid; idx < total;
         idx += (long long)gridDim.x * 256) {
        int h = (int)(idx & 63);
        z[idx] = (f16)elu_f((float)z[idx] * scale_s[h] + shift_s[h]);
    }
}

__global__ void pool_kernel(const f16* __restrict__ hbuf, const int* __restrict__ bidx,
                            float* __restrict__ gbuf) {
    __shared__ float smax[256], ssum[256];
    int g = blockIdx.x;
    int tid = threadIdx.x;
    int lo = 0, hi = N_SIMP;
    while (lo < hi) { int mid = (lo + hi) >> 1; if (bidx[mid] < g) lo = mid + 1; else hi = mid; }
    int start = lo;
    hi = N_SIMP;
    while (lo < hi) { int mid = (lo + hi) >> 1; if (bidx[mid] < g + 1) lo = mid + 1; else hi = mid; }
    int end = lo;
    int h = tid & 63, rep = tid >> 6;
    float mx = -INFINITY, sm = 0.f;
    for (int i = start + rep; i < end; i += 4) {
        float v = (float)hbuf[(size_t)i * HDIM + h];
        mx = fmaxf(mx, v);
        sm += v;
    }
    smax[tid] = mx; ssum[tid] = sm;
    __syncthreads();
    if (tid < 64) {
        float m = fmaxf(fmaxf(smax[tid], smax[tid + 64]), fmaxf(smax[tid + 128], smax[tid + 192]));
        float s = ssum[tid] + ssum[tid + 64] + ssum[tid + 128] + ssum[tid + 192];
        int cnt = end - start;
        float mean = s / fmaxf((float)cnt, 1.f);
        gbuf[g * 128 + tid] = elu_f(m);
        gbuf[g * 128 + 64 + tid] = elu_f(mean);
    }
}

__global__ void mlp_kernel(const float* __restrict__ gbuf, const float* __restrict__ W1,
                           const float* __restrict__ b1, const float* __restrict__ W2,
                           const float* __restrict__ b2, float* __restrict__ out) {
    __shared__ float gs[128];
    __shared__ float hs[64];
    int g = blockIdx.x, tid = threadIdx.x;
    gs[tid] = gbuf[g * 128 + tid];
    gs[64 + tid] = gbuf[g * 128 + 64 + tid];
    __syncthreads();
    float acc = b1[tid];
#pragma unroll
    for (int k = 0; k < 128; ++k) acc += gs[k] * W1[k * 64 + tid];
    hs[tid] = fmaxf(acc, 0.f);
    __syncthreads();
    if (tid < 8) {
        float o = b2[tid];
#pragma unroll
        for (int k = 0; k < 64; ++k) o += hs[k] * W2[k * 8 + tid];
        out[g * 8 + tid] = o;
    }
}

// ---------------- host side ----------------

extern "C" void kernel_launch(void* const* d_in, const int* in_sizes, int n_in,
                              void* d_out, int out_size, void* d_ws, size_t ws_size,
                              hipStream_t stream) {
    const float* x     = (const float*)d_in[0];
    const int*   li    = (const int*)d_in[1];
    const float* lv    = (const float*)d_in[2];
    const int*   ui    = (const int*)d_in[3];
    const float* uv    = (const float*)d_in[4];
    const int*   bidx  = (const int*)d_in[5];
    const float* l0_Wl = (const float*)d_in[6];
    const float* l0_bl = (const float*)d_in[7];
    const float* l0_Wu = (const float*)d_in[8];
    const float* l0_bu = (const float*)d_in[9];
    const float* l0_Wh = (const float*)d_in[10];
    const float* l0_bh = (const float*)d_in[11];
    const float* l1_Wl = (const float*)d_in[12];
    const float* l1_bl = (const float*)d_in[13];
    const float* l1_Wu = (const float*)d_in[14];
    const float* l1_bu = (const float*)d_in[15];
    const float* l1_Wh = (const float*)d_in[16];
    const float* l1_bh = (const float*)d_in[17];
    const float* bn0_g = (const float*)d_in[18];
    const float* bn0_b = (const float*)d_in[19];
    const float* bn1_g = (const float*)d_in[20];
    const float* bn1_b = (const float*)d_in[21];
    const float* mW1   = (const float*)d_in[22];
    const float* mb1   = (const float*)d_in[23];
    const float* mW2   = (const float*)d_in[24];
    const float* mb2   = (const float*)d_in[25];
    float* out = (float*)d_out;

    // ---- workspace layout (total ~246.8 MB <= 256 MiB) ----
    char* base = (char*)d_ws;
    f16*   z     = (f16*)base;                                    //  51,200,000
    bf16*  h0bf  = (bf16*)(base + 51200000ull);                   //  51,200,000
    bf16*  g1    = (bf16*)(base + 102400000ull);                  //  51,200,000
    bf16*  g2    = (bf16*)(base + 153600000ull);                  //  51,200,000
    int2*  edgeL = (int2*)(base + 204800000ull);                  //  19,200,000
    int2*  edgeU = (int2*)(base + 224000000ull);                  //  19,200,000
    int*   rpL   = (int*)(base + 243200000ull);                   //   1,600,032
    int*   rpU   = (int*)(base + 244800032ull);                   //   1,600,032
    double* stats = (double*)(base + 246404160ull);               //   1 KB
    float* cbias  = (float*)(base + 246405184ull);                //   256 B
    float* gbuf   = (float*)(base + 246405440ull);                //   262,144
    ushort* wt    = (ushort*)(base + 246667584ull);               //   86,016

    // CSR-build scratch aliases (dead regions during build):
    //  z region  : coarse 38.4 MB + basev 12.5 KB + chunkpart 50 KB
    //  h0bf region: per-block counts 14.66 MB
    int2* coarse    = (int2*)base;                                // 38,400,000
    int*  basev     = (int*)(base + 38400000ull);                 // (NDIG+1)*4
    int*  chunkpart = (int*)(base + 38416000ull);                 // CHUNKS*NDIG*4
    int*  ccnt      = (int*)(base + 51200000ull);                 // P1_BLOCKS*NDIG*4

    // layer-0 scratch: 4 slots of N*32 bf16 inside g1/g2
    bf16* xbf = g1;
    bf16* cA  = g1 + (size_t)N_SIMP * 32;
    bf16* cB  = g2;
    bf16* cC  = g2 + (size_t)N_SIMP * 32;

    // weight-transpose sub-buffers (ushort elements; offsets match wtrans_all_kernel)
    ushort* wt_l0h = wt;            // 64 x 32
    ushort* wt_l1h = wt + 2048;     // 64 x 64
    ushort* wt_l0l = wt + 6144;     // 64 x 96
    ushort* wt_l0u = wt + 12288;    // 64 x 96
    ushort* wt_l1l = wt + 18432;    // 64 x 192
    ushort* wt_l1u = wt + 30720;    // 64 x 192

    const int SP32_BLOCKS = N_SIMP / 64;   // 6,250
    const int SP64_BLOCKS = N_SIMP / 32;   // 12,500
    const int MF_BLOCKS   = N_SIMP / 64;   // 6,250

    // ---- prep: weight transposes (one dispatch) + x->bf16 ----
    wtrans_all_kernel<<<168, 256, 0, stream>>>(l0_Wh, l1_Wh, l0_Wl, l0_Wu, l1_Wl, l1_Wu, wt);
    f32_to_bf16_kernel<<<N_SIMP * 32 / 256, 256, 0, stream>>>(x, xbf);

    // ---- CSR builds: two-level LDS counting sort (no global atomics) ----
    p1_hist_kernel<<<P1_BLOCKS, 256, 0, stream>>>(li, ui, ccnt);
    col_prefix_kernel<<<(CHUNKS * NDIG + 255) / 256, 256, 0, stream>>>(ccnt, chunkpart);
    chunk_scan_kernel<<<(NDIG + 255) / 256, 256, 0, stream>>>(chunkpart, basev);
    scan_base_kernel<<<1, 1024, 0, stream>>>(basev);
    p1_scatter_kernel<<<P1_BLOCKS, 256, 0, stream>>>(li, lv, ui, uv, ccnt, chunkpart,
                                                     basev, coarse);
    p2_build_kernel<<<NDIG, 256, 0, stream>>>(coarse, basev, rpL, rpU, edgeL, edgeU);

    const ushort* xbfu = (const ushort*)xbf;
    const ushort* h0u  = (const ushort*)h0bf;
    const ushort* g1u  = (const ushort*)g1;
    const ushort* g2u  = (const ushort*)g2;

    // ---------------- layer 0 (F_IN=32 -> H=64), 32-wide chains ----------------
    combine_bias_kernel<<<1, 64, 0, stream>>>(l0_bh, l0_bl, l0_bu, cbias);
    mfma_gemm_kernel<1, true><<<MF_BLOCKS, 256, 0, stream>>>(
        xbfu, 32, nullptr, 0, nullptr, 0, nullptr, 0, wt_l0h, 32, cbias, z);

    // lower chain
    spmm32_kernel<<<SP32_BLOCKS, 256, 0, stream>>>(rpL, edgeL, xbf, 32, cA);
    spmm32_kernel<<<SP32_BLOCKS, 256, 0, stream>>>(rpL, edgeL, cA, 32, cB);
    spmm32_kernel<<<SP32_BLOCKS, 256, 0, stream>>>(rpL, edgeL, cB, 32, cC);
    mfma_gemm_kernel<3, false><<<MF_BLOCKS, 256, 0, stream>>>(
        (const ushort*)cA, 32, (const ushort*)cB, 32, (const ushort*)cC, 32,
        nullptr, 0, wt_l0l, 96, nullptr, z);
    // upper chain
    spmm32_kernel<<<SP32_BLOCKS, 256, 0, stream>>>(rpU, edgeU, xbf, 32, cA);
    spmm32_kernel<<<SP32_BLOCKS, 256, 0, stream>>>(rpU, edgeU, cA, 32, cB);
    spmm32_kernel<<<SP32_BLOCKS, 256, 0, stream>>>(rpU, edgeU, cB, 32, cC);
    mfma_gemm_kernel<3, false><<<MF_BLOCKS, 256, 0, stream>>>(
        (const ushort*)cA, 32, (const ushort*)cB, 32, (const ushort*)cC, 32,
        nullptr, 0, wt_l0u, 96, nullptr, z);

    (void)hipMemsetAsync(stats, 0, 128 * sizeof(double), stream);
    bn_stats_kernel<<<1024, 256, 0, stream>>>(z, stats);
    bn_elu_bf16_kernel<<<2048, 256, 0, stream>>>(z, stats, bn0_g, bn0_b, h0bf);

    // ---------------- layer 1 (H=64 -> H=64), 64-wide chains ----------------
    combine_bias_kernel<<<1, 64, 0, stream>>>(l1_bh, l1_bl, l1_bu, cbias);
    mfma_gemm_kernel<2, true><<<MF_BLOCKS, 256, 0, stream>>>(
        h0u, 64, h0u + 32, 64, nullptr, 0, nullptr, 0, wt_l1h, 64, cbias, z);

    {
        const int*  rps[2]   = {rpL, rpU};
        const int2* edges[2] = {edgeL, edgeU};
        ushort*     wts[2]   = {wt_l1l, wt_l1u};
        for (int lap = 0; lap < 2; ++lap) {
            spmm64_kernel<<<SP64_BLOCKS, 256, 0, stream>>>(rps[lap], edges[lap], h0bf, g1);
            spmm64_kernel<<<SP64_BLOCKS, 256, 0, stream>>>(rps[lap], edges[lap], g1, g2);
            mfma_gemm_kernel<4, false><<<MF_BLOCKS, 256, 0, stream>>>(
                g1u, 64, g1u + 32, 64, g2u, 64, g2u + 32, 64, wts[lap], 192, nullptr, z);
            spmm64_kernel<<<SP64_BLOCKS, 256, 0, stream>>>(rps[lap], edges[lap], g2, g1);
            mfma_gemm_kernel<2, false><<<MF_BLOCKS, 256, 0, stream>>>(
                g1u, 64, g1u + 32, 64, nullptr, 0, nullptr, 0, wts[lap] + 128, 192, nullptr, z);
        }
    }

    (void)hipMemsetAsync(stats, 0, 128 * sizeof(double), stream);
    bn_stats_kernel<<<1024, 256, 0, stream>>>(z, stats);
    bn_elu_f16_kernel<<<2048, 256, 0, stream>>>(z, stats, bn1_g, bn1_b);

    // ---------------- pool + MLP ----------------
    pool_kernel<<<G_NUM, 256, 0, stream>>>(z, bidx, gbuf);
    mlp_kernel<<<G_NUM, 64, 0, stream>>>(gbuf, mW1, mb1, mW2, mb2, out);
}

// Round 3
// 1527.463 us; speedup vs baseline: 1.2321x; 1.0518x over previous
//
#include <hip/hip_runtime.h>
#include <hip/hip_bf16.h>
#include <math.h>

#define N_SIMP 400000
#define E_NNZ  2400000
#define FIN    32
#define HDIM   64
#define KAPPA  3
#define G_NUM  512
#define NOUT   8
#define BN_EPS 1e-5

// ---- CSR build (two-level LDS counting sort, 1024-row coarse buckets) ----
#define NDIG_HALF 391             // ceil(400000/1024) coarse buckets per matrix
#define NDIG      782             // L + U
#define P1_EDGES  16384           // edges per pass-1 block (16/thread @ 1024 thr)
#define P1_BLOCKS 293             // ceil(4.8M / 16384)
#define P1_T      1024
#define P2_CAP    7168            // bucket capacity (avg 6144, +13 sigma headroom)
#define P2_T      512

typedef __hip_bfloat16 bf16;
typedef _Float16 f16;
typedef short s8v __attribute__((ext_vector_type(8)));    // 8 bf16 in 4 VGPRs
typedef ushort u8v __attribute__((ext_vector_type(8)));   // 8 bf16 raw
typedef float f4v __attribute__((ext_vector_type(4)));

__device__ __forceinline__ float elu_f(float x) {
    return x > 0.f ? x : expm1f(x);
}
__device__ __forceinline__ float bf2f(ushort u) {
    return __uint_as_float(((unsigned int)u) << 16);
}
__device__ __forceinline__ ushort f2bf(float f) {
    bf16 h = (bf16)f;
    return *(ushort*)&h;
}

// ---------------- CSR build: pass 1 (coarse bucketing, LDS hist) ----------------

__global__ __launch_bounds__(P1_T) void p1_hist_kernel(const int* __restrict__ eiL,
                                                       const int* __restrict__ eiU,
                                                       int* __restrict__ cnt) {
    __shared__ int h[NDIG];
    int t = threadIdx.x;
    for (int j = t; j < NDIG; j += P1_T) h[j] = 0;
    __syncthreads();
    int base_i = blockIdx.x * P1_EDGES;
#pragma unroll 4
    for (int k = 0; k < P1_EDGES / P1_T; ++k) {
        int i = base_i + k * P1_T + t;
        if (i < 2 * E_NNZ) {
            int dd;
            if (i < E_NNZ) dd = eiL[i] >> 10;
            else           dd = NDIG_HALF + (eiU[i - E_NNZ] >> 10);
            atomicAdd(&h[dd], 1);
        }
    }
    __syncthreads();
    for (int j = t; j < NDIG; j += P1_T) cnt[blockIdx.x * NDIG + j] = h[j];
}

// per-digit running prefix over blocks; cnt becomes per-block exclusive prefix;
// tot[d] = digit total
__global__ void col_prefix_kernel(int* __restrict__ cnt, int* __restrict__ tot) {
    int d = blockIdx.x * 256 + threadIdx.x;
    if (d >= NDIG) return;
    int run = 0;
#pragma unroll 8
    for (int b = 0; b < P1_BLOCKS; ++b) {
        int idx = b * NDIG + d;
        int v = cnt[idx];
        cnt[idx] = run;
        run += v;
    }
    tot[d] = run;
}

// exclusive scan of tot[NDIG] in place (becomes digit base), sentinel at [NDIG]
__global__ __launch_bounds__(1024) void scan_base_kernel(int* __restrict__ tot) {
    __shared__ int s[1024];
    int t = threadIdx.x;
    int v = (t < NDIG) ? tot[t] : 0;
    s[t] = v;
    __syncthreads();
    for (int off = 1; off < 1024; off <<= 1) {
        int x = (t >= off) ? s[t - off] : 0;
        __syncthreads();
        s[t] += x;
        __syncthreads();
    }
    if (t < NDIG) tot[t] = s[t] - v;
    if (t == 1023) tot[NDIG] = s[1023];   // = 2*E_NNZ
}

// scatter records into digit-grouped coarse array; base+prefix fused into LDS hist
__global__ __launch_bounds__(P1_T) void p1_scatter_kernel(
        const int* __restrict__ eiL, const float* __restrict__ lv,
        const int* __restrict__ eiU, const float* __restrict__ uv,
        const int* __restrict__ cnt, const int* __restrict__ basev,
        int2* __restrict__ coarse) {
    __shared__ int h[NDIG];
    int t = threadIdx.x;
    int cbase = blockIdx.x * NDIG;
    for (int j = t; j < NDIG; j += P1_T) h[j] = basev[j] + cnt[cbase + j];
    __syncthreads();
    int base_i = blockIdx.x * P1_EDGES;
#pragma unroll 4
    for (int k = 0; k < P1_EDGES / P1_T; ++k) {
        int i = base_i + k * P1_T + t;
        if (i < 2 * E_NNZ) {
            int row, col, dd;
            float val;
            if (i < E_NNZ) {
                row = eiL[i]; col = eiL[E_NNZ + i]; val = lv[i];
                dd = row >> 10;
            } else {
                int e = i - E_NNZ;
                row = eiU[e]; col = eiU[E_NNZ + e]; val = uv[e];
                dd = NDIG_HALF + (row >> 10);
            }
            int pos = atomicAdd(&h[dd], 1);
            coarse[pos] = make_int2(((row & 1023) << 22) | col, __float_as_int(val));
        }
    }
}

// ---------------- CSR build: pass 2 (per-bucket LDS counting sort) ----------------

__global__ __launch_bounds__(P2_T) void p2_build_kernel(
        const int2* __restrict__ coarse, const int* __restrict__ basev,
        int* __restrict__ rpL, int* __restrict__ rpU,
        int2* __restrict__ edgeL, int2* __restrict__ edgeU) {
    __shared__ int pk[P2_CAP];
    __shared__ int vl[P2_CAP];
    __shared__ int hist[1024];
    __shared__ int sc[P2_T];
    int d = blockIdx.x;
    int t = threadIdx.x;
    int start = basev[d], end = basev[d + 1];
    int sz = end - start;
    if (sz > P2_CAP) sz = P2_CAP;   // never expected (avg 6144, 13 sigma)
    for (int j = t; j < sz; j += P2_T) {
        int2 r = coarse[start + j];
        pk[j] = r.x;
        vl[j] = r.y;
    }
    hist[t] = 0;
    hist[t + P2_T] = 0;
    __syncthreads();
    int myrank[P2_CAP / P2_T];
#pragma unroll
    for (int k = 0; k < P2_CAP / P2_T; ++k) {
        int j = k * P2_T + t;
        myrank[k] = (j < sz) ? atomicAdd(&hist[((unsigned)pk[j]) >> 22], 1) : 0;
    }
    __syncthreads();
    int h0 = hist[2 * t], h1 = hist[2 * t + 1];
    sc[t] = h0 + h1;
    __syncthreads();
    for (int off = 1; off < P2_T; off <<= 1) {
        int x = (t >= off) ? sc[t - off] : 0;
        __syncthreads();
        sc[t] += x;
        __syncthreads();
    }
    int pbase = sc[t] - (h0 + h1);   // exclusive prefix of bin pair
    __syncthreads();
    hist[2 * t] = pbase;
    hist[2 * t + 1] = pbase + h0;
    // rp write (2 rows per thread)
    int which = (d >= NDIG_HALF);
    int lbase = start - (which ? E_NNZ : 0);
    int rowbase = (which ? d - NDIG_HALF : d) << 10;
    int* rp = which ? rpU : rpL;
    int r0 = rowbase + 2 * t, r1 = r0 + 1;
    if (r0 < N_SIMP) rp[r0] = lbase + pbase;
    if (r1 < N_SIMP) rp[r1] = lbase + pbase + h0;
    __syncthreads();
    int2* eout = which ? edgeU : edgeL;
#pragma unroll
    for (int k = 0; k < P2_CAP / P2_T; ++k) {
        int j = k * P2_T + t;
        if (j < sz) {
            unsigned p = (unsigned)pk[j];
            int pos = lbase + hist[p >> 22] + myrank[k];
            eout[pos] = make_int2((int)(p & 0x3FFFFF), vl[j]);
        }
    }
}

// ---------------- small prep kernels ----------------

__global__ void combine_bias_kernel(const float* __restrict__ bh,
                                    const float* __restrict__ bl,
                                    const float* __restrict__ bu,
                                    float* __restrict__ out) {
    int h = threadIdx.x;
    float acc = bh[h];
    for (int k = 0; k < KAPPA; ++k) acc += bl[k * HDIM + h] + bu[k * HDIM + h];
    out[h] = acc;
}

__global__ void f32_to_bf16_kernel(const float* __restrict__ in, bf16* __restrict__ out) {
    int idx = blockIdx.x * 256 + threadIdx.x;
    out[idx] = (bf16)in[idx];
}

// all 6 weight transposes in one dispatch; wt layout fixed (offsets in ushorts)
__global__ void wtrans_all_kernel(const float* __restrict__ s0, const float* __restrict__ s1,
                                  const float* __restrict__ s2, const float* __restrict__ s3,
                                  const float* __restrict__ s4, const float* __restrict__ s5,
                                  ushort* __restrict__ wt) {
    int idx = blockIdx.x * 256 + threadIdx.x;   // 0..43007
    const float* src; int Ktot, off;
    if (idx < 2048)       { src = s0; Ktot = 32;  off = 0; }
    else if (idx < 6144)  { src = s1; Ktot = 64;  off = 2048; }
    else if (idx < 12288) { src = s2; Ktot = 96;  off = 6144; }
    else if (idx < 18432) { src = s3; Ktot = 96;  off = 12288; }
    else if (idx < 30720) { src = s4; Ktot = 192; off = 18432; }
    else                  { src = s5; Ktot = 192; off = 30720; }
    int rel = idx - off;
    int n = rel / Ktot, kk = rel - n * Ktot;
    wt[idx] = f2bf(src[kk * 64 + n]);
}

// ---------------- SpMM (CSR gather; max per-wave concurrency, 16B lanes) --------
// rp holds EXCLUSIVE row starts: s = rp[row], e = rp[row+1] (guarded at N-1)

// 32-wide: 4 lanes/row (8 ch each), 16 rows/wave, 64 rows/block
__global__ void spmm32_kernel(const int* __restrict__ rp, const int2* __restrict__ edge,
                              const bf16* __restrict__ srcb, int src_stride,
                              bf16* __restrict__ dstb) {
    const ushort* src = (const ushort*)srcb;
    ushort* dst = (ushort*)dstb;
    int tid = threadIdx.x;
    int lane = tid & 63;
    int wv = tid >> 6;
    int grp = lane >> 2;      // 0..15: row within wave
    int li = lane & 3;        // channels li*8 .. li*8+7
    int row = blockIdx.x * 64 + wv * 16 + grp;
    int s = rp[row];
    int e = (row == N_SIMP - 1) ? E_NNZ : rp[row + 1];
    int deg = e - s;
    float a[8] = {0.f, 0.f, 0.f, 0.f, 0.f, 0.f, 0.f, 0.f};
    if (deg > 0) {
        int2 ed[8];
#pragma unroll
        for (int t = 0; t < 8; ++t) {
            int j = s + t;
            ed[t] = edge[(j < e) ? j : (e - 1)];
        }
        u8v xs[8];
#pragma unroll
        for (int t = 0; t < 8; ++t)
            xs[t] = *(const u8v*)(src + (size_t)ed[t].x * src_stride + li * 8);
#pragma unroll
        for (int t = 0; t < 8; ++t) {
            float v = (t < deg) ? __int_as_float(ed[t].y) : 0.f;
#pragma unroll
            for (int c = 0; c < 8; ++c) a[c] += v * bf2f(xs[t][c]);
        }
        for (int j = s + 8; j < e; j += 4) {
            int2 e2[4];
#pragma unroll
            for (int t = 0; t < 4; ++t) {
                int jj = j + t;
                e2[t] = edge[(jj < e) ? jj : (e - 1)];
            }
            u8v x2[4];
#pragma unroll
            for (int t = 0; t < 4; ++t)
                x2[t] = *(const u8v*)(src + (size_t)e2[t].x * src_stride + li * 8);
#pragma unroll
            for (int t = 0; t < 4; ++t) {
                float v = (j + t < e) ? __int_as_float(e2[t].y) : 0.f;
#pragma unroll
                for (int c = 0; c < 8; ++c) a[c] += v * bf2f(x2[t][c]);
            }
        }
    }
    u8v w;
#pragma unroll
    for (int c = 0; c < 8; ++c) w[c] = f2bf(a[c]);
    *(u8v*)(dst + (size_t)row * 32 + li * 8) = w;
}

// 64-wide: 8 lanes/row (8 ch each), 8 rows/wave, 32 rows/block; stride 64
__global__ void spmm64_kernel(const int* __restrict__ rp, const int2* __restrict__ edge,
                              const bf16* __restrict__ srcb, bf16* __restrict__ dstb) {
    const ushort* src = (const ushort*)srcb;
    ushort* dst = (ushort*)dstb;
    int tid = threadIdx.x;
    int lane = tid & 63;
    int wv = tid >> 6;
    int grp = lane >> 3;      // 0..7: row within wave
    int li = lane & 7;        // channels li*8 .. li*8+7
    int row = blockIdx.x * 32 + wv * 8 + grp;
    int s = rp[row];
    int e = (row == N_SIMP - 1) ? E_NNZ : rp[row + 1];
    int deg = e - s;
    float a[8] = {0.f, 0.f, 0.f, 0.f, 0.f, 0.f, 0.f, 0.f};
    if (deg > 0) {
        int2 ed[8];
#pragma unroll
        for (int t = 0; t < 8; ++t) {
            int j = s + t;
            ed[t] = edge[(j < e) ? j : (e - 1)];
        }
        u8v xs[8];
#pragma unroll
        for (int t = 0; t < 8; ++t)
            xs[t] = *(const u8v*)(src + (size_t)ed[t].x * 64 + li * 8);
#pragma unroll
        for (int t = 0; t < 8; ++t) {
            float v = (t < deg) ? __int_as_float(ed[t].y) : 0.f;
#pragma unroll
            for (int c = 0; c < 8; ++c) a[c] += v * bf2f(xs[t][c]);
        }
        for (int j = s + 8; j < e; j += 4) {
            int2 e2[4];
#pragma unroll
            for (int t = 0; t < 4; ++t) {
                int jj = j + t;
                e2[t] = edge[(jj < e) ? jj : (e - 1)];
            }
            u8v x2[4];
#pragma unroll
            for (int t = 0; t < 4; ++t)
                x2[t] = *(const u8v*)(src + (size_t)e2[t].x * 64 + li * 8);
#pragma unroll
            for (int t = 0; t < 4; ++t) {
                float v = (j + t < e) ? __int_as_float(e2[t].y) : 0.f;
#pragma unroll
                for (int c = 0; c < 8; ++c) a[c] += v * bf2f(x2[t][c]);
            }
        }
    }
    u8v w;
#pragma unroll
    for (int c = 0; c < 8; ++c) w[c] = f2bf(a[c]);
    *(u8v*)(dst + (size_t)row * 64 + li * 8) = w;
}

// ---------------- MFMA GEMM: z[N,64] (fp16) (=bias+ / +=) A[N, NCH*32] @ W -------

template <int NCH, bool INIT>
__global__ __launch_bounds__(256) void mfma_gemm_kernel(
        const ushort* __restrict__ s0, int st0,
        const ushort* __restrict__ s1, int st1,
        const ushort* __restrict__ s2, int st2,
        const ushort* __restrict__ s3, int st3,
        const ushort* __restrict__ Wt, int Kstride,
        const float* __restrict__ bias,
        f16* __restrict__ z) {
    int tid = threadIdx.x;
    int wv = tid >> 6, lane = tid & 63;
    int quad = lane >> 4, n = lane & 15;
    int rowbase = blockIdx.x * 64 + wv * 16;
    int arow = rowbase + n;  // A-operand row m = lane&15

    f4v acc0 = {0.f, 0.f, 0.f, 0.f};
    f4v acc1 = {0.f, 0.f, 0.f, 0.f};
    f4v acc2 = {0.f, 0.f, 0.f, 0.f};
    f4v acc3 = {0.f, 0.f, 0.f, 0.f};

#pragma unroll
    for (int ch = 0; ch < NCH; ++ch) {
        const ushort* sp = (ch == 0) ? s0 : (ch == 1) ? s1 : (ch == 2) ? s2 : s3;
        int st = (ch == 0) ? st0 : (ch == 1) ? st1 : (ch == 2) ? st2 : st3;
        s8v a = *(const s8v*)(sp + (size_t)arow * st + quad * 8);
        const ushort* wb = Wt + ch * 32 + quad * 8;
        s8v b0 = *(const s8v*)(wb + (size_t)(0 * 16 + n) * Kstride);
        s8v b1 = *(const s8v*)(wb + (size_t)(1 * 16 + n) * Kstride);
        s8v b2 = *(const s8v*)(wb + (size_t)(2 * 16 + n) * Kstride);
        s8v b3 = *(const s8v*)(wb + (size_t)(3 * 16 + n) * Kstride);
        acc0 = __builtin_amdgcn_mfma_f32_16x16x32_bf16(a, b0, acc0, 0, 0, 0);
        acc1 = __builtin_amdgcn_mfma_f32_16x16x32_bf16(a, b1, acc1, 0, 0, 0);
        acc2 = __builtin_amdgcn_mfma_f32_16x16x32_bf16(a, b2, acc2, 0, 0, 0);
        acc3 = __builtin_amdgcn_mfma_f32_16x16x32_bf16(a, b3, acc3, 0, 0, 0);
    }
    // C/D layout: col = lane&15, row = quad*4 + reg
#pragma unroll
    for (int r = 0; r < 4; ++r) {
        int orow = rowbase + quad * 4 + r;
        f16* zp = z + (size_t)orow * 64 + n;
        if (INIT) {
            zp[0]  = (f16)(bias[n]      + acc0[r]);
            zp[16] = (f16)(bias[16 + n] + acc1[r]);
            zp[32] = (f16)(bias[32 + n] + acc2[r]);
            zp[48] = (f16)(bias[48 + n] + acc3[r]);
        } else {
            zp[0]  = (f16)((float)zp[0]  + acc0[r]);
            zp[16] = (f16)((float)zp[16] + acc1[r]);
            zp[32] = (f16)((float)zp[32] + acc2[r]);
            zp[48] = (f16)((float)zp[48] + acc3[r]);
        }
    }
}

// ---------------- BN / pool / MLP ----------------

__global__ void bn_stats_kernel(const f16* __restrict__ z, double* __restrict__ stats) {
    __shared__ double s1[256], s2[256];
    int tid = threadIdx.x;
    const long long total = (long long)N_SIMP * HDIM;
    double sum = 0.0, sq = 0.0;
    for (long long idx = (long long)blockIdx.x * 256 + tid; idx < total;
         idx += (long long)gridDim.x * 256) {
        float v = (float)z[idx];
        sum += v;
        sq += (double)v * v;
    }
    s1[tid] = sum; s2[tid] = sq;
    __syncthreads();
    if (tid < 64) {
        double a = s1[tid] + s1[tid + 64] + s1[tid + 128] + s1[tid + 192];
        double b = s2[tid] + s2[tid + 64] + s2[tid + 128] + s2[tid + 192];
        atomicAdd(&stats[tid], a);
        atomicAdd(&stats[64 + tid], b);
    }
}

// layer-0: h0bf = bf16(elu(bn(z)))
__global__ void bn_elu_bf16_kernel(const f16* __restrict__ z, const double* __restrict__ stats,
                                   const float* __restrict__ gamma, const float* __restrict__ beta,
                                   bf16* __restrict__ out) {
    __shared__ float scale_s[64], shift_s[64];
    int tid = threadIdx.x;
    if (tid < 64) {
        double mean = stats[tid] / (double)N_SIMP;
        double var = stats[64 + tid] / (double)N_SIMP - mean * mean;
        double sc = (double)gamma[tid] / sqrt(var + BN_EPS);
        scale_s[tid] = (float)sc;
        shift_s[tid] = (float)((double)beta[tid] - mean * sc);
    }
    __syncthreads();
    const long long total = (long long)N_SIMP * HDIM;
    for (long long idx = (long long)blockIdx.x * 256 + tid; idx < total;
         idx += (long long)gridDim.x * 256) {
        int h = (int)(idx & 63);
        out[idx] = (bf16)elu_f((float)z[idx] * scale_s[h] + shift_s[h]);
    }
}

// layer-1: z = elu(bn(z)) in place (fp16)
__global__ void bn_elu_f16_kernel(f16* __restrict__ z, const double* __restrict__ stats,
                                  const float* __restrict__ gamma, const float* __restrict__ beta) {
    __shared__ float scale_s[64], shift_s[64];
    int tid = threadIdx.x;
    if (tid < 64) {
        double mean = stats[tid] / (double)N_SIMP;
        double var = stats[64 + tid] / (double)N_SIMP - mean * mean;
        double sc = (double)gamma[tid] / sqrt(var + BN_EPS);
        scale_s[tid] = (float)sc;
        shift_s[tid] = (float)((double)beta[tid] - mean * sc);
    }
    __syncthreads();
    const long long total = (long long)N_SIMP * HDIM;
    for (long long idx = (long long)blockIdx.x * 256 + tid; idx < total;
         idx += (long long)gridDim.x * 256) {
        int h = (int)(idx & 63);
        z[idx] = (f16)elu_f((float)z[idx] * scale_s[h] + shift_s[h]);
    }
}

__global__ void pool_kernel(const f16* __restrict__ hbuf, const int* __restrict__ bidx,
                            float* __restrict__ gbuf) {
    __shared__ float smax[256], ssum[256];
    int g = blockIdx.x;
    int tid = threadIdx.x;
    int lo = 0, hi = N_SIMP;
    while (lo < hi) { int mid = (lo + hi) >> 1; if (bidx[mid] < g) lo = mid + 1; else hi = mid; }
    int start = lo;
    hi = N_SIMP;
    while (lo < hi) { int mid = (lo + hi) >> 1; if (bidx[mid] < g + 1) lo = mid + 1; else hi = mid; }
    int end = lo;
    int h = tid & 63, rep = tid >> 6;
    float mx = -INFINITY, sm = 0.f;
    for (int i = start + rep; i < end; i += 4) {
        float v = (float)hbuf[(size_t)i * HDIM + h];
        mx = fmaxf(mx, v);
        sm += v;
    }
    smax[tid] = mx; ssum[tid] = sm;
    __syncthreads();
    if (tid < 64) {
        float m = fmaxf(fmaxf(smax[tid], smax[tid + 64]), fmaxf(smax[tid + 128], smax[tid + 192]));
        float s = ssum[tid] + ssum[tid + 64] + ssum[tid + 128] + ssum[tid + 192];
        int cnt = end - start;
        float mean = s / fmaxf((float)cnt, 1.f);
        gbuf[g * 128 + tid] = elu_f(m);
        gbuf[g * 128 + 64 + tid] = elu_f(mean);
    }
}

__global__ void mlp_kernel(const float* __restrict__ gbuf, const float* __restrict__ W1,
                           const float* __restrict__ b1, const float* __restrict__ W2,
                           const float* __restrict__ b2, float* __restrict__ out) {
    __shared__ float gs[128];
    __shared__ float hs[64];
    int g = blockIdx.x, tid = threadIdx.x;
    gs[tid] = gbuf[g * 128 + tid];
    gs[64 + tid] = gbuf[g * 128 + 64 + tid];
    __syncthreads();
    float acc = b1[tid];
#pragma unroll
    for (int k = 0; k < 128; ++k) acc += gs[k] * W1[k * 64 + tid];
    hs[tid] = fmaxf(acc, 0.f);
    __syncthreads();
    if (tid < 8) {
        float o = b2[tid];
#pragma unroll
        for (int k = 0; k < 64; ++k) o += hs[k] * W2[k * 8 + tid];
        out[g * 8 + tid] = o;
    }
}

// ---------------- host side ----------------

extern "C" void kernel_launch(void* const* d_in, const int* in_sizes, int n_in,
                              void* d_out, int out_size, void* d_ws, size_t ws_size,
                              hipStream_t stream) {
    const float* x     = (const float*)d_in[0];
    const int*   li    = (const int*)d_in[1];
    const float* lv    = (const float*)d_in[2];
    const int*   ui    = (const int*)d_in[3];
    const float* uv    = (const float*)d_in[4];
    const int*   bidx  = (const int*)d_in[5];
    const float* l0_Wl = (const float*)d_in[6];
    const float* l0_bl = (const float*)d_in[7];
    const float* l0_Wu = (const float*)d_in[8];
    const float* l0_bu = (const float*)d_in[9];
    const float* l0_Wh = (const float*)d_in[10];
    const float* l0_bh = (const float*)d_in[11];
    const float* l1_Wl = (const float*)d_in[12];
    const float* l1_bl = (const float*)d_in[13];
    const float* l1_Wu = (const float*)d_in[14];
    const float* l1_bu = (const float*)d_in[15];
    const float* l1_Wh = (const float*)d_in[16];
    const float* l1_bh = (const float*)d_in[17];
    const float* bn0_g = (const float*)d_in[18];
    const float* bn0_b = (const float*)d_in[19];
    const float* bn1_g = (const float*)d_in[20];
    const float* bn1_b = (const float*)d_in[21];
    const float* mW1   = (const float*)d_in[22];
    const float* mb1   = (const float*)d_in[23];
    const float* mW2   = (const float*)d_in[24];
    const float* mb2   = (const float*)d_in[25];
    float* out = (float*)d_out;

    // ---- workspace layout (total ~246.8 MB <= 256 MiB) ----
    char* base = (char*)d_ws;
    f16*   z     = (f16*)base;                                    //  51,200,000
    bf16*  h0bf  = (bf16*)(base + 51200000ull);                   //  51,200,000
    bf16*  g1    = (bf16*)(base + 102400000ull);                  //  51,200,000
    bf16*  g2    = (bf16*)(base + 153600000ull);                  //  51,200,000
    int2*  edgeL = (int2*)(base + 204800000ull);                  //  19,200,000
    int2*  edgeU = (int2*)(base + 224000000ull);                  //  19,200,000
    int*   rpL   = (int*)(base + 243200000ull);                   //   1,600,032
    int*   rpU   = (int*)(base + 244800032ull);                   //   1,600,032
    double* stats = (double*)(base + 246404160ull);               //   1 KB
    float* cbias  = (float*)(base + 246405184ull);                //   256 B
    float* gbuf   = (float*)(base + 246405440ull);                //   262,144
    ushort* wt    = (ushort*)(base + 246667584ull);               //   86,016

    // CSR-build scratch aliases (dead regions during build):
    //  z region   : coarse 38.4 MB + basev 3.1 KB
    //  h0bf region: per-block counts 916 KB
    int2* coarse = (int2*)base;                                   // 38,400,000
    int*  basev  = (int*)(base + 38400000ull);                    // (NDIG+1)*4
    int*  ccnt   = (int*)(base + 51200000ull);                    // P1_BLOCKS*NDIG*4

    // layer-0 scratch: 4 slots of N*32 bf16 inside g1/g2
    bf16* xbf = g1;
    bf16* cA  = g1 + (size_t)N_SIMP * 32;
    bf16* cB  = g2;
    bf16* cC  = g2 + (size_t)N_SIMP * 32;

    // weight-transpose sub-buffers (ushort elements; offsets match wtrans_all_kernel)
    ushort* wt_l0h = wt;            // 64 x 32
    ushort* wt_l1h = wt + 2048;     // 64 x 64
    ushort* wt_l0l = wt + 6144;     // 64 x 96
    ushort* wt_l0u = wt + 12288;    // 64 x 96
    ushort* wt_l1l = wt + 18432;    // 64 x 192
    ushort* wt_l1u = wt + 30720;    // 64 x 192

    const int SP32_BLOCKS = N_SIMP / 64;   // 6,250
    const int SP64_BLOCKS = N_SIMP / 32;   // 12,500
    const int MF_BLOCKS   = N_SIMP / 64;   // 6,250

    // ---- prep: weight transposes (one dispatch) + x->bf16 ----
    wtrans_all_kernel<<<168, 256, 0, stream>>>(l0_Wh, l1_Wh, l0_Wl, l0_Wu, l1_Wl, l1_Wu, wt);
    f32_to_bf16_kernel<<<N_SIMP * 32 / 256, 256, 0, stream>>>(x, xbf);

    // ---- CSR builds: two-level LDS counting sort (no global atomics) ----
    p1_hist_kernel<<<P1_BLOCKS, P1_T, 0, stream>>>(li, ui, ccnt);
    col_prefix_kernel<<<(NDIG + 255) / 256, 256, 0, stream>>>(ccnt, basev);
    scan_base_kernel<<<1, 1024, 0, stream>>>(basev);
    p1_scatter_kernel<<<P1_BLOCKS, P1_T, 0, stream>>>(li, lv, ui, uv, ccnt, basev, coarse);
    p2_build_kernel<<<NDIG, P2_T, 0, stream>>>(coarse, basev, rpL, rpU, edgeL, edgeU);

    const ushort* xbfu = (const ushort*)xbf;
    const ushort* h0u  = (const ushort*)h0bf;
    const ushort* g1u  = (const ushort*)g1;
    const ushort* g2u  = (const ushort*)g2;

    // ---------------- layer 0 (F_IN=32 -> H=64), 32-wide chains ----------------
    combine_bias_kernel<<<1, 64, 0, stream>>>(l0_bh, l0_bl, l0_bu, cbias);
    mfma_gemm_kernel<1, true><<<MF_BLOCKS, 256, 0, stream>>>(
        xbfu, 32, nullptr, 0, nullptr, 0, nullptr, 0, wt_l0h, 32, cbias, z);

    // lower chain
    spmm32_kernel<<<SP32_BLOCKS, 256, 0, stream>>>(rpL, edgeL, xbf, 32, cA);
    spmm32_kernel<<<SP32_BLOCKS, 256, 0, stream>>>(rpL, edgeL, cA, 32, cB);
    spmm32_kernel<<<SP32_BLOCKS, 256, 0, stream>>>(rpL, edgeL, cB, 32, cC);
    mfma_gemm_kernel<3, false><<<MF_BLOCKS, 256, 0, stream>>>(
        (const ushort*)cA, 32, (const ushort*)cB, 32, (const ushort*)cC, 32,
        nullptr, 0, wt_l0l, 96, nullptr, z);
    // upper chain
    spmm32_kernel<<<SP32_BLOCKS, 256, 0, stream>>>(rpU, edgeU, xbf, 32, cA);
    spmm32_kernel<<<SP32_BLOCKS, 256, 0, stream>>>(rpU, edgeU, cA, 32, cB);
    spmm32_kernel<<<SP32_BLOCKS, 256, 0, stream>>>(rpU, edgeU, cB, 32, cC);
    mfma_gemm_kernel<3, false><<<MF_BLOCKS, 256, 0, stream>>>(
        (const ushort*)cA, 32, (const ushort*)cB, 32, (const ushort*)cC, 32,
        nullptr, 0, wt_l0u, 96, nullptr, z);

    (void)hipMemsetAsync(stats, 0, 128 * sizeof(double), stream);
    bn_stats_kernel<<<1024, 256, 0, stream>>>(z, stats);
    bn_elu_bf16_kernel<<<2048, 256, 0, stream>>>(z, stats, bn0_g, bn0_b, h0bf);

    // ---------------- layer 1 (H=64 -> H=64), 64-wide chains ----------------
    combine_bias_kernel<<<1, 64, 0, stream>>>(l1_bh, l1_bl, l1_bu, cbias);
    mfma_gemm_kernel<2, true><<<MF_BLOCKS, 256, 0, stream>>>(
        h0u, 64, h0u + 32, 64, nullptr, 0, nullptr, 0, wt_l1h, 64, cbias, z);

    {
        const int*  rps[2]   = {rpL, rpU};
        const int2* edges[2] = {edgeL, edgeU};
        ushort*     wts[2]   = {wt_l1l, wt_l1u};
        for (int lap = 0; lap < 2; ++lap) {
            spmm64_kernel<<<SP64_BLOCKS, 256, 0, stream>>>(rps[lap], edges[lap], h0bf, g1);
            spmm64_kernel<<<SP64_BLOCKS, 256, 0, stream>>>(rps[lap], edges[lap], g1, g2);
            mfma_gemm_kernel<4, false><<<MF_BLOCKS, 256, 0, stream>>>(
                g1u, 64, g1u + 32, 64, g2u, 64, g2u + 32, 64, wts[lap], 192, nullptr, z);
            spmm64_kernel<<<SP64_BLOCKS, 256, 0, stream>>>(rps[lap], edges[lap], g2, g1);
            mfma_gemm_kernel<2, false><<<MF_BLOCKS, 256, 0, stream>>>(
                g1u, 64, g1u + 32, 64, nullptr, 0, nullptr, 0, wts[lap] + 128, 192, nullptr, z);
        }
    }

    (void)hipMemsetAsync(stats, 0, 128 * sizeof(double), stream);
    bn_stats_kernel<<<1024, 256, 0, stream>>>(z, stats);
    bn_elu_f16_kernel<<<2048, 256, 0, stream>>>(z, stats, bn1_g, bn1_b);

    // ---------------- pool + MLP ----------------
    pool_kernel<<<G_NUM, 256, 0, stream>>>(z, bidx, gbuf);
    mlp_kernel<<<G_NUM, 64, 0, stream>>>(gbuf, mW1, mb1, mW2, mb2, out);
}

// Round 4
// 1437.525 us; speedup vs baseline: 1.3092x; 1.0626x over previous
//
#include <hip/hip_runtime.h>
#include <hip/hip_bf16.h>
#include <math.h>

#define N_SIMP 400000
#define E_NNZ  2400000
#define FIN    32
#define HDIM   64
#define KAPPA  3
#define G_NUM  512
#define NOUT   8
#define BN_EPS 1e-5

// ---- CSR build (two-level LDS counting sort, block-window scatter) ----
#define NDIG_HALF 391             // ceil(400000/1024) coarse buckets per matrix
#define NDIG      782             // L + U
#define P1_EDGES  16384           // edges per pass-1 block (16/thread @ 1024 thr)
#define P1_BLOCKS 293             // ceil(4.8M / 16384)
#define P1_T      1024
#define P2_CAP    7168            // bucket capacity (avg 6144, +13 sigma headroom)
#define P2_T      512
#define P2_ITERS  14              // P2_CAP / P2_T

typedef __hip_bfloat16 bf16;
typedef _Float16 f16;
typedef short s8v __attribute__((ext_vector_type(8)));    // 8 bf16 in 4 VGPRs
typedef ushort u8v __attribute__((ext_vector_type(8)));   // 8 bf16 raw
typedef _Float16 h8v __attribute__((ext_vector_type(8))); // 8 f16
typedef float f4v __attribute__((ext_vector_type(4)));

__device__ __forceinline__ float elu_f(float x) {
    return x > 0.f ? x : expm1f(x);
}
__device__ __forceinline__ float bf2f(ushort u) {
    return __uint_as_float(((unsigned int)u) << 16);
}
__device__ __forceinline__ ushort f2bf(float f) {
    bf16 h = (bf16)f;
    return *(ushort*)&h;
}

// ---------------- CSR build: pass 1 ----------------

__global__ __launch_bounds__(P1_T) void p1_hist_kernel(const int* __restrict__ eiL,
                                                       const int* __restrict__ eiU,
                                                       int* __restrict__ cnt) {
    __shared__ int h[NDIG];
    int t = threadIdx.x;
    for (int j = t; j < NDIG; j += P1_T) h[j] = 0;
    __syncthreads();
    int base_i = blockIdx.x * P1_EDGES;
#pragma unroll 4
    for (int k = 0; k < P1_EDGES / P1_T; ++k) {
        int i = base_i + k * P1_T + t;
        if (i < 2 * E_NNZ) {
            int dd;
            if (i < E_NNZ) dd = eiL[i] >> 10;
            else           dd = NDIG_HALF + (eiU[i - E_NNZ] >> 10);
            atomicAdd(&h[dd], 1);
        }
    }
    __syncthreads();
    for (int j = t; j < NDIG; j += P1_T) cnt[blockIdx.x * NDIG + j] = h[j];
}

// per-block exclusive prefix over digits: bofs[b][d] = sum_{d'<d} cnt[b][d']
__global__ void bofs_kernel(const int* __restrict__ cnt, int* __restrict__ bofs) {
    __shared__ int sdata[256];
    int t = threadIdx.x;
    const int* src = cnt + blockIdx.x * NDIG;
    int* dst = bofs + blockIdx.x * NDIG;
    int base = t * 4;
    int v0 = (base + 0 < NDIG) ? src[base + 0] : 0;
    int v1 = (base + 1 < NDIG) ? src[base + 1] : 0;
    int v2 = (base + 2 < NDIG) ? src[base + 2] : 0;
    int v3 = (base + 3 < NDIG) ? src[base + 3] : 0;
    int tsum = v0 + v1 + v2 + v3;
    sdata[t] = tsum;
    __syncthreads();
    for (int off = 1; off < 256; off <<= 1) {
        int x = (t >= off) ? sdata[t - off] : 0;
        __syncthreads();
        sdata[t] += x;
        __syncthreads();
    }
    int run = sdata[t] - tsum;
    if (base + 0 < NDIG) { dst[base + 0] = run; } run += v0;
    if (base + 1 < NDIG) { dst[base + 1] = run; } run += v1;
    if (base + 2 < NDIG) { dst[base + 2] = run; } run += v2;
    if (base + 3 < NDIG) { dst[base + 3] = run; }
}

// per-digit totals over blocks
__global__ void digit_total_kernel(const int* __restrict__ cnt, int* __restrict__ tot) {
    int d = blockIdx.x * 256 + threadIdx.x;
    if (d >= NDIG) return;
    int run = 0;
    for (int b = 0; b < P1_BLOCKS; ++b) run += cnt[b * NDIG + d];
    tot[d] = run;
}

// exclusive scan of tot[NDIG] in place (becomes digit global base)
__global__ __launch_bounds__(1024) void scan_base_kernel(int* __restrict__ tot) {
    __shared__ int s[1024];
    int t = threadIdx.x;
    int v = (t < NDIG) ? tot[t] : 0;
    s[t] = v;
    __syncthreads();
    for (int off = 1; off < 1024; off <<= 1) {
        int x = (t >= off) ? s[t - off] : 0;
        __syncthreads();
        s[t] += x;
        __syncthreads();
    }
    if (t < NDIG) tot[t] = s[t] - v;
    if (t == 1023) tot[NDIG] = s[1023];   // = 2*E_NNZ
}

// scatter records digit-grouped WITHIN the block's own 128KB window:
// pos = b*P1_EDGES + bofs[b][d] + rank  -> L2 write-combines the window
__global__ __launch_bounds__(P1_T) void p1_scatter_kernel(
        const int* __restrict__ eiL, const float* __restrict__ lv,
        const int* __restrict__ eiU, const float* __restrict__ uv,
        const int* __restrict__ bofsv, int2* __restrict__ coarse) {
    __shared__ int h[NDIG];
    int t = threadIdx.x;
    int bbase = blockIdx.x * NDIG;
    for (int j = t; j < NDIG; j += P1_T) h[j] = bofsv[bbase + j];
    __syncthreads();
    int base_i = blockIdx.x * P1_EDGES;
    int wbase = blockIdx.x * P1_EDGES;
#pragma unroll 4
    for (int k = 0; k < P1_EDGES / P1_T; ++k) {
        int i = base_i + k * P1_T + t;
        if (i < 2 * E_NNZ) {
            int row, col, dd;
            float val;
            if (i < E_NNZ) {
                row = eiL[i]; col = eiL[E_NNZ + i]; val = lv[i];
                dd = row >> 10;
            } else {
                int e = i - E_NNZ;
                row = eiU[e]; col = eiU[E_NNZ + e]; val = uv[e];
                dd = NDIG_HALF + (row >> 10);
            }
            int pos = wbase + atomicAdd(&h[dd], 1);
            coarse[pos] = make_int2(((row & 1023) << 22) | col, __float_as_int(val));
        }
    }
}

// ---------------- CSR build: pass 2 (fragment gather + LDS counting sort) -------

__global__ __launch_bounds__(P2_T) void p2_build_kernel(
        const int2* __restrict__ coarse, const int* __restrict__ ccnt,
        const int* __restrict__ bofsv, const int* __restrict__ basev,
        int* __restrict__ rpL, int* __restrict__ rpU,
        int2* __restrict__ edgeL, int2* __restrict__ edgeU) {
    __shared__ int pk[P2_CAP];
    __shared__ int vl[P2_CAP];
    __shared__ int hist[1024];
    __shared__ int sc[P2_T];
    __shared__ int fo[P1_BLOCKS];
    __shared__ int stot;
    int d = blockIdx.x;
    int t = threadIdx.x;
    // fragment table: len/ofs per pass-1 block
    int len = 0, ofs = 0;
    if (t < P1_BLOCKS) { len = ccnt[t * NDIG + d]; ofs = bofsv[t * NDIG + d]; }
    sc[t] = len;
    __syncthreads();
    for (int off = 1; off < P2_T; off <<= 1) {
        int x = (t >= off) ? sc[t - off] : 0;
        __syncthreads();
        sc[t] += x;
        __syncthreads();
    }
    if (t < P1_BLOCKS) { fo[t] = sc[t] - len; hist[t] = len; hist[512 + t] = ofs; }
    if (t == P1_BLOCKS - 1) stot = sc[t];
    __syncthreads();
    int sz = stot;
    if (sz > P2_CAP) sz = P2_CAP;   // never expected
    // cooperative fragment copy: wave w handles fragments b = w, w+8, ...
    int wv = t >> 6, lane = t & 63;
    for (int b = wv; b < P1_BLOCKS; b += P2_T / 64) {
        int L = hist[b], O = hist[512 + b], F = fo[b];
        const int2* sp = coarse + (size_t)b * P1_EDGES + O;
        for (int j = lane; j < L; j += 64) {
            int dst2 = F + j;
            if (dst2 < P2_CAP) {
                int2 r = sp[j];
                pk[dst2] = r.x;
                vl[dst2] = r.y;
            }
        }
    }
    __syncthreads();
    hist[t] = 0;
    hist[t + P2_T] = 0;
    __syncthreads();
    int myrank[P2_ITERS];
#pragma unroll
    for (int k = 0; k < P2_ITERS; ++k) {
        int j = k * P2_T + t;
        myrank[k] = (j < sz) ? atomicAdd(&hist[((unsigned)pk[j]) >> 22], 1) : 0;
    }
    __syncthreads();
    int h0 = hist[2 * t], h1 = hist[2 * t + 1];
    sc[t] = h0 + h1;
    __syncthreads();
    for (int off = 1; off < P2_T; off <<= 1) {
        int x = (t >= off) ? sc[t - off] : 0;
        __syncthreads();
        sc[t] += x;
        __syncthreads();
    }
    int pbase = sc[t] - (h0 + h1);   // exclusive prefix of bin pair
    __syncthreads();
    hist[2 * t] = pbase;
    hist[2 * t + 1] = pbase + h0;
    // rp write (2 rows per thread)
    int which = (d >= NDIG_HALF);
    int lbase = basev[d] - (which ? E_NNZ : 0);
    int rowbase = (which ? d - NDIG_HALF : d) << 10;
    int* rp = which ? rpU : rpL;
    int r0 = rowbase + 2 * t, r1 = r0 + 1;
    if (r0 < N_SIMP) rp[r0] = lbase + pbase;
    if (r1 < N_SIMP) rp[r1] = lbase + pbase + h0;
    __syncthreads();
    int2* eout = which ? edgeU : edgeL;
#pragma unroll
    for (int k = 0; k < P2_ITERS; ++k) {
        int j = k * P2_T + t;
        if (j < sz) {
            unsigned p = (unsigned)pk[j];
            int pos = lbase + hist[p >> 22] + myrank[k];
            eout[pos] = make_int2((int)(p & 0x3FFFFF), vl[j]);
        }
    }
}

// ---------------- small prep kernels ----------------

__global__ void combine_bias_kernel(const float* __restrict__ bh,
                                    const float* __restrict__ bl,
                                    const float* __restrict__ bu,
                                    float* __restrict__ out) {
    int h = threadIdx.x;
    float acc = bh[h];
    for (int k = 0; k < KAPPA; ++k) acc += bl[k * HDIM + h] + bu[k * HDIM + h];
    out[h] = acc;
}

__global__ void f32_to_bf16_kernel(const float* __restrict__ in, bf16* __restrict__ out) {
    int idx = blockIdx.x * 256 + threadIdx.x;   // per float4
    float4 v = ((const float4*)in)[idx];
    ushort4 w;
    w.x = f2bf(v.x); w.y = f2bf(v.y); w.z = f2bf(v.z); w.w = f2bf(v.w);
    ((ushort4*)out)[idx] = w;
}

// all 6 weight transposes in one dispatch; wt layout fixed (offsets in ushorts)
__global__ void wtrans_all_kernel(const float* __restrict__ s0, const float* __restrict__ s1,
                                  const float* __restrict__ s2, const float* __restrict__ s3,
                                  const float* __restrict__ s4, const float* __restrict__ s5,
                                  ushort* __restrict__ wt) {
    int idx = blockIdx.x * 256 + threadIdx.x;   // 0..43007
    const float* src; int Ktot, off;
    if (idx < 2048)       { src = s0; Ktot = 32;  off = 0; }
    else if (idx < 6144)  { src = s1; Ktot = 64;  off = 2048; }
    else if (idx < 12288) { src = s2; Ktot = 96;  off = 6144; }
    else if (idx < 18432) { src = s3; Ktot = 96;  off = 12288; }
    else if (idx < 30720) { src = s4; Ktot = 192; off = 18432; }
    else                  { src = s5; Ktot = 192; off = 30720; }
    int rel = idx - off;
    int n = rel / Ktot, kk = rel - n * Ktot;
    wt[idx] = f2bf(src[kk * 64 + n]);
}

// ---------------- SpMM (CSR gather) --------
// rp holds EXCLUSIVE row starts: s = rp[row], e = rp[row+1] (guarded at N-1)

// 32-wide: 4 lanes/row (8 ch each), 16 rows/wave, 64 rows/block
__global__ void spmm32_kernel(const int* __restrict__ rp, const int2* __restrict__ edge,
                              const bf16* __restrict__ srcb, int src_stride,
                              bf16* __restrict__ dstb) {
    const ushort* src = (const ushort*)srcb;
    ushort* dst = (ushort*)dstb;
    int tid = threadIdx.x;
    int lane = tid & 63;
    int wv = tid >> 6;
    int grp = lane >> 2;      // 0..15: row within wave
    int li = lane & 3;        // channels li*8 .. li*8+7
    int row = blockIdx.x * 64 + wv * 16 + grp;
    int s = rp[row];
    int e = (row == N_SIMP - 1) ? E_NNZ : rp[row + 1];
    int deg = e - s;
    float a[8] = {0.f, 0.f, 0.f, 0.f, 0.f, 0.f, 0.f, 0.f};
    if (deg > 0) {
        int2 ed[8];
#pragma unroll
        for (int t = 0; t < 8; ++t) {
            int j = s + t;
            ed[t] = edge[(j < e) ? j : (e - 1)];
        }
        u8v xs[8];
#pragma unroll
        for (int t = 0; t < 8; ++t)
            xs[t] = *(const u8v*)(src + (size_t)ed[t].x * src_stride + li * 8);
#pragma unroll
        for (int t = 0; t < 8; ++t) {
            float v = (t < deg) ? __int_as_float(ed[t].y) : 0.f;
#pragma unroll
            for (int c = 0; c < 8; ++c) a[c] += v * bf2f(xs[t][c]);
        }
        for (int j = s + 8; j < e; j += 4) {
            int2 e2[4];
#pragma unroll
            for (int t = 0; t < 4; ++t) {
                int jj = j + t;
                e2[t] = edge[(jj < e) ? jj : (e - 1)];
            }
            u8v x2[4];
#pragma unroll
            for (int t = 0; t < 4; ++t)
                x2[t] = *(const u8v*)(src + (size_t)e2[t].x * src_stride + li * 8);
#pragma unroll
            for (int t = 0; t < 4; ++t) {
                float v = (j + t < e) ? __int_as_float(e2[t].y) : 0.f;
#pragma unroll
                for (int c = 0; c < 8; ++c) a[c] += v * bf2f(x2[t][c]);
            }
        }
    }
    u8v w;
#pragma unroll
    for (int c = 0; c < 8; ++c) w[c] = f2bf(a[c]);
    *(u8v*)(dst + (size_t)row * 32 + li * 8) = w;
}

// 64-wide: 8 lanes/row (8 ch each), 8 rows/wave, 32 rows/block; stride 64
__global__ void spmm64_kernel(const int* __restrict__ rp, const int2* __restrict__ edge,
                              const bf16* __restrict__ srcb, bf16* __restrict__ dstb) {
    const ushort* src = (const ushort*)srcb;
    ushort* dst = (ushort*)dstb;
    int tid = threadIdx.x;
    int lane = tid & 63;
    int wv = tid >> 6;
    int grp = lane >> 3;      // 0..7: row within wave
    int li = lane & 7;        // channels li*8 .. li*8+7
    int row = blockIdx.x * 32 + wv * 8 + grp;
    int s = rp[row];
    int e = (row == N_SIMP - 1) ? E_NNZ : rp[row + 1];
    int deg = e - s;
    float a[8] = {0.f, 0.f, 0.f, 0.f, 0.f, 0.f, 0.f, 0.f};
    if (deg > 0) {
        int2 ed[8];
#pragma unroll
        for (int t = 0; t < 8; ++t) {
            int j = s + t;
            ed[t] = edge[(j < e) ? j : (e - 1)];
        }
        u8v xs[8];
#pragma unroll
        for (int t = 0; t < 8; ++t)
            xs[t] = *(const u8v*)(src + (size_t)ed[t].x * 64 + li * 8);
#pragma unroll
        for (int t = 0; t < 8; ++t) {
            float v = (t < deg) ? __int_as_float(ed[t].y) : 0.f;
#pragma unroll
            for (int c = 0; c < 8; ++c) a[c] += v * bf2f(xs[t][c]);
        }
        for (int j = s + 8; j < e; j += 4) {
            int2 e2[4];
#pragma unroll
            for (int t = 0; t < 4; ++t) {
                int jj = j + t;
                e2[t] = edge[(jj < e) ? jj : (e - 1)];
            }
            u8v x2[4];
#pragma unroll
            for (int t = 0; t < 4; ++t)
                x2[t] = *(const u8v*)(src + (size_t)e2[t].x * 64 + li * 8);
#pragma unroll
            for (int t = 0; t < 4; ++t) {
                float v = (j + t < e) ? __int_as_float(e2[t].y) : 0.f;
#pragma unroll
                for (int c = 0; c < 8; ++c) a[c] += v * bf2f(x2[t][c]);
            }
        }
    }
    u8v w;
#pragma unroll
    for (int c = 0; c < 8; ++c) w[c] = f2bf(a[c]);
    *(u8v*)(dst + (size_t)row * 64 + li * 8) = w;
}

// ---------------- MFMA GEMM: z[N,64] (fp16) (=bias+ / +=) A[N, NCH*32] @ W -------
// up to 6 A-channel sources; W split into two groups (Wt1 for ch<NCH1, Wt2 rest)

template <int NCH, int NCH1, bool INIT>
__global__ __launch_bounds__(256) void mfma_gemm_kernel(
        const ushort* __restrict__ s0, int st0,
        const ushort* __restrict__ s1, int st1,
        const ushort* __restrict__ s2, int st2,
        const ushort* __restrict__ s3, int st3,
        const ushort* __restrict__ s4, int st4,
        const ushort* __restrict__ s5, int st5,
        const ushort* __restrict__ Wt1, int Kstride1,
        const ushort* __restrict__ Wt2, int Kstride2,
        const float* __restrict__ bias,
        f16* __restrict__ z) {
    int tid = threadIdx.x;
    int wv = tid >> 6, lane = tid & 63;
    int quad = lane >> 4, n = lane & 15;
    int rowbase = blockIdx.x * 64 + wv * 16;
    int arow = rowbase + n;  // A-operand row m = lane&15

    f4v acc0 = {0.f, 0.f, 0.f, 0.f};
    f4v acc1 = {0.f, 0.f, 0.f, 0.f};
    f4v acc2 = {0.f, 0.f, 0.f, 0.f};
    f4v acc3 = {0.f, 0.f, 0.f, 0.f};

#pragma unroll
    for (int ch = 0; ch < NCH; ++ch) {
        const ushort* sp = (ch == 0) ? s0 : (ch == 1) ? s1 : (ch == 2) ? s2
                         : (ch == 3) ? s3 : (ch == 4) ? s4 : s5;
        int st = (ch == 0) ? st0 : (ch == 1) ? st1 : (ch == 2) ? st2
               : (ch == 3) ? st3 : (ch == 4) ? st4 : st5;
        const ushort* wb = (ch < NCH1) ? (Wt1 + ch * 32) : (Wt2 + (ch - NCH1) * 32);
        int Ks = (ch < NCH1) ? Kstride1 : Kstride2;
        s8v a = *(const s8v*)(sp + (size_t)arow * st + quad * 8);
        const ushort* wq = wb + quad * 8;
        s8v b0 = *(const s8v*)(wq + (size_t)(0 * 16 + n) * Ks);
        s8v b1 = *(const s8v*)(wq + (size_t)(1 * 16 + n) * Ks);
        s8v b2 = *(const s8v*)(wq + (size_t)(2 * 16 + n) * Ks);
        s8v b3 = *(const s8v*)(wq + (size_t)(3 * 16 + n) * Ks);
        acc0 = __builtin_amdgcn_mfma_f32_16x16x32_bf16(a, b0, acc0, 0, 0, 0);
        acc1 = __builtin_amdgcn_mfma_f32_16x16x32_bf16(a, b1, acc1, 0, 0, 0);
        acc2 = __builtin_amdgcn_mfma_f32_16x16x32_bf16(a, b2, acc2, 0, 0, 0);
        acc3 = __builtin_amdgcn_mfma_f32_16x16x32_bf16(a, b3, acc3, 0, 0, 0);
    }
    // C/D layout: col = lane&15, row = quad*4 + reg
#pragma unroll
    for (int r = 0; r < 4; ++r) {
        int orow = rowbase + quad * 4 + r;
        f16* zp = z + (size_t)orow * 64 + n;
        if (INIT) {
            zp[0]  = (f16)(bias[n]      + acc0[r]);
            zp[16] = (f16)(bias[16 + n] + acc1[r]);
            zp[32] = (f16)(bias[32 + n] + acc2[r]);
            zp[48] = (f16)(bias[48 + n] + acc3[r]);
        } else {
            zp[0]  = (f16)((float)zp[0]  + acc0[r]);
            zp[16] = (f16)((float)zp[16] + acc1[r]);
            zp[32] = (f16)((float)zp[32] + acc2[r]);
            zp[48] = (f16)((float)zp[48] + acc3[r]);
        }
    }
}

// ---------------- BN / pool / MLP (vectorized) ----------------

__global__ void bn_stats_kernel(const f16* __restrict__ z, double* __restrict__ stats) {
    __shared__ float ss[256 * 8], qq[256 * 8];
    int tid = threadIdx.x;
    const h8v* z8 = (const h8v*)z;
    const int total8 = N_SIMP * HDIM / 8;
    float fs[8] = {0, 0, 0, 0, 0, 0, 0, 0};
    float fq[8] = {0, 0, 0, 0, 0, 0, 0, 0};
    for (int i = blockIdx.x * 256 + tid; i < total8; i += (int)gridDim.x * 256) {
        h8v v = z8[i];
#pragma unroll
        for (int c = 0; c < 8; ++c) {
            float f = (float)v[c];
            fs[c] += f;
            fq[c] += f * f;
        }
    }
#pragma unroll
    for (int c = 0; c < 8; ++c) { ss[tid * 8 + c] = fs[c]; qq[tid * 8 + c] = fq[c]; }
    __syncthreads();
    if (tid < 64) {
        // channel tid: contributions from threads t with (t&7)==tid>>3, slot tid&7
        int sel = tid >> 3, slot = tid & 7;
        double a = 0.0, b = 0.0;
#pragma unroll 8
        for (int k = 0; k < 32; ++k) {
            int t = sel + (k << 3);
            a += (double)ss[t * 8 + slot];
            b += (double)qq[t * 8 + slot];
        }
        atomicAdd(&stats[tid], a);
        atomicAdd(&stats[64 + tid], b);
    }
}

// layer-0: h0bf = bf16(elu(bn(z)))
__global__ void bn_elu_bf16_kernel(const f16* __restrict__ z, const double* __restrict__ stats,
                                   const float* __restrict__ gamma, const float* __restrict__ beta,
                                   bf16* __restrict__ out) {
    __shared__ float scale_s[64], shift_s[64];
    int tid = threadIdx.x;
    if (tid < 64) {
        double mean = stats[tid] / (double)N_SIMP;
        double var = stats[64 + tid] / (double)N_SIMP - mean * mean;
        double sc = (double)gamma[tid] / sqrt(var + BN_EPS);
        scale_s[tid] = (float)sc;
        shift_s[tid] = (float)((double)beta[tid] - mean * sc);
    }
    __syncthreads();
    const h8v* z8 = (const h8v*)z;
    u8v* o8 = (u8v*)out;
    const int total8 = N_SIMP * HDIM / 8;
    int hb = (tid & 7) * 8;
    for (int i = blockIdx.x * 256 + tid; i < total8; i += (int)gridDim.x * 256) {
        h8v v = z8[i];
        u8v w;
#pragma unroll
        for (int c = 0; c < 8; ++c)
            w[c] = f2bf(elu_f((float)v[c] * scale_s[hb + c] + shift_s[hb + c]));
        o8[i] = w;
    }
}

// layer-1: z = elu(bn(z)) in place (fp16)
__global__ void bn_elu_f16_kernel(f16* __restrict__ z, const double* __restrict__ stats,
                                  const float* __restrict__ gamma, const float* __restrict__ beta) {
    __shared__ float scale_s[64], shift_s[64];
    int tid = threadIdx.x;
    if (tid < 64) {
        double mean = stats[tid] / (double)N_SIMP;
        double var = stats[64 + tid] / (double)N_SIMP - mean * mean;
        double sc = (double)gamma[tid] / sqrt(var + BN_EPS);
        scale_s[tid] = (float)sc;
        shift_s[tid] = (float)((double)beta[tid] - mean * sc);
    }
    __syncthreads();
    h8v* z8 = (h8v*)z;
    const int total8 = N_SIMP * HDIM / 8;
    int hb = (tid & 7) * 8;
    for (int i = blockIdx.x * 256 + tid; i < total8; i += (int)gridDim.x * 256) {
        h8v v = z8[i];
        h8v w;
#pragma unroll
        for (int c = 0; c < 8; ++c)
            w[c] = (f16)elu_f((float)v[c] * scale_s[hb + c] + shift_s[hb + c]);
        z8[i] = w;
    }
}

__global__ void pool_kernel(const f16* __restrict__ hbuf, const int* __restrict__ bidx,
                            float* __restrict__ gbuf) {
    __shared__ float smax[256], ssum[256];
    int g = blockIdx.x;
    int tid = threadIdx.x;
    int lo = 0, hi = N_SIMP;
    while (lo < hi) { int mid = (lo + hi) >> 1; if (bidx[mid] < g) lo = mid + 1; else hi = mid; }
    int start = lo;
    hi = N_SIMP;
    while (lo < hi) { int mid = (lo + hi) >> 1; if (bidx[mid] < g + 1) lo = mid + 1; else hi = mid; }
    int end = lo;
    int h = tid & 63, rep = tid >> 6;
    float mx = -INFINITY, sm = 0.f;
    for (int i = start + rep; i < end; i += 4) {
        float v = (float)hbuf[(size_t)i * HDIM + h];
        mx = fmaxf(mx, v);
        sm += v;
    }
    smax[tid] = mx; ssum[tid] = sm;
    __syncthreads();
    if (tid < 64) {
        float m = fmaxf(fmaxf(smax[tid], smax[tid + 64]), fmaxf(smax[tid + 128], smax[tid + 192]));
        float s = ssum[tid] + ssum[tid + 64] + ssum[tid + 128] + ssum[tid + 192];
        int cnt = end - start;
        float mean = s / fmaxf((float)cnt, 1.f);
        gbuf[g * 128 + tid] = elu_f(m);
        gbuf[g * 128 + 64 + tid] = elu_f(mean);
    }
}

__global__ void mlp_kernel(const float* __restrict__ gbuf, const float* __restrict__ W1,
                           const float* __restrict__ b1, const float* __restrict__ W2,
                           const float* __restrict__ b2, float* __restrict__ out) {
    __shared__ float gs[128];
    __shared__ float hs[64];
    int g = blockIdx.x, tid = threadIdx.x;
    gs[tid] = gbuf[g * 128 + tid];
    gs[64 + tid] = gbuf[g * 128 + 64 + tid];
    __syncthreads();
    float acc = b1[tid];
#pragma unroll
    for (int k = 0; k < 128; ++k) acc += gs[k] * W1[k * 64 + tid];
    hs[tid] = fmaxf(acc, 0.f);
    __syncthreads();
    if (tid < 8) {
        float o = b2[tid];
#pragma unroll
        for (int k = 0; k < 64; ++k) o += hs[k] * W2[k * 8 + tid];
        out[g * 8 + tid] = o;
    }
}

// ---------------- host side ----------------

extern "C" void kernel_launch(void* const* d_in, const int* in_sizes, int n_in,
                              void* d_out, int out_size, void* d_ws, size_t ws_size,
                              hipStream_t stream) {
    const float* x     = (const float*)d_in[0];
    const int*   li    = (const int*)d_in[1];
    const float* lv    = (const float*)d_in[2];
    const int*   ui    = (const int*)d_in[3];
    const float* uv    = (const float*)d_in[4];
    const int*   bidx  = (const int*)d_in[5];
    const float* l0_Wl = (const float*)d_in[6];
    const float* l0_bl = (const float*)d_in[7];
    const float* l0_Wu = (const float*)d_in[8];
    const float* l0_bu = (const float*)d_in[9];
    const float* l0_Wh = (const float*)d_in[10];
    const float* l0_bh = (const float*)d_in[11];
    const float* l1_Wl = (const float*)d_in[12];
    const float* l1_bl = (const float*)d_in[13];
    const float* l1_Wu = (const float*)d_in[14];
    const float* l1_bu = (const float*)d_in[15];
    const float* l1_Wh = (const float*)d_in[16];
    const float* l1_bh = (const float*)d_in[17];
    const float* bn0_g = (const float*)d_in[18];
    const float* bn0_b = (const float*)d_in[19];
    const float* bn1_g = (const float*)d_in[20];
    const float* bn1_b = (const float*)d_in[21];
    const float* mW1   = (const float*)d_in[22];
    const float* mb1   = (const float*)d_in[23];
    const float* mW2   = (const float*)d_in[24];
    const float* mb2   = (const float*)d_in[25];
    float* out = (float*)d_out;

    // ---- workspace layout (total ~246.8 MB <= 256 MiB) ----
    char* base = (char*)d_ws;
    f16*   z     = (f16*)base;                                    //  51,200,000
    bf16*  h0bf  = (bf16*)(base + 51200000ull);                   //  51,200,000
    bf16*  g1    = (bf16*)(base + 102400000ull);                  //  51,200,000
    bf16*  g2    = (bf16*)(base + 153600000ull);                  //  51,200,000
    int2*  edgeL = (int2*)(base + 204800000ull);                  //  19,200,000
    int2*  edgeU = (int2*)(base + 224000000ull);                  //  19,200,000
    int*   rpL   = (int*)(base + 243200000ull);                   //   1,600,032
    int*   rpU   = (int*)(base + 244800032ull);                   //   1,600,032
    double* stats = (double*)(base + 246404160ull);               //   1 KB
    float* cbias  = (float*)(base + 246405184ull);                //   256 B
    float* gbuf   = (float*)(base + 246405440ull);                //   262,144
    ushort* wt    = (ushort*)(base + 246667584ull);               //   86,016

    // CSR-build scratch aliases (regions dead during build):
    //  z region   : coarse 38.4 MB + basev 3.1 KB
    //  h0bf region: ccnt 916 KB + bofs 916 KB
    int2* coarse = (int2*)base;                                   // 38,404,096
    int*  basev  = (int*)(base + 38500000ull);                    // (NDIG+1)*4
    int*  ccnt   = (int*)(base + 51200000ull);                    // 916,504
    int*  bofsv  = (int*)(base + 52200000ull);                    // 916,504

    // layer-0 scratch: 6 slots of N*32 bf16 in g1/g2/h0bf regions
    bf16* xbf  = g1;                                 // g1 slot 0 (later cCU)
    bf16* cAL  = g1 + (size_t)N_SIMP * 32;           // g1 slot 1
    bf16* cBL  = g2;                                 // g2 slot 0
    bf16* cCL  = g2 + (size_t)N_SIMP * 32;           // g2 slot 1
    bf16* cAU  = h0bf;                               // h0 slot 0
    bf16* cBU  = h0bf + (size_t)N_SIMP * 32;         // h0 slot 1
    bf16* cCU  = g1;                                 // reuses xbf slot (xbf dead)

    // weight-transpose sub-buffers (ushort elements; offsets match wtrans_all_kernel)
    ushort* wt_l0h = wt;            // 64 x 32
    ushort* wt_l1h = wt + 2048;     // 64 x 64
    ushort* wt_l0l = wt + 6144;     // 64 x 96
    ushort* wt_l0u = wt + 12288;    // 64 x 96
    ushort* wt_l1l = wt + 18432;    // 64 x 192
    ushort* wt_l1u = wt + 30720;    // 64 x 192

    const int SP32_BLOCKS = N_SIMP / 64;   // 6,250
    const int SP64_BLOCKS = N_SIMP / 32;   // 12,500
    const int MF_BLOCKS   = N_SIMP / 64;   // 6,250

    // ---- prep: weight transposes (one dispatch) + x->bf16 ----
    wtrans_all_kernel<<<168, 256, 0, stream>>>(l0_Wh, l1_Wh, l0_Wl, l0_Wu, l1_Wl, l1_Wu, wt);
    f32_to_bf16_kernel<<<N_SIMP * 32 / 4 / 256, 256, 0, stream>>>(x, xbf);

    // ---- CSR builds: block-window scatter + fragment-gather sort ----
    p1_hist_kernel<<<P1_BLOCKS, P1_T, 0, stream>>>(li, ui, ccnt);
    bofs_kernel<<<P1_BLOCKS, 256, 0, stream>>>(ccnt, bofsv);
    digit_total_kernel<<<(NDIG + 255) / 256, 256, 0, stream>>>(ccnt, basev);
    scan_base_kernel<<<1, 1024, 0, stream>>>(basev);
    p1_scatter_kernel<<<P1_BLOCKS, P1_T, 0, stream>>>(li, lv, ui, uv, bofsv, coarse);
    p2_build_kernel<<<NDIG, P2_T, 0, stream>>>(coarse, ccnt, bofsv, basev,
                                               rpL, rpU, edgeL, edgeU);

    const ushort* xbfu = (const ushort*)xbf;
    const ushort* h0u  = (const ushort*)h0bf;
    const ushort* g1u  = (const ushort*)g1;
    const ushort* g2u  = (const ushort*)g2;

    // ---------------- layer 0 (F_IN=32 -> H=64) ----------------
    combine_bias_kernel<<<1, 64, 0, stream>>>(l0_bh, l0_bl, l0_bu, cbias);
    mfma_gemm_kernel<1, 1, true><<<MF_BLOCKS, 256, 0, stream>>>(
        xbfu, 32, nullptr, 0, nullptr, 0, nullptr, 0, nullptr, 0, nullptr, 0,
        wt_l0h, 32, wt_l0h, 32, cbias, z);

    // lower chain
    spmm32_kernel<<<SP32_BLOCKS, 256, 0, stream>>>(rpL, edgeL, xbf, 32, cAL);
    spmm32_kernel<<<SP32_BLOCKS, 256, 0, stream>>>(rpL, edgeL, cAL, 32, cBL);
    spmm32_kernel<<<SP32_BLOCKS, 256, 0, stream>>>(rpL, edgeL, cBL, 32, cCL);
    // upper chain (cAU spmm reads xbf before cCU overwrites that slot)
    spmm32_kernel<<<SP32_BLOCKS, 256, 0, stream>>>(rpU, edgeU, xbf, 32, cAU);
    spmm32_kernel<<<SP32_BLOCKS, 256, 0, stream>>>(rpU, edgeU, cAU, 32, cBU);
    spmm32_kernel<<<SP32_BLOCKS, 256, 0, stream>>>(rpU, edgeU, cBU, 32, cCU);
    // single accumulate-GEMM over all 6 chain outputs
    mfma_gemm_kernel<6, 3, false><<<MF_BLOCKS, 256, 0, stream>>>(
        (const ushort*)cAL, 32, (const ushort*)cBL, 32, (const ushort*)cCL, 32,
        (const ushort*)cAU, 32, (const ushort*)cBU, 32, (const ushort*)cCU, 32,
        wt_l0l, 96, wt_l0u, 96, nullptr, z);

    (void)hipMemsetAsync(stats, 0, 128 * sizeof(double), stream);
    bn_stats_kernel<<<1024, 256, 0, stream>>>(z, stats);
    bn_elu_bf16_kernel<<<1024, 256, 0, stream>>>(z, stats, bn0_g, bn0_b, h0bf);

    // ---------------- layer 1 (H=64 -> H=64), 64-wide chains ----------------
    combine_bias_kernel<<<1, 64, 0, stream>>>(l1_bh, l1_bl, l1_bu, cbias);
    mfma_gemm_kernel<2, 2, true><<<MF_BLOCKS, 256, 0, stream>>>(
        h0u, 64, h0u + 32, 64, nullptr, 0, nullptr, 0, nullptr, 0, nullptr, 0,
        wt_l1h, 64, wt_l1h, 64, cbias, z);

    // u1 = L h0 -> g1 ; u2 = L u1 -> g2
    spmm64_kernel<<<SP64_BLOCKS, 256, 0, stream>>>(rpL, edgeL, h0bf, g1);
    spmm64_kernel<<<SP64_BLOCKS, 256, 0, stream>>>(rpL, edgeL, g1, g2);
    // gemm A: u1 (K 0-63), u2 (K 64-127) of wt_l1l
    mfma_gemm_kernel<4, 4, false><<<MF_BLOCKS, 256, 0, stream>>>(
        g1u, 64, g1u + 32, 64, g2u, 64, g2u + 32, 64, nullptr, 0, nullptr, 0,
        wt_l1l, 192, wt_l1l, 192, nullptr, z);
    // u3 = L u2 -> g1 ; v1 = U h0 -> g2
    spmm64_kernel<<<SP64_BLOCKS, 256, 0, stream>>>(rpL, edgeL, g2, g1);
    spmm64_kernel<<<SP64_BLOCKS, 256, 0, stream>>>(rpU, edgeU, h0bf, g2);
    // gemm B: u3 (wt_l1l K 128-191), v1 (wt_l1u K 0-63)
    mfma_gemm_kernel<4, 2, false><<<MF_BLOCKS, 256, 0, stream>>>(
        g1u, 64, g1u + 32, 64, g2u, 64, g2u + 32, 64, nullptr, 0, nullptr, 0,
        wt_l1l + 128, 192, wt_l1u, 192, nullptr, z);
    // v2 = U v1 -> g1 ; v3 = U v2 -> g2
    spmm64_kernel<<<SP64_BLOCKS, 256, 0, stream>>>(rpU, edgeU, g2, g1);
    spmm64_kernel<<<SP64_BLOCKS, 256, 0, stream>>>(rpU, edgeU, g1, g2);
    // gemm C: v2 (K 64-127), v3 (K 128-191) of wt_l1u
    mfma_gemm_kernel<4, 4, false><<<MF_BLOCKS, 256, 0, stream>>>(
        g1u, 64, g1u + 32, 64, g2u, 64, g2u + 32, 64, nullptr, 0, nullptr, 0,
        wt_l1u + 64, 192, wt_l1u + 64, 192, nullptr, z);

    (void)hipMemsetAsync(stats, 0, 128 * sizeof(double), stream);
    bn_stats_kernel<<<1024, 256, 0, stream>>>(z, stats);
    bn_elu_f16_kernel<<<1024, 256, 0, stream>>>(z, stats, bn1_g, bn1_b);

    // ---------------- pool + MLP ----------------
    pool_kernel<<<G_NUM, 256, 0, stream>>>(z, bidx, gbuf);
    mlp_kernel<<<G_NUM, 64, 0, stream>>>(gbuf, mW1, mb1, mW2, mb2, out);
}

// Round 5
// 1391.290 us; speedup vs baseline: 1.3527x; 1.0332x over previous
//
#include <hip/hip_runtime.h>
#include <hip/hip_bf16.h>
#include <math.h>

#define N_SIMP 400000
#define E_NNZ  2400000
#define FIN    32
#define HDIM   64
#define KAPPA  3
#define G_NUM  512
#define NOUT   8
#define BN_EPS 1e-5

// ---- CSR build (two-level LDS counting sort; pass-1 sorts fully in LDS) ----
#define NDIG_HALF 391             // ceil(400000/1024) coarse buckets per matrix
#define NDIG      782             // L + U
#define P1_EDGES  16384           // edges per pass-1 block (16/thread @ 1024 thr)
#define P1_BLOCKS 293             // ceil(4.8M / 16384)
#define P1_T      1024
#define P1_EPT    16
#define P2_CAP    7168            // bucket capacity (avg 6144, +13 sigma headroom)
#define P2_T      512
#define P2_ITERS  14              // P2_CAP / P2_T

typedef __hip_bfloat16 bf16;
typedef _Float16 f16;
typedef short s8v __attribute__((ext_vector_type(8)));    // 8 bf16 in 4 VGPRs
typedef ushort u8v __attribute__((ext_vector_type(8)));   // 8 bf16 raw
typedef _Float16 h8v __attribute__((ext_vector_type(8))); // 8 f16
typedef float f4v __attribute__((ext_vector_type(4)));

__device__ __forceinline__ float elu_f(float x) {
    return x > 0.f ? x : expm1f(x);
}
__device__ __forceinline__ float bf2f(ushort u) {
    return __uint_as_float(((unsigned int)u) << 16);
}
__device__ __forceinline__ ushort f2bf(float f) {
    bf16 h = (bf16)f;
    return *(ushort*)&h;
}

// ---------------- CSR build: pass 1 (full in-LDS counting sort per block) -------
// Replaces p1_hist + bofs + p1_scatter. Output: coarse window (contiguous,
// digit-sorted -> full-line streaming writes), ccnt[b][d], bofs[b][d].

__global__ __launch_bounds__(P1_T, 1) void p1_sort_kernel(
        const int* __restrict__ eiL, const float* __restrict__ lv,
        const int* __restrict__ eiU, const float* __restrict__ uv,
        int* __restrict__ ccnt, int* __restrict__ bofsv,
        int2* __restrict__ coarse) {
    __shared__ int2 rec[P1_EDGES];   // 128 KB
    __shared__ int h[NDIG];          // counts -> running offsets
    __shared__ int hscan[P1_T];      // scan scratch
    int t = threadIdx.x;
    for (int j = t; j < NDIG; j += P1_T) h[j] = 0;
    __syncthreads();
    int base_i = blockIdx.x * P1_EDGES;
    int key[P1_EPT], val[P1_EPT], dg[P1_EPT];
#pragma unroll
    for (int k = 0; k < P1_EPT; ++k) {
        int i = base_i + k * P1_T + t;
        int dd = -1;
        if (i < 2 * E_NNZ) {
            int row, col;
            float v;
            if (i < E_NNZ) {
                row = eiL[i]; col = eiL[E_NNZ + i]; v = lv[i];
                dd = row >> 10;
            } else {
                int e = i - E_NNZ;
                row = eiU[e]; col = eiU[E_NNZ + e]; v = uv[e];
                dd = NDIG_HALF + (row >> 10);
            }
            key[k] = ((row & 1023) << 22) | col;
            val[k] = __float_as_int(v);
            atomicAdd(&h[dd], 1);
        }
        dg[k] = dd;
    }
    __syncthreads();
    // scan the 782 counts (1024-thread Hillis-Steele); emit ccnt/bofs; h := excl.
    int cv = (t < NDIG) ? h[t] : 0;
    hscan[t] = cv;
    __syncthreads();
    for (int off = 1; off < P1_T; off <<= 1) {
        int x = (t >= off) ? hscan[t - off] : 0;
        __syncthreads();
        hscan[t] += x;
        __syncthreads();
    }
    if (t < NDIG) {
        int ex = hscan[t] - cv;
        ccnt[blockIdx.x * NDIG + t] = cv;
        bofsv[blockIdx.x * NDIG + t] = ex;
        h[t] = ex;
    }
    __syncthreads();
    // placement into digit-sorted LDS buffer
#pragma unroll
    for (int k = 0; k < P1_EPT; ++k) {
        if (dg[k] >= 0) {
            int pos = atomicAdd(&h[dg[k]], 1);
            rec[pos] = make_int2(key[k], val[k]);
        }
    }
    __syncthreads();
    // contiguous stream-out: full-line writes only
    int2* dst = coarse + (size_t)blockIdx.x * P1_EDGES;
    int nrec = 2 * E_NNZ - base_i;
    if (nrec > P1_EDGES) nrec = P1_EDGES;
    for (int j = t; j < nrec; j += P1_T) dst[j] = rec[j];
}

// per-digit totals over blocks
__global__ void digit_total_kernel(const int* __restrict__ cnt, int* __restrict__ tot) {
    int d = blockIdx.x * 256 + threadIdx.x;
    if (d >= NDIG) return;
    int run = 0;
    for (int b = 0; b < P1_BLOCKS; ++b) run += cnt[b * NDIG + d];
    tot[d] = run;
}

// exclusive scan of tot[NDIG] in place (becomes digit global base)
__global__ __launch_bounds__(1024) void scan_base_kernel(int* __restrict__ tot) {
    __shared__ int s[1024];
    int t = threadIdx.x;
    int v = (t < NDIG) ? tot[t] : 0;
    s[t] = v;
    __syncthreads();
    for (int off = 1; off < 1024; off <<= 1) {
        int x = (t >= off) ? s[t - off] : 0;
        __syncthreads();
        s[t] += x;
        __syncthreads();
    }
    if (t < NDIG) tot[t] = s[t] - v;
    if (t == 1023) tot[NDIG] = s[1023];   // = 2*E_NNZ
}

// ---------------- CSR build: pass 2 (fragment gather + LDS counting sort) -------

__global__ __launch_bounds__(P2_T) void p2_build_kernel(
        const int2* __restrict__ coarse, const int* __restrict__ ccnt,
        const int* __restrict__ bofsv, const int* __restrict__ basev,
        int* __restrict__ rpL, int* __restrict__ rpU,
        int2* __restrict__ edgeL, int2* __restrict__ edgeU) {
    __shared__ int pk[P2_CAP];
    __shared__ int vl[P2_CAP];
    __shared__ int hist[1024];
    __shared__ int sc[P2_T];
    __shared__ int fo[P1_BLOCKS];
    __shared__ int stot;
    int d = blockIdx.x;
    int t = threadIdx.x;
    // fragment table: len/ofs per pass-1 block
    int len = 0, ofs = 0;
    if (t < P1_BLOCKS) { len = ccnt[t * NDIG + d]; ofs = bofsv[t * NDIG + d]; }
    sc[t] = len;
    __syncthreads();
    for (int off = 1; off < P2_T; off <<= 1) {
        int x = (t >= off) ? sc[t - off] : 0;
        __syncthreads();
        sc[t] += x;
        __syncthreads();
    }
    if (t < P1_BLOCKS) { fo[t] = sc[t] - len; hist[t] = len; hist[512 + t] = ofs; }
    if (t == P1_BLOCKS - 1) stot = sc[t];
    __syncthreads();
    int sz = stot;
    if (sz > P2_CAP) sz = P2_CAP;   // never expected
    // cooperative fragment copy: wave w handles fragments b = w, w+8, ...
    int wv = t >> 6, lane = t & 63;
    for (int b = wv; b < P1_BLOCKS; b += P2_T / 64) {
        int L = hist[b], O = hist[512 + b], F = fo[b];
        const int2* sp = coarse + (size_t)b * P1_EDGES + O;
        for (int j = lane; j < L; j += 64) {
            int dst2 = F + j;
            if (dst2 < P2_CAP) {
                int2 r = sp[j];
                pk[dst2] = r.x;
                vl[dst2] = r.y;
            }
        }
    }
    __syncthreads();
    hist[t] = 0;
    hist[t + P2_T] = 0;
    __syncthreads();
    int myrank[P2_ITERS];
#pragma unroll
    for (int k = 0; k < P2_ITERS; ++k) {
        int j = k * P2_T + t;
        myrank[k] = (j < sz) ? atomicAdd(&hist[((unsigned)pk[j]) >> 22], 1) : 0;
    }
    __syncthreads();
    int h0 = hist[2 * t], h1 = hist[2 * t + 1];
    sc[t] = h0 + h1;
    __syncthreads();
    for (int off = 1; off < P2_T; off <<= 1) {
        int x = (t >= off) ? sc[t - off] : 0;
        __syncthreads();
        sc[t] += x;
        __syncthreads();
    }
    int pbase = sc[t] - (h0 + h1);   // exclusive prefix of bin pair
    __syncthreads();
    hist[2 * t] = pbase;
    hist[2 * t + 1] = pbase + h0;
    // rp write (2 rows per thread)
    int which = (d >= NDIG_HALF);
    int lbase = basev[d] - (which ? E_NNZ : 0);
    int rowbase = (which ? d - NDIG_HALF : d) << 10;
    int* rp = which ? rpU : rpL;
    int r0 = rowbase + 2 * t, r1 = r0 + 1;
    if (r0 < N_SIMP) rp[r0] = lbase + pbase;
    if (r1 < N_SIMP) rp[r1] = lbase + pbase + h0;
    __syncthreads();
    int2* eout = which ? edgeU : edgeL;
#pragma unroll
    for (int k = 0; k < P2_ITERS; ++k) {
        int j = k * P2_T + t;
        if (j < sz) {
            unsigned p = (unsigned)pk[j];
            int pos = lbase + hist[p >> 22] + myrank[k];
            eout[pos] = make_int2((int)(p & 0x3FFFFF), vl[j]);
        }
    }
}

// ---------------- small prep kernels ----------------

__global__ void combine_bias_kernel(const float* __restrict__ bh,
                                    const float* __restrict__ bl,
                                    const float* __restrict__ bu,
                                    float* __restrict__ out) {
    int h = threadIdx.x;
    float acc = bh[h];
    for (int k = 0; k < KAPPA; ++k) acc += bl[k * HDIM + h] + bu[k * HDIM + h];
    out[h] = acc;
}

__global__ void f32_to_bf16_kernel(const float* __restrict__ in, bf16* __restrict__ out) {
    int idx = blockIdx.x * 256 + threadIdx.x;   // per float4
    float4 v = ((const float4*)in)[idx];
    ushort4 w;
    w.x = f2bf(v.x); w.y = f2bf(v.y); w.z = f2bf(v.z); w.w = f2bf(v.w);
    ((ushort4*)out)[idx] = w;
}

// all 6 weight transposes in one dispatch; wt layout fixed (offsets in ushorts)
__global__ void wtrans_all_kernel(const float* __restrict__ s0, const float* __restrict__ s1,
                                  const float* __restrict__ s2, const float* __restrict__ s3,
                                  const float* __restrict__ s4, const float* __restrict__ s5,
                                  ushort* __restrict__ wt) {
    int idx = blockIdx.x * 256 + threadIdx.x;   // 0..43007
    const float* src; int Ktot, off;
    if (idx < 2048)       { src = s0; Ktot = 32;  off = 0; }
    else if (idx < 6144)  { src = s1; Ktot = 64;  off = 2048; }
    else if (idx < 12288) { src = s2; Ktot = 96;  off = 6144; }
    else if (idx < 18432) { src = s3; Ktot = 96;  off = 12288; }
    else if (idx < 30720) { src = s4; Ktot = 192; off = 18432; }
    else                  { src = s5; Ktot = 192; off = 30720; }
    int rel = idx - off;
    int n = rel / Ktot, kk = rel - n * Ktot;
    wt[idx] = f2bf(src[kk * 64 + n]);
}

// ---------------- SpMM (CSR gather) --------
// rp holds EXCLUSIVE row starts: s = rp[row], e = rp[row+1] (guarded at N-1)

// 32-wide: 4 lanes/row (8 ch each), 16 rows/wave, 64 rows/block
__global__ void spmm32_kernel(const int* __restrict__ rp, const int2* __restrict__ edge,
                              const bf16* __restrict__ srcb, int src_stride,
                              bf16* __restrict__ dstb) {
    const ushort* src = (const ushort*)srcb;
    ushort* dst = (ushort*)dstb;
    int tid = threadIdx.x;
    int lane = tid & 63;
    int wv = tid >> 6;
    int grp = lane >> 2;      // 0..15: row within wave
    int li = lane & 3;        // channels li*8 .. li*8+7
    int row = blockIdx.x * 64 + wv * 16 + grp;
    int s = rp[row];
    int e = (row == N_SIMP - 1) ? E_NNZ : rp[row + 1];
    int deg = e - s;
    float a[8] = {0.f, 0.f, 0.f, 0.f, 0.f, 0.f, 0.f, 0.f};
    if (deg > 0) {
        int2 ed[8];
#pragma unroll
        for (int t = 0; t < 8; ++t) {
            int j = s + t;
            ed[t] = edge[(j < e) ? j : (e - 1)];
        }
        u8v xs[8];
#pragma unroll
        for (int t = 0; t < 8; ++t)
            xs[t] = *(const u8v*)(src + (size_t)ed[t].x * src_stride + li * 8);
#pragma unroll
        for (int t = 0; t < 8; ++t) {
            float v = (t < deg) ? __int_as_float(ed[t].y) : 0.f;
#pragma unroll
            for (int c = 0; c < 8; ++c) a[c] += v * bf2f(xs[t][c]);
        }
        for (int j = s + 8; j < e; j += 4) {
            int2 e2[4];
#pragma unroll
            for (int t = 0; t < 4; ++t) {
                int jj = j + t;
                e2[t] = edge[(jj < e) ? jj : (e - 1)];
            }
            u8v x2[4];
#pragma unroll
            for (int t = 0; t < 4; ++t)
                x2[t] = *(const u8v*)(src + (size_t)e2[t].x * src_stride + li * 8);
#pragma unroll
            for (int t = 0; t < 4; ++t) {
                float v = (j + t < e) ? __int_as_float(e2[t].y) : 0.f;
#pragma unroll
                for (int c = 0; c < 8; ++c) a[c] += v * bf2f(x2[t][c]);
            }
        }
    }
    u8v w;
#pragma unroll
    for (int c = 0; c < 8; ++c) w[c] = f2bf(a[c]);
    *(u8v*)(dst + (size_t)row * 32 + li * 8) = w;
}

// 64-wide: 8 lanes/row (8 ch each), 8 rows/wave, 32 rows/block; stride 64
__global__ void spmm64_kernel(const int* __restrict__ rp, const int2* __restrict__ edge,
                              const bf16* __restrict__ srcb, bf16* __restrict__ dstb) {
    const ushort* src = (const ushort*)srcb;
    ushort* dst = (ushort*)dstb;
    int tid = threadIdx.x;
    int lane = tid & 63;
    int wv = tid >> 6;
    int grp = lane >> 3;      // 0..7: row within wave
    int li = lane & 7;        // channels li*8 .. li*8+7
    int row = blockIdx.x * 32 + wv * 8 + grp;
    int s = rp[row];
    int e = (row == N_SIMP - 1) ? E_NNZ : rp[row + 1];
    int deg = e - s;
    float a[8] = {0.f, 0.f, 0.f, 0.f, 0.f, 0.f, 0.f, 0.f};
    if (deg > 0) {
        int2 ed[8];
#pragma unroll
        for (int t = 0; t < 8; ++t) {
            int j = s + t;
            ed[t] = edge[(j < e) ? j : (e - 1)];
        }
        u8v xs[8];
#pragma unroll
        for (int t = 0; t < 8; ++t)
            xs[t] = *(const u8v*)(src + (size_t)ed[t].x * 64 + li * 8);
#pragma unroll
        for (int t = 0; t < 8; ++t) {
            float v = (t < deg) ? __int_as_float(ed[t].y) : 0.f;
#pragma unroll
            for (int c = 0; c < 8; ++c) a[c] += v * bf2f(xs[t][c]);
        }
        for (int j = s + 8; j < e; j += 4) {
            int2 e2[4];
#pragma unroll
            for (int t = 0; t < 4; ++t) {
                int jj = j + t;
                e2[t] = edge[(jj < e) ? jj : (e - 1)];
            }
            u8v x2[4];
#pragma unroll
            for (int t = 0; t < 4; ++t)
                x2[t] = *(const u8v*)(src + (size_t)e2[t].x * 64 + li * 8);
#pragma unroll
            for (int t = 0; t < 4; ++t) {
                float v = (j + t < e) ? __int_as_float(e2[t].y) : 0.f;
#pragma unroll
                for (int c = 0; c < 8; ++c) a[c] += v * bf2f(x2[t][c]);
            }
        }
    }
    u8v w;
#pragma unroll
    for (int c = 0; c < 8; ++c) w[c] = f2bf(a[c]);
    *(u8v*)(dst + (size_t)row * 64 + li * 8) = w;
}

// ---------------- MFMA GEMM: z[N,64] (fp16) (=bias+ / +=) A[N, NCH*32] @ W -------
// up to 6 A-channel sources; W split into two groups (Wt1 for ch<NCH1, Wt2 rest)

template <int NCH, int NCH1, bool INIT>
__global__ __launch_bounds__(256) void mfma_gemm_kernel(
        const ushort* __restrict__ s0, int st0,
        const ushort* __restrict__ s1, int st1,
        const ushort* __restrict__ s2, int st2,
        const ushort* __restrict__ s3, int st3,
        const ushort* __restrict__ s4, int st4,
        const ushort* __restrict__ s5, int st5,
        const ushort* __restrict__ Wt1, int Kstride1,
        const ushort* __restrict__ Wt2, int Kstride2,
        const float* __restrict__ bias,
        f16* __restrict__ z) {
    int tid = threadIdx.x;
    int wv = tid >> 6, lane = tid & 63;
    int quad = lane >> 4, n = lane & 15;
    int rowbase = blockIdx.x * 64 + wv * 16;
    int arow = rowbase + n;  // A-operand row m = lane&15

    f4v acc0 = {0.f, 0.f, 0.f, 0.f};
    f4v acc1 = {0.f, 0.f, 0.f, 0.f};
    f4v acc2 = {0.f, 0.f, 0.f, 0.f};
    f4v acc3 = {0.f, 0.f, 0.f, 0.f};

#pragma unroll
    for (int ch = 0; ch < NCH; ++ch) {
        const ushort* sp = (ch == 0) ? s0 : (ch == 1) ? s1 : (ch == 2) ? s2
                         : (ch == 3) ? s3 : (ch == 4) ? s4 : s5;
        int st = (ch == 0) ? st0 : (ch == 1) ? st1 : (ch == 2) ? st2
               : (ch == 3) ? st3 : (ch == 4) ? st4 : st5;
        const ushort* wb = (ch < NCH1) ? (Wt1 + ch * 32) : (Wt2 + (ch - NCH1) * 32);
        int Ks = (ch < NCH1) ? Kstride1 : Kstride2;
        s8v a = *(const s8v*)(sp + (size_t)arow * st + quad * 8);
        const ushort* wq = wb + quad * 8;
        s8v b0 = *(const s8v*)(wq + (size_t)(0 * 16 + n) * Ks);
        s8v b1 = *(const s8v*)(wq + (size_t)(1 * 16 + n) * Ks);
        s8v b2 = *(const s8v*)(wq + (size_t)(2 * 16 + n) * Ks);
        s8v b3 = *(const s8v*)(wq + (size_t)(3 * 16 + n) * Ks);
        acc0 = __builtin_amdgcn_mfma_f32_16x16x32_bf16(a, b0, acc0, 0, 0, 0);
        acc1 = __builtin_amdgcn_mfma_f32_16x16x32_bf16(a, b1, acc1, 0, 0, 0);
        acc2 = __builtin_amdgcn_mfma_f32_16x16x32_bf16(a, b2, acc2, 0, 0, 0);
        acc3 = __builtin_amdgcn_mfma_f32_16x16x32_bf16(a, b3, acc3, 0, 0, 0);
    }
    // C/D layout: col = lane&15, row = quad*4 + reg
#pragma unroll
    for (int r = 0; r < 4; ++r) {
        int orow = rowbase + quad * 4 + r;
        f16* zp = z + (size_t)orow * 64 + n;
        if (INIT) {
            zp[0]  = (f16)(bias[n]      + acc0[r]);
            zp[16] = (f16)(bias[16 + n] + acc1[r]);
            zp[32] = (f16)(bias[32 + n] + acc2[r]);
            zp[48] = (f16)(bias[48 + n] + acc3[r]);
        } else {
            zp[0]  = (f16)((float)zp[0]  + acc0[r]);
            zp[16] = (f16)((float)zp[16] + acc1[r]);
            zp[32] = (f16)((float)zp[32] + acc2[r]);
            zp[48] = (f16)((float)zp[48] + acc3[r]);
        }
    }
}

// ---------------- BN / pool / MLP (vectorized) ----------------

__global__ void bn_stats_kernel(const f16* __restrict__ z, double* __restrict__ stats) {
    __shared__ float ss[256 * 8], qq[256 * 8];
    int tid = threadIdx.x;
    const h8v* z8 = (const h8v*)z;
    const int total8 = N_SIMP * HDIM / 8;
    float fs[8] = {0, 0, 0, 0, 0, 0, 0, 0};
    float fq[8] = {0, 0, 0, 0, 0, 0, 0, 0};
    for (int i = blockIdx.x * 256 + tid; i < total8; i += (int)gridDim.x * 256) {
        h8v v = z8[i];
#pragma unroll
        for (int c = 0; c < 8; ++c) {
            float f = (float)v[c];
            fs[c] += f;
            fq[c] += f * f;
        }
    }
#pragma unroll
    for (int c = 0; c < 8; ++c) { ss[tid * 8 + c] = fs[c]; qq[tid * 8 + c] = fq[c]; }
    __syncthreads();
    if (tid < 64) {
        // channel tid: contributions from threads t with (t&7)==tid>>3, slot tid&7
        int sel = tid >> 3, slot = tid & 7;
        double a = 0.0, b = 0.0;
#pragma unroll 8
        for (int k = 0; k < 32; ++k) {
            int t = sel + (k << 3);
            a += (double)ss[t * 8 + slot];
            b += (double)qq[t * 8 + slot];
        }
        atomicAdd(&stats[tid], a);
        atomicAdd(&stats[64 + tid], b);
    }
}

// layer-0: h0bf = bf16(elu(bn(z)))
__global__ void bn_elu_bf16_kernel(const f16* __restrict__ z, const double* __restrict__ stats,
                                   const float* __restrict__ gamma, const float* __restrict__ beta,
                                   bf16* __restrict__ out) {
    __shared__ float scale_s[64], shift_s[64];
    int tid = threadIdx.x;
    if (tid < 64) {
        double mean = stats[tid] / (double)N_SIMP;
        double var = stats[64 + tid] / (double)N_SIMP - mean * mean;
        double sc = (double)gamma[tid] / sqrt(var + BN_EPS);
        scale_s[tid] = (float)sc;
        shift_s[tid] = (float)((double)beta[tid] - mean * sc);
    }
    __syncthreads();
    const h8v* z8 = (const h8v*)z;
    u8v* o8 = (u8v*)out;
    const int total8 = N_SIMP * HDIM / 8;
    int hb = (tid & 7) * 8;
    for (int i = blockIdx.x * 256 + tid; i < total8; i += (int)gridDim.x * 256) {
        h8v v = z8[i];
        u8v w;
#pragma unroll
        for (int c = 0; c < 8; ++c)
            w[c] = f2bf(elu_f((float)v[c] * scale_s[hb + c] + shift_s[hb + c]));
        o8[i] = w;
    }
}

// layer-1: z = elu(bn(z)) in place (fp16)
__global__ void bn_elu_f16_kernel(f16* __restrict__ z, const double* __restrict__ stats,
                                  const float* __restrict__ gamma, const float* __restrict__ beta) {
    __shared__ float scale_s[64], shift_s[64];
    int tid = threadIdx.x;
    if (tid < 64) {
        double mean = stats[tid] / (double)N_SIMP;
        double var = stats[64 + tid] / (double)N_SIMP - mean * mean;
        double sc = (double)gamma[tid] / sqrt(var + BN_EPS);
        scale_s[tid] = (float)sc;
        shift_s[tid] = (float)((double)beta[tid] - mean * sc);
    }
    __syncthreads();
    h8v* z8 = (h8v*)z;
    const int total8 = N_SIMP * HDIM / 8;
    int hb = (tid & 7) * 8;
    for (int i = blockIdx.x * 256 + tid; i < total8; i += (int)gridDim.x * 256) {
        h8v v = z8[i];
        h8v w;
#pragma unroll
        for (int c = 0; c < 8; ++c)
            w[c] = (f16)elu_f((float)v[c] * scale_s[hb + c] + shift_s[hb + c]);
        z8[i] = w;
    }
}

__global__ void pool_kernel(const f16* __restrict__ hbuf, const int* __restrict__ bidx,
                            float* __restrict__ gbuf) {
    __shared__ float smax[256], ssum[256];
    int g = blockIdx.x;
    int tid = threadIdx.x;
    int lo = 0, hi = N_SIMP;
    while (lo < hi) { int mid = (lo + hi) >> 1; if (bidx[mid] < g) lo = mid + 1; else hi = mid; }
    int start = lo;
    hi = N_SIMP;
    while (lo < hi) { int mid = (lo + hi) >> 1; if (bidx[mid] < g + 1) lo = mid + 1; else hi = mid; }
    int end = lo;
    int h = tid & 63, rep = tid >> 6;
    float mx = -INFINITY, sm = 0.f;
    for (int i = start + rep; i < end; i += 4) {
        float v = (float)hbuf[(size_t)i * HDIM + h];
        mx = fmaxf(mx, v);
        sm += v;
    }
    smax[tid] = mx; ssum[tid] = sm;
    __syncthreads();
    if (tid < 64) {
        float m = fmaxf(fmaxf(smax[tid], smax[tid + 64]), fmaxf(smax[tid + 128], smax[tid + 192]));
        float s = ssum[tid] + ssum[tid + 64] + ssum[tid + 128] + ssum[tid + 192];
        int cnt = end - start;
        float mean = s / fmaxf((float)cnt, 1.f);
        gbuf[g * 128 + tid] = elu_f(m);
        gbuf[g * 128 + 64 + tid] = elu_f(mean);
    }
}

__global__ void mlp_kernel(const float* __restrict__ gbuf, const float* __restrict__ W1,
                           const float* __restrict__ b1, const float* __restrict__ W2,
                           const float* __restrict__ b2, float* __restrict__ out) {
    __shared__ float gs[128];
    __shared__ float hs[64];
    int g = blockIdx.x, tid = threadIdx.x;
    gs[tid] = gbuf[g * 128 + tid];
    gs[64 + tid] = gbuf[g * 128 + 64 + tid];
    __syncthreads();
    float acc = b1[tid];
#pragma unroll
    for (int k = 0; k < 128; ++k) acc += gs[k] * W1[k * 64 + tid];
    hs[tid] = fmaxf(acc, 0.f);
    __syncthreads();
    if (tid < 8) {
        float o = b2[tid];
#pragma unroll
        for (int k = 0; k < 64; ++k) o += hs[k] * W2[k * 8 + tid];
        out[g * 8 + tid] = o;
    }
}

// ---------------- host side ----------------

extern "C" void kernel_launch(void* const* d_in, const int* in_sizes, int n_in,
                              void* d_out, int out_size, void* d_ws, size_t ws_size,
                              hipStream_t stream) {
    const float* x     = (const float*)d_in[0];
    const int*   li    = (const int*)d_in[1];
    const float* lv    = (const float*)d_in[2];
    const int*   ui    = (const int*)d_in[3];
    const float* uv    = (const float*)d_in[4];
    const int*   bidx  = (const int*)d_in[5];
    const float* l0_Wl = (const float*)d_in[6];
    const float* l0_bl = (const float*)d_in[7];
    const float* l0_Wu = (const float*)d_in[8];
    const float* l0_bu = (const float*)d_in[9];
    const float* l0_Wh = (const float*)d_in[10];
    const float* l0_bh = (const float*)d_in[11];
    const float* l1_Wl = (const float*)d_in[12];
    const float* l1_bl = (const float*)d_in[13];
    const float* l1_Wu = (const float*)d_in[14];
    const float* l1_bu = (const float*)d_in[15];
    const float* l1_Wh = (const float*)d_in[16];
    const float* l1_bh = (const float*)d_in[17];
    const float* bn0_g = (const float*)d_in[18];
    const float* bn0_b = (const float*)d_in[19];
    const float* bn1_g = (const float*)d_in[20];
    const float* bn1_b = (const float*)d_in[21];
    const float* mW1   = (const float*)d_in[22];
    const float* mb1   = (const float*)d_in[23];
    const float* mW2   = (const float*)d_in[24];
    const float* mb2   = (const float*)d_in[25];
    float* out = (float*)d_out;

    // ---- workspace layout (total ~246.8 MB <= 256 MiB) ----
    char* base = (char*)d_ws;
    f16*   z     = (f16*)base;                                    //  51,200,000
    bf16*  h0bf  = (bf16*)(base + 51200000ull);                   //  51,200,000
    bf16*  g1    = (bf16*)(base + 102400000ull);                  //  51,200,000
    bf16*  g2    = (bf16*)(base + 153600000ull);                  //  51,200,000
    int2*  edgeL = (int2*)(base + 204800000ull);                  //  19,200,000
    int2*  edgeU = (int2*)(base + 224000000ull);                  //  19,200,000
    int*   rpL   = (int*)(base + 243200000ull);                   //   1,600,032
    int*   rpU   = (int*)(base + 244800032ull);                   //   1,600,032
    double* stats = (double*)(base + 246404160ull);               //   1 KB
    float* cbias  = (float*)(base + 246405184ull);                //   256 B
    float* gbuf   = (float*)(base + 246405440ull);                //   262,144
    ushort* wt    = (ushort*)(base + 246667584ull);               //   86,016

    // CSR-build scratch aliases (regions dead during build):
    //  z region   : coarse 38.4 MB + basev 3.1 KB
    //  h0bf region: ccnt 916 KB + bofs 916 KB
    int2* coarse = (int2*)base;                                   // 38,404,096
    int*  basev  = (int*)(base + 38500000ull);                    // (NDIG+1)*4
    int*  ccnt   = (int*)(base + 51200000ull);                    // 916,504
    int*  bofsv  = (int*)(base + 52200000ull);                    // 916,504

    // layer-0 scratch: 6 slots of N*32 bf16 in g1/g2/h0bf regions
    bf16* xbf  = g1;                                 // g1 slot 0 (later cCU)
    bf16* cAL  = g1 + (size_t)N_SIMP * 32;           // g1 slot 1
    bf16* cBL  = g2;                                 // g2 slot 0
    bf16* cCL  = g2 + (size_t)N_SIMP * 32;           // g2 slot 1
    bf16* cAU  = h0bf;                               // h0 slot 0
    bf16* cBU  = h0bf + (size_t)N_SIMP * 32;         // h0 slot 1
    bf16* cCU  = g1;                                 // reuses xbf slot (xbf dead)

    // weight-transpose sub-buffers (ushort elements; offsets match wtrans_all_kernel)
    ushort* wt_l0h = wt;            // 64 x 32
    ushort* wt_l1h = wt + 2048;     // 64 x 64
    ushort* wt_l0l = wt + 6144;     // 64 x 96
    ushort* wt_l0u = wt + 12288;    // 64 x 96
    ushort* wt_l1l = wt + 18432;    // 64 x 192
    ushort* wt_l1u = wt + 30720;    // 64 x 192

    const int SP32_BLOCKS = N_SIMP / 64;   // 6,250
    const int SP64_BLOCKS = N_SIMP / 32;   // 12,500
    const int MF_BLOCKS   = N_SIMP / 64;   // 6,250

    // ---- prep: weight transposes (one dispatch) + x->bf16 ----
    wtrans_all_kernel<<<168, 256, 0, stream>>>(l0_Wh, l1_Wh, l0_Wl, l0_Wu, l1_Wl, l1_Wu, wt);
    f32_to_bf16_kernel<<<N_SIMP * 32 / 4 / 256, 256, 0, stream>>>(x, xbf);

    // ---- CSR builds: in-LDS block sort + fragment-gather bucket sort ----
    p1_sort_kernel<<<P1_BLOCKS, P1_T, 0, stream>>>(li, lv, ui, uv, ccnt, bofsv, coarse);
    digit_total_kernel<<<(NDIG + 255) / 256, 256, 0, stream>>>(ccnt, basev);
    scan_base_kernel<<<1, 1024, 0, stream>>>(basev);
    p2_build_kernel<<<NDIG, P2_T, 0, stream>>>(coarse, ccnt, bofsv, basev,
                                               rpL, rpU, edgeL, edgeU);

    const ushort* xbfu = (const ushort*)xbf;
    const ushort* h0u  = (const ushort*)h0bf;
    const ushort* g1u  = (const ushort*)g1;
    const ushort* g2u  = (const ushort*)g2;

    // ---------------- layer 0 (F_IN=32 -> H=64) ----------------
    combine_bias_kernel<<<1, 64, 0, stream>>>(l0_bh, l0_bl, l0_bu, cbias);
    mfma_gemm_kernel<1, 1, true><<<MF_BLOCKS, 256, 0, stream>>>(
        xbfu, 32, nullptr, 0, nullptr, 0, nullptr, 0, nullptr, 0, nullptr, 0,
        wt_l0h, 32, wt_l0h, 32, cbias, z);

    // lower chain
    spmm32_kernel<<<SP32_BLOCKS, 256, 0, stream>>>(rpL, edgeL, xbf, 32, cAL);
    spmm32_kernel<<<SP32_BLOCKS, 256, 0, stream>>>(rpL, edgeL, cAL, 32, cBL);
    spmm32_kernel<<<SP32_BLOCKS, 256, 0, stream>>>(rpL, edgeL, cBL, 32, cCL);
    // upper chain (cAU spmm reads xbf before cCU overwrites that slot)
    spmm32_kernel<<<SP32_BLOCKS, 256, 0, stream>>>(rpU, edgeU, xbf, 32, cAU);
    spmm32_kernel<<<SP32_BLOCKS, 256, 0, stream>>>(rpU, edgeU, cAU, 32, cBU);
    spmm32_kernel<<<SP32_BLOCKS, 256, 0, stream>>>(rpU, edgeU, cBU, 32, cCU);
    // single accumulate-GEMM over all 6 chain outputs
    mfma_gemm_kernel<6, 3, false><<<MF_BLOCKS, 256, 0, stream>>>(
        (const ushort*)cAL, 32, (const ushort*)cBL, 32, (const ushort*)cCL, 32,
        (const ushort*)cAU, 32, (const ushort*)cBU, 32, (const ushort*)cCU, 32,
        wt_l0l, 96, wt_l0u, 96, nullptr, z);

    (void)hipMemsetAsync(stats, 0, 128 * sizeof(double), stream);
    bn_stats_kernel<<<1024, 256, 0, stream>>>(z, stats);
    bn_elu_bf16_kernel<<<1024, 256, 0, stream>>>(z, stats, bn0_g, bn0_b, h0bf);

    // ---------------- layer 1 (H=64 -> H=64), 64-wide chains ----------------
    combine_bias_kernel<<<1, 64, 0, stream>>>(l1_bh, l1_bl, l1_bu, cbias);
    mfma_gemm_kernel<2, 2, true><<<MF_BLOCKS, 256, 0, stream>>>(
        h0u, 64, h0u + 32, 64, nullptr, 0, nullptr, 0, nullptr, 0, nullptr, 0,
        wt_l1h, 64, wt_l1h, 64, cbias, z);

    // u1 = L h0 -> g1 ; u2 = L u1 -> g2
    spmm64_kernel<<<SP64_BLOCKS, 256, 0, stream>>>(rpL, edgeL, h0bf, g1);
    spmm64_kernel<<<SP64_BLOCKS, 256, 0, stream>>>(rpL, edgeL, g1, g2);
    // gemm A: u1 (K 0-63), u2 (K 64-127) of wt_l1l
    mfma_gemm_kernel<4, 4, false><<<MF_BLOCKS, 256, 0, stream>>>(
        g1u, 64, g1u + 32, 64, g2u, 64, g2u + 32, 64, nullptr, 0, nullptr, 0,
        wt_l1l, 192, wt_l1l, 192, nullptr, z);
    // u3 = L u2 -> g1 ; v1 = U h0 -> g2
    spmm64_kernel<<<SP64_BLOCKS, 256, 0, stream>>>(rpL, edgeL, g2, g1);
    spmm64_kernel<<<SP64_BLOCKS, 256, 0, stream>>>(rpU, edgeU, h0bf, g2);
    // gemm B: u3 (wt_l1l K 128-191), v1 (wt_l1u K 0-63)
    mfma_gemm_kernel<4, 2, false><<<MF_BLOCKS, 256, 0, stream>>>(
        g1u, 64, g1u + 32, 64, g2u, 64, g2u + 32, 64, nullptr, 0, nullptr, 0,
        wt_l1l + 128, 192, wt_l1u, 192, nullptr, z);
    // v2 = U v1 -> g1 ; v3 = U v2 -> g2
    spmm64_kernel<<<SP64_BLOCKS, 256, 0, stream>>>(rpU, edgeU, g2, g1);
    spmm64_kernel<<<SP64_BLOCKS, 256, 0, stream>>>(rpU, edgeU, g1, g2);
    // gemm C: v2 (K 64-127), v3 (K 128-191) of wt_l1u
    mfma_gemm_kernel<4, 4, false><<<MF_BLOCKS, 256, 0, stream>>>(
        g1u, 64, g1u + 32, 64, g2u, 64, g2u + 32, 64, nullptr, 0, nullptr, 0,
        wt_l1u + 64, 192, wt_l1u + 64, 192, nullptr, z);

    (void)hipMemsetAsync(stats, 0, 128 * sizeof(double), stream);
    bn_stats_kernel<<<1024, 256, 0, stream>>>(z, stats);
    bn_elu_f16_kernel<<<1024, 256, 0, stream>>>(z, stats, bn1_g, bn1_b);

    // ---------------- pool + MLP ----------------
    pool_kernel<<<G_NUM, 256, 0, stream>>>(z, bidx, gbuf);
    mlp_kernel<<<G_NUM, 64, 0, stream>>>(gbuf, mW1, mb1, mW2, mb2, out);
}

// Round 7
// 1324.474 us; speedup vs baseline: 1.4209x; 1.0504x over previous
//
#include <hip/hip_runtime.h>
#include <hip/hip_bf16.h>
#include <math.h>

#define N_SIMP 400000
#define E_NNZ  2400000
#define FIN    32
#define HDIM   64
#define KAPPA  3
#define G_NUM  512
#define NOUT   8
#define BN_EPS 1e-5

// ---- CSR build (two-level LDS counting sort; pass-1 sorts fully in LDS) ----
#define NDIG_HALF 391             // ceil(400000/1024) coarse buckets per matrix
#define NDIG      782             // L + U
#define P1_EDGES  16384           // edges per pass-1 block (16/thread @ 1024 thr)
#define P1_BLOCKS 293             // ceil(4.8M / 16384)
#define P1_T      1024
#define P1_EPT    16
#define P2_CAP    7168            // bucket capacity (avg 6144, +13 sigma headroom)
#define P2_T      512
#define P2_ITERS  14              // P2_CAP / P2_T

typedef __hip_bfloat16 bf16;
typedef _Float16 f16;
typedef short s8v __attribute__((ext_vector_type(8)));    // 8 bf16 in 4 VGPRs
typedef ushort u8v __attribute__((ext_vector_type(8)));   // 8 bf16 raw
typedef _Float16 h8v __attribute__((ext_vector_type(8))); // 8 f16
typedef float f4v __attribute__((ext_vector_type(4)));

__device__ __forceinline__ float elu_f(float x) {
    return x > 0.f ? x : expm1f(x);
}
__device__ __forceinline__ float bf2f(ushort u) {
    return __uint_as_float(((unsigned int)u) << 16);
}
__device__ __forceinline__ ushort f2bf(float f) {
    bf16 h = (bf16)f;
    return *(ushort*)&h;
}

// ---------------- CSR build: pass 1 (full in-LDS counting sort per block) -------

__global__ __launch_bounds__(P1_T, 1) void p1_sort_kernel(
        const int* __restrict__ eiL, const float* __restrict__ lv,
        const int* __restrict__ eiU, const float* __restrict__ uv,
        int* __restrict__ ccnt, int* __restrict__ bofsv,
        int2* __restrict__ coarse) {
    __shared__ int2 rec[P1_EDGES];   // 128 KB
    __shared__ int h[NDIG];          // counts -> running offsets
    __shared__ int hscan[P1_T];      // scan scratch
    int t = threadIdx.x;
    for (int j = t; j < NDIG; j += P1_T) h[j] = 0;
    __syncthreads();
    int base_i = blockIdx.x * P1_EDGES;
    int key[P1_EPT], val[P1_EPT], dg[P1_EPT];
#pragma unroll
    for (int k = 0; k < P1_EPT; ++k) {
        int i = base_i + k * P1_T + t;
        int dd = -1;
        if (i < 2 * E_NNZ) {
            int row, col;
            float v;
            if (i < E_NNZ) {
                row = eiL[i]; col = eiL[E_NNZ + i]; v = lv[i];
                dd = row >> 10;
            } else {
                int e = i - E_NNZ;
                row = eiU[e]; col = eiU[E_NNZ + e]; v = uv[e];
                dd = NDIG_HALF + (row >> 10);
            }
            key[k] = ((row & 1023) << 22) | col;
            val[k] = __float_as_int(v);
            atomicAdd(&h[dd], 1);
        }
        dg[k] = dd;
    }
    __syncthreads();
    // scan the 782 counts (1024-thread Hillis-Steele); emit ccnt/bofs; h := excl.
    int cv = (t < NDIG) ? h[t] : 0;
    hscan[t] = cv;
    __syncthreads();
    for (int off = 1; off < P1_T; off <<= 1) {
        int x = (t >= off) ? hscan[t - off] : 0;
        __syncthreads();
        hscan[t] += x;
        __syncthreads();
    }
    if (t < NDIG) {
        int ex = hscan[t] - cv;
        ccnt[blockIdx.x * NDIG + t] = cv;
        bofsv[blockIdx.x * NDIG + t] = ex;
        h[t] = ex;
    }
    __syncthreads();
    // placement into digit-sorted LDS buffer
#pragma unroll
    for (int k = 0; k < P1_EPT; ++k) {
        if (dg[k] >= 0) {
            int pos = atomicAdd(&h[dg[k]], 1);
            rec[pos] = make_int2(key[k], val[k]);
        }
    }
    __syncthreads();
    // contiguous stream-out: full-line writes only
    int2* dst = coarse + (size_t)blockIdx.x * P1_EDGES;
    int nrec = 2 * E_NNZ - base_i;
    if (nrec > P1_EDGES) nrec = P1_EDGES;
    for (int j = t; j < nrec; j += P1_T) dst[j] = rec[j];
}

// per-digit totals over blocks
__global__ void digit_total_kernel(const int* __restrict__ cnt, int* __restrict__ tot) {
    int d = blockIdx.x * 256 + threadIdx.x;
    if (d >= NDIG) return;
    int run = 0;
    for (int b = 0; b < P1_BLOCKS; ++b) run += cnt[b * NDIG + d];
    tot[d] = run;
}

// exclusive scan of tot[NDIG] in place (becomes digit global base)
__global__ __launch_bounds__(1024) void scan_base_kernel(int* __restrict__ tot) {
    __shared__ int s[1024];
    int t = threadIdx.x;
    int v = (t < NDIG) ? tot[t] : 0;
    s[t] = v;
    __syncthreads();
    for (int off = 1; off < 1024; off <<= 1) {
        int x = (t >= off) ? s[t - off] : 0;
        __syncthreads();
        s[t] += x;
        __syncthreads();
    }
    if (t < NDIG) tot[t] = s[t] - v;
    if (t == 1023) tot[NDIG] = s[1023];   // = 2*E_NNZ
}

// ---------------- CSR build: pass 2 (fragment gather + LDS counting sort) -------

__global__ __launch_bounds__(P2_T) void p2_build_kernel(
        const int2* __restrict__ coarse, const int* __restrict__ ccnt,
        const int* __restrict__ bofsv, const int* __restrict__ basev,
        int* __restrict__ rpL, int* __restrict__ rpU,
        int2* __restrict__ edgeL, int2* __restrict__ edgeU) {
    __shared__ int pk[P2_CAP];
    __shared__ int vl[P2_CAP];
    __shared__ int hist[1024];
    __shared__ int sc[P2_T];
    __shared__ int fo[P1_BLOCKS];
    __shared__ int stot;
    int d = blockIdx.x;
    int t = threadIdx.x;
    // fragment table: len/ofs per pass-1 block
    int len = 0, ofs = 0;
    if (t < P1_BLOCKS) { len = ccnt[t * NDIG + d]; ofs = bofsv[t * NDIG + d]; }
    sc[t] = len;
    __syncthreads();
    for (int off = 1; off < P2_T; off <<= 1) {
        int x = (t >= off) ? sc[t - off] : 0;
        __syncthreads();
        sc[t] += x;
        __syncthreads();
    }
    if (t < P1_BLOCKS) { fo[t] = sc[t] - len; hist[t] = len; hist[512 + t] = ofs; }
    if (t == P1_BLOCKS - 1) stot = sc[t];
    __syncthreads();
    int sz = stot;
    if (sz > P2_CAP) sz = P2_CAP;   // never expected
    // cooperative fragment copy: wave w handles fragments b = w, w+8, ...
    int wv = t >> 6, lane = t & 63;
    for (int b = wv; b < P1_BLOCKS; b += P2_T / 64) {
        int L = hist[b], O = hist[512 + b], F = fo[b];
        const int2* sp = coarse + (size_t)b * P1_EDGES + O;
        for (int j = lane; j < L; j += 64) {
            int dst2 = F + j;
            if (dst2 < P2_CAP) {
                int2 r = sp[j];
                pk[dst2] = r.x;
                vl[dst2] = r.y;
            }
        }
    }
    __syncthreads();
    hist[t] = 0;
    hist[t + P2_T] = 0;
    __syncthreads();
    int myrank[P2_ITERS];
#pragma unroll
    for (int k = 0; k < P2_ITERS; ++k) {
        int j = k * P2_T + t;
        myrank[k] = (j < sz) ? atomicAdd(&hist[((unsigned)pk[j]) >> 22], 1) : 0;
    }
    __syncthreads();
    int h0 = hist[2 * t], h1 = hist[2 * t + 1];
    sc[t] = h0 + h1;
    __syncthreads();
    for (int off = 1; off < P2_T; off <<= 1) {
        int x = (t >= off) ? sc[t - off] : 0;
        __syncthreads();
        sc[t] += x;
        __syncthreads();
    }
    int pbase = sc[t] - (h0 + h1);   // exclusive prefix of bin pair
    __syncthreads();
    hist[2 * t] = pbase;
    hist[2 * t + 1] = pbase + h0;
    // rp write (2 rows per thread)
    int which = (d >= NDIG_HALF);
    int lbase = basev[d] - (which ? E_NNZ : 0);
    int rowbase = (which ? d - NDIG_HALF : d) << 10;
    int* rp = which ? rpU : rpL;
    int r0 = rowbase + 2 * t, r1 = r0 + 1;
    if (r0 < N_SIMP) rp[r0] = lbase + pbase;
    if (r1 < N_SIMP) rp[r1] = lbase + pbase + h0;
    __syncthreads();
    int2* eout = which ? edgeU : edgeL;
#pragma unroll
    for (int k = 0; k < P2_ITERS; ++k) {
        int j = k * P2_T + t;
        if (j < sz) {
            unsigned p = (unsigned)pk[j];
            int pos = lbase + hist[p >> 22] + myrank[k];
            eout[pos] = make_int2((int)(p & 0x3FFFFF), vl[j]);
        }
    }
}

// ---------------- small prep kernels ----------------

__global__ void combine_bias_kernel(const float* __restrict__ bh,
                                    const float* __restrict__ bl,
                                    const float* __restrict__ bu,
                                    float* __restrict__ out) {
    int h = threadIdx.x;
    float acc = bh[h];
    for (int k = 0; k < KAPPA; ++k) acc += bl[k * HDIM + h] + bu[k * HDIM + h];
    out[h] = acc;
}

__global__ void f32_to_bf16_kernel(const float* __restrict__ in, bf16* __restrict__ out) {
    int idx = blockIdx.x * 256 + threadIdx.x;   // per float4
    float4 v = ((const float4*)in)[idx];
    ushort4 w;
    w.x = f2bf(v.x); w.y = f2bf(v.y); w.z = f2bf(v.z); w.w = f2bf(v.w);
    ((ushort4*)out)[idx] = w;
}

// all 6 weight transposes in one dispatch; wt layout fixed (offsets in ushorts)
__global__ void wtrans_all_kernel(const float* __restrict__ s0, const float* __restrict__ s1,
                                  const float* __restrict__ s2, const float* __restrict__ s3,
                                  const float* __restrict__ s4, const float* __restrict__ s5,
                                  ushort* __restrict__ wt) {
    int idx = blockIdx.x * 256 + threadIdx.x;   // 0..43007
    const float* src; int Ktot, off;
    if (idx < 2048)       { src = s0; Ktot = 32;  off = 0; }
    else if (idx < 6144)  { src = s1; Ktot = 64;  off = 2048; }
    else if (idx < 12288) { src = s2; Ktot = 96;  off = 6144; }
    else if (idx < 18432) { src = s3; Ktot = 96;  off = 12288; }
    else if (idx < 30720) { src = s4; Ktot = 192; off = 18432; }
    else                  { src = s5; Ktot = 192; off = 30720; }
    int rel = idx - off;
    int n = rel / Ktot, kk = rel - n * Ktot;
    wt[idx] = f2bf(src[kk * 64 + n]);
}

// ---------------- SpMM (CSR gather) --------
// rp holds EXCLUSIVE row starts: s = rp[row], e = rp[row+1] (guarded at N-1)

// 32-wide: 4 lanes/row (8 ch each), 16 rows/wave, 64 rows/block
__global__ void spmm32_kernel(const int* __restrict__ rp, const int2* __restrict__ edge,
                              const bf16* __restrict__ srcb, int src_stride,
                              bf16* __restrict__ dstb) {
    const ushort* src = (const ushort*)srcb;
    ushort* dst = (ushort*)dstb;
    int tid = threadIdx.x;
    int lane = tid & 63;
    int wv = tid >> 6;
    int grp = lane >> 2;      // 0..15: row within wave
    int li = lane & 3;        // channels li*8 .. li*8+7
    int row = blockIdx.x * 64 + wv * 16 + grp;
    int s = rp[row];
    int e = (row == N_SIMP - 1) ? E_NNZ : rp[row + 1];
    int deg = e - s;
    float a[8] = {0.f, 0.f, 0.f, 0.f, 0.f, 0.f, 0.f, 0.f};
    if (deg > 0) {
        int2 ed[8];
#pragma unroll
        for (int t = 0; t < 8; ++t) {
            int j = s + t;
            ed[t] = edge[(j < e) ? j : (e - 1)];
        }
        u8v xs[8];
#pragma unroll
        for (int t = 0; t < 8; ++t)
            xs[t] = *(const u8v*)(src + (size_t)ed[t].x * src_stride + li * 8);
#pragma unroll
        for (int t = 0; t < 8; ++t) {
            float v = (t < deg) ? __int_as_float(ed[t].y) : 0.f;
#pragma unroll
            for (int c = 0; c < 8; ++c) a[c] += v * bf2f(xs[t][c]);
        }
        for (int j = s + 8; j < e; j += 4) {
            int2 e2[4];
#pragma unroll
            for (int t = 0; t < 4; ++t) {
                int jj = j + t;
                e2[t] = edge[(jj < e) ? jj : (e - 1)];
            }
            u8v x2[4];
#pragma unroll
            for (int t = 0; t < 4; ++t)
                x2[t] = *(const u8v*)(src + (size_t)e2[t].x * src_stride + li * 8);
#pragma unroll
            for (int t = 0; t < 4; ++t) {
                float v = (j + t < e) ? __int_as_float(e2[t].y) : 0.f;
#pragma unroll
                for (int c = 0; c < 8; ++c) a[c] += v * bf2f(x2[t][c]);
            }
        }
    }
    u8v w;
#pragma unroll
    for (int c = 0; c < 8; ++c) w[c] = f2bf(a[c]);
    *(u8v*)(dst + (size_t)row * 32 + li * 8) = w;
}

// 64-wide: 8 lanes/row (8 ch each), 8 rows/wave, 32 rows/block; stride 64
__global__ void spmm64_kernel(const int* __restrict__ rp, const int2* __restrict__ edge,
                              const bf16* __restrict__ srcb, bf16* __restrict__ dstb) {
    const ushort* src = (const ushort*)srcb;
    ushort* dst = (ushort*)dstb;
    int tid = threadIdx.x;
    int lane = tid & 63;
    int wv = tid >> 6;
    int grp = lane >> 3;      // 0..7: row within wave
    int li = lane & 7;        // channels li*8 .. li*8+7
    int row = blockIdx.x * 32 + wv * 8 + grp;
    int s = rp[row];
    int e = (row == N_SIMP - 1) ? E_NNZ : rp[row + 1];
    int deg = e - s;
    float a[8] = {0.f, 0.f, 0.f, 0.f, 0.f, 0.f, 0.f, 0.f};
    if (deg > 0) {
        int2 ed[8];
#pragma unroll
        for (int t = 0; t < 8; ++t) {
            int j = s + t;
            ed[t] = edge[(j < e) ? j : (e - 1)];
        }
        u8v xs[8];
#pragma unroll
        for (int t = 0; t < 8; ++t)
            xs[t] = *(const u8v*)(src + (size_t)ed[t].x * 64 + li * 8);
#pragma unroll
        for (int t = 0; t < 8; ++t) {
            float v = (t < deg) ? __int_as_float(ed[t].y) : 0.f;
#pragma unroll
            for (int c = 0; c < 8; ++c) a[c] += v * bf2f(xs[t][c]);
        }
        for (int j = s + 8; j < e; j += 4) {
            int2 e2[4];
#pragma unroll
            for (int t = 0; t < 4; ++t) {
                int jj = j + t;
                e2[t] = edge[(jj < e) ? jj : (e - 1)];
            }
            u8v x2[4];
#pragma unroll
            for (int t = 0; t < 4; ++t)
                x2[t] = *(const u8v*)(src + (size_t)e2[t].x * 64 + li * 8);
#pragma unroll
            for (int t = 0; t < 4; ++t) {
                float v = (j + t < e) ? __int_as_float(e2[t].y) : 0.f;
#pragma unroll
                for (int c = 0; c < 8; ++c) a[c] += v * bf2f(x2[t][c]);
            }
        }
    }
    u8v w;
#pragma unroll
    for (int c = 0; c < 8; ++c) w[c] = f2bf(a[c]);
    *(u8v*)(dst + (size_t)row * 64 + li * 8) = w;
}

// ---------------- MFMA GEMM: z[N,64] (fp16) (=bias+ / +=) A[N, NCH*32] @ W -------
// up to 6 A-channel sources; W split into two groups (Wt1 for ch<NCH1, Wt2 rest)

template <int NCH, int NCH1, bool INIT>
__global__ __launch_bounds__(256) void mfma_gemm_kernel(
        const ushort* __restrict__ s0, int st0,
        const ushort* __restrict__ s1, int st1,
        const ushort* __restrict__ s2, int st2,
        const ushort* __restrict__ s3, int st3,
        const ushort* __restrict__ s4, int st4,
        const ushort* __restrict__ s5, int st5,
        const ushort* __restrict__ Wt1, int Kstride1,
        const ushort* __restrict__ Wt2, int Kstride2,
        const float* __restrict__ bias,
        f16* __restrict__ z) {
    int tid = threadIdx.x;
    int wv = tid >> 6, lane = tid & 63;
    int quad = lane >> 4, n = lane & 15;
    int rowbase = blockIdx.x * 64 + wv * 16;
    int arow = rowbase + n;  // A-operand row m = lane&15

    f4v acc0 = {0.f, 0.f, 0.f, 0.f};
    f4v acc1 = {0.f, 0.f, 0.f, 0.f};
    f4v acc2 = {0.f, 0.f, 0.f, 0.f};
    f4v acc3 = {0.f, 0.f, 0.f, 0.f};

#pragma unroll
    for (int ch = 0; ch < NCH; ++ch) {
        const ushort* sp = (ch == 0) ? s0 : (ch == 1) ? s1 : (ch == 2) ? s2
                         : (ch == 3) ? s3 : (ch == 4) ? s4 : s5;
        int st = (ch == 0) ? st0 : (ch == 1) ? st1 : (ch == 2) ? st2
               : (ch == 3) ? st3 : (ch == 4) ? st4 : st5;
        const ushort* wb = (ch < NCH1) ? (Wt1 + ch * 32) : (Wt2 + (ch - NCH1) * 32);
        int Ks = (ch < NCH1) ? Kstride1 : Kstride2;
        s8v a = *(const s8v*)(sp + (size_t)arow * st + quad * 8);
        const ushort* wq = wb + quad * 8;
        s8v b0 = *(const s8v*)(wq + (size_t)(0 * 16 + n) * Ks);
        s8v b1 = *(const s8v*)(wq + (size_t)(1 * 16 + n) * Ks);
        s8v b2 = *(const s8v*)(wq + (size_t)(2 * 16 + n) * Ks);
        s8v b3 = *(const s8v*)(wq + (size_t)(3 * 16 + n) * Ks);
        acc0 = __builtin_amdgcn_mfma_f32_16x16x32_bf16(a, b0, acc0, 0, 0, 0);
        acc1 = __builtin_amdgcn_mfma_f32_16x16x32_bf16(a, b1, acc1, 0, 0, 0);
        acc2 = __builtin_amdgcn_mfma_f32_16x16x32_bf16(a, b2, acc2, 0, 0, 0);
        acc3 = __builtin_amdgcn_mfma_f32_16x16x32_bf16(a, b3, acc3, 0, 0, 0);
    }
    // C/D layout: col = lane&15, row = quad*4 + reg
#pragma unroll
    for (int r = 0; r < 4; ++r) {
        int orow = rowbase + quad * 4 + r;
        f16* zp = z + (size_t)orow * 64 + n;
        if (INIT) {
            zp[0]  = (f16)(bias[n]      + acc0[r]);
            zp[16] = (f16)(bias[16 + n] + acc1[r]);
            zp[32] = (f16)(bias[32 + n] + acc2[r]);
            zp[48] = (f16)(bias[48 + n] + acc3[r]);
        } else {
            zp[0]  = (f16)((float)zp[0]  + acc0[r]);
            zp[16] = (f16)((float)zp[16] + acc1[r]);
            zp[32] = (f16)((float)zp[32] + acc2[r]);
            zp[48] = (f16)((float)zp[48] + acc3[r]);
        }
    }
}

// ---------------- BN / pool / MLP (vectorized) ----------------

__global__ void bn_stats_kernel(const f16* __restrict__ z, double* __restrict__ stats) {
    __shared__ float ss[256 * 8], qq[256 * 8];
    int tid = threadIdx.x;
    const h8v* z8 = (const h8v*)z;
    const int total8 = N_SIMP * HDIM / 8;
    float fs[8] = {0, 0, 0, 0, 0, 0, 0, 0};
    float fq[8] = {0, 0, 0, 0, 0, 0, 0, 0};
    for (int i = blockIdx.x * 256 + tid; i < total8; i += (int)gridDim.x * 256) {
        h8v v = z8[i];
#pragma unroll
        for (int c = 0; c < 8; ++c) {
            float f = (float)v[c];
            fs[c] += f;
            fq[c] += f * f;
        }
    }
#pragma unroll
    for (int c = 0; c < 8; ++c) { ss[tid * 8 + c] = fs[c]; qq[tid * 8 + c] = fq[c]; }
    __syncthreads();
    if (tid < 64) {
        // channel tid: contributions from threads t with (t&7)==tid>>3, slot tid&7
        int sel = tid >> 3, slot = tid & 7;
        double a = 0.0, b = 0.0;
#pragma unroll 8
        for (int k = 0; k < 32; ++k) {
            int t = sel + (k << 3);
            a += (double)ss[t * 8 + slot];
            b += (double)qq[t * 8 + slot];
        }
        atomicAdd(&stats[tid], a);
        atomicAdd(&stats[64 + tid], b);
    }
}

// layer-0: h0bf = bf16(elu(bn(z)))
__global__ void bn_elu_bf16_kernel(const f16* __restrict__ z, const double* __restrict__ stats,
                                   const float* __restrict__ gamma, const float* __restrict__ beta,
                                   bf16* __restrict__ out) {
    __shared__ float scale_s[64], shift_s[64];
    int tid = threadIdx.x;
    if (tid < 64) {
        double mean = stats[tid] / (double)N_SIMP;
        double var = stats[64 + tid] / (double)N_SIMP - mean * mean;
        double sc = (double)gamma[tid] / sqrt(var + BN_EPS);
        scale_s[tid] = (float)sc;
        shift_s[tid] = (float)((double)beta[tid] - mean * sc);
    }
    __syncthreads();
    const h8v* z8 = (const h8v*)z;
    u8v* o8 = (u8v*)out;
    const int total8 = N_SIMP * HDIM / 8;
    int hb = (tid & 7) * 8;
    for (int i = blockIdx.x * 256 + tid; i < total8; i += (int)gridDim.x * 256) {
        h8v v = z8[i];
        u8v w;
#pragma unroll
        for (int c = 0; c < 8; ++c)
            w[c] = f2bf(elu_f((float)v[c] * scale_s[hb + c] + shift_s[hb + c]));
        o8[i] = w;
    }
}

// fused bn1 + elu + global max/mean pool: reads raw z, applies elu(bn(z)) inline.
// 8 lanes/row (h8v = 16B each), 32 rows in flight per 256-thread block.
__global__ void pool_bn_kernel(const f16* __restrict__ zbuf, const int* __restrict__ bidx,
                               const double* __restrict__ stats,
                               const float* __restrict__ gamma, const float* __restrict__ beta,
                               float* __restrict__ gbuf) {
    __shared__ float scale_s[64], shift_s[64];
    __shared__ float pmax[256 * 8], psum[256 * 8];
    int tid = threadIdx.x;
    if (tid < 64) {
        double mean = stats[tid] / (double)N_SIMP;
        double var = stats[64 + tid] / (double)N_SIMP - mean * mean;
        double sc = (double)gamma[tid] / sqrt(var + BN_EPS);
        scale_s[tid] = (float)sc;
        shift_s[tid] = (float)((double)beta[tid] - mean * sc);
    }
    __syncthreads();
    int g = blockIdx.x;
    int lo = 0, hi = N_SIMP;
    while (lo < hi) { int mid = (lo + hi) >> 1; if (bidx[mid] < g) lo = mid + 1; else hi = mid; }
    int start = lo;
    hi = N_SIMP;
    while (lo < hi) { int mid = (lo + hi) >> 1; if (bidx[mid] < g + 1) lo = mid + 1; else hi = mid; }
    int end = lo;
    int li = tid & 7;        // channel block: li*8 .. li*8+7
    int rr = tid >> 3;       // row offset 0..31
    const h8v* z8 = (const h8v*)zbuf;
    float mx[8], sm[8];
#pragma unroll
    for (int c = 0; c < 8; ++c) { mx[c] = -INFINITY; sm[c] = 0.f; }
    float sc8[8], sh8[8];
#pragma unroll
    for (int c = 0; c < 8; ++c) { sc8[c] = scale_s[li * 8 + c]; sh8[c] = shift_s[li * 8 + c]; }
    for (int i = start + rr; i < end; i += 32) {
        h8v v = z8[(size_t)i * 8 + li];
#pragma unroll
        for (int c = 0; c < 8; ++c) {
            float y = elu_f((float)v[c] * sc8[c] + sh8[c]);
            mx[c] = fmaxf(mx[c], y);
            sm[c] += y;
        }
    }
#pragma unroll
    for (int c = 0; c < 8; ++c) { pmax[tid * 8 + c] = mx[c]; psum[tid * 8 + c] = sm[c]; }
    __syncthreads();
    if (tid < 64) {
        int sel = tid >> 3, slot = tid & 7;   // li = sel, c = slot
        float m = -INFINITY, s = 0.f;
#pragma unroll 8
        for (int k = 0; k < 32; ++k) {
            int t = k * 8 + sel;
            m = fmaxf(m, pmax[t * 8 + slot]);
            s += psum[t * 8 + slot];
        }
        int cnt = end - start;
        float mean = s / fmaxf((float)cnt, 1.f);
        gbuf[g * 128 + tid] = elu_f(m);
        gbuf[g * 128 + 64 + tid] = elu_f(mean);
    }
}

__global__ void mlp_kernel(const float* __restrict__ gbuf, const float* __restrict__ W1,
                           const float* __restrict__ b1, const float* __restrict__ W2,
                           const float* __restrict__ b2, float* __restrict__ out) {
    __shared__ float gs[128];
    __shared__ float hs[64];
    int g = blockIdx.x, tid = threadIdx.x;
    gs[tid] = gbuf[g * 128 + tid];
    gs[64 + tid] = gbuf[g * 128 + 64 + tid];
    __syncthreads();
    float acc = b1[tid];
#pragma unroll
    for (int k = 0; k < 128; ++k) acc += gs[k] * W1[k * 64 + tid];
    hs[tid] = fmaxf(acc, 0.f);
    __syncthreads();
    if (tid < 8) {
        float o = b2[tid];
#pragma unroll
        for (int k = 0; k < 64; ++k) o += hs[k] * W2[k * 8 + tid];
        out[g * 8 + tid] = o;
    }
}

// ---------------- host side ----------------

extern "C" void kernel_launch(void* const* d_in, const int* in_sizes, int n_in,
                              void* d_out, int out_size, void* d_ws, size_t ws_size,
                              hipStream_t stream) {
    const float* x     = (const float*)d_in[0];
    const int*   li    = (const int*)d_in[1];
    const float* lv    = (const float*)d_in[2];
    const int*   ui    = (const int*)d_in[3];
    const float* uv    = (const float*)d_in[4];
    const int*   bidx  = (const int*)d_in[5];
    const float* l0_Wl = (const float*)d_in[6];
    const float* l0_bl = (const float*)d_in[7];
    const float* l0_Wu = (const float*)d_in[8];
    const float* l0_bu = (const float*)d_in[9];
    const float* l0_Wh = (const float*)d_in[10];
    const float* l0_bh = (const float*)d_in[11];
    const float* l1_Wl = (const float*)d_in[12];
    const float* l1_bl = (const float*)d_in[13];
    const float* l1_Wu = (const float*)d_in[14];
    const float* l1_bu = (const float*)d_in[15];
    const float* l1_Wh = (const float*)d_in[16];
    const float* l1_bh = (const float*)d_in[17];
    const float* bn0_g = (const float*)d_in[18];
    const float* bn0_b = (const float*)d_in[19];
    const float* bn1_g = (const float*)d_in[20];
    const float* bn1_b = (const float*)d_in[21];
    const float* mW1   = (const float*)d_in[22];
    const float* mb1   = (const float*)d_in[23];
    const float* mW2   = (const float*)d_in[24];
    const float* mb2   = (const float*)d_in[25];
    float* out = (float*)d_out;

    // ---- workspace layout (total ~246.8 MB <= 256 MiB) ----
    char* base = (char*)d_ws;
    f16*   z     = (f16*)base;                                    //  51,200,000
    bf16*  h0bf  = (bf16*)(base + 51200000ull);                   //  51,200,000
    bf16*  g1    = (bf16*)(base + 102400000ull);                  //  51,200,000
    bf16*  g2    = (bf16*)(base + 153600000ull);                  //  51,200,000
    int2*  edgeL = (int2*)(base + 204800000ull);                  //  19,200,000
    int2*  edgeU = (int2*)(base + 224000000ull);                  //  19,200,000
    int*   rpL   = (int*)(base + 243200000ull);                   //   1,600,032
    int*   rpU   = (int*)(base + 244800032ull);                   //   1,600,032
    double* stats = (double*)(base + 246404160ull);               //   1 KB
    float* cbias  = (float*)(base + 246405184ull);                //   256 B
    float* gbuf   = (float*)(base + 246405440ull);                //   262,144
    ushort* wt    = (ushort*)(base + 246667584ull);               //   86,016

    // CSR-build scratch aliases (regions dead during build):
    //  z region   : coarse 38.4 MB + basev 3.1 KB
    //  h0bf region: ccnt 916 KB + bofs 916 KB
    int2* coarse = (int2*)base;                                   // 38,404,096
    int*  basev  = (int*)(base + 38500000ull);                    // (NDIG+1)*4
    int*  ccnt   = (int*)(base + 51200000ull);                    // 916,504
    int*  bofsv  = (int*)(base + 52200000ull);                    // 916,504

    // layer-0 scratch: 6 slots of N*32 bf16 in g1/g2/h0bf regions
    bf16* xbf  = g1;                                 // g1 slot 0 (later cCU)
    bf16* cAL  = g1 + (size_t)N_SIMP * 32;           // g1 slot 1
    bf16* cBL  = g2;                                 // g2 slot 0
    bf16* cCL  = g2 + (size_t)N_SIMP * 32;           // g2 slot 1
    bf16* cAU  = h0bf;                               // h0 slot 0
    bf16* cBU  = h0bf + (size_t)N_SIMP * 32;         // h0 slot 1
    bf16* cCU  = g1;                                 // reuses xbf slot (xbf dead)

    // weight-transpose sub-buffers (ushort elements; offsets match wtrans_all_kernel)
    ushort* wt_l0h = wt;            // 64 x 32
    ushort* wt_l1h = wt + 2048;     // 64 x 64
    ushort* wt_l0l = wt + 6144;     // 64 x 96
    ushort* wt_l0u = wt + 12288;    // 64 x 96
    ushort* wt_l1l = wt + 18432;    // 64 x 192
    ushort* wt_l1u = wt + 30720;    // 64 x 192

    const int SP32_BLOCKS = N_SIMP / 64;   // 6,250
    const int SP64_BLOCKS = N_SIMP / 32;   // 12,500
    const int MF_BLOCKS   = N_SIMP / 64;   // 6,250

    // ---- prep: weight transposes (one dispatch) + x->bf16 ----
    wtrans_all_kernel<<<168, 256, 0, stream>>>(l0_Wh, l1_Wh, l0_Wl, l0_Wu, l1_Wl, l1_Wu, wt);
    f32_to_bf16_kernel<<<N_SIMP * 32 / 4 / 256, 256, 0, stream>>>(x, xbf);

    // ---- CSR builds: in-LDS block sort + fragment-gather bucket sort ----
    p1_sort_kernel<<<P1_BLOCKS, P1_T, 0, stream>>>(li, lv, ui, uv, ccnt, bofsv, coarse);
    digit_total_kernel<<<(NDIG + 255) / 256, 256, 0, stream>>>(ccnt, basev);
    scan_base_kernel<<<1, 1024, 0, stream>>>(basev);
    p2_build_kernel<<<NDIG, P2_T, 0, stream>>>(coarse, ccnt, bofsv, basev,
                                               rpL, rpU, edgeL, edgeU);

    const ushort* xbfu = (const ushort*)xbf;
    const ushort* h0u  = (const ushort*)h0bf;
    const ushort* g1u  = (const ushort*)g1;
    const ushort* g2u  = (const ushort*)g2;

    // ---------------- layer 0 (F_IN=32 -> H=64) ----------------
    combine_bias_kernel<<<1, 64, 0, stream>>>(l0_bh, l0_bl, l0_bu, cbias);
    mfma_gemm_kernel<1, 1, true><<<MF_BLOCKS, 256, 0, stream>>>(
        xbfu, 32, nullptr, 0, nullptr, 0, nullptr, 0, nullptr, 0, nullptr, 0,
        wt_l0h, 32, wt_l0h, 32, cbias, z);

    // lower chain
    spmm32_kernel<<<SP32_BLOCKS, 256, 0, stream>>>(rpL, edgeL, xbf, 32, cAL);
    spmm32_kernel<<<SP32_BLOCKS, 256, 0, stream>>>(rpL, edgeL, cAL, 32, cBL);
    spmm32_kernel<<<SP32_BLOCKS, 256, 0, stream>>>(rpL, edgeL, cBL, 32, cCL);
    // upper chain (cAU spmm reads xbf before cCU overwrites that slot)
    spmm32_kernel<<<SP32_BLOCKS, 256, 0, stream>>>(rpU, edgeU, xbf, 32, cAU);
    spmm32_kernel<<<SP32_BLOCKS, 256, 0, stream>>>(rpU, edgeU, cAU, 32, cBU);
    spmm32_kernel<<<SP32_BLOCKS, 256, 0, stream>>>(rpU, edgeU, cBU, 32, cCU);
    // single accumulate-GEMM over all 6 chain outputs
    mfma_gemm_kernel<6, 3, false><<<MF_BLOCKS, 256, 0, stream>>>(
        (const ushort*)cAL, 32, (const ushort*)cBL, 32, (const ushort*)cCL, 32,
        (const ushort*)cAU, 32, (const ushort*)cBU, 32, (const ushort*)cCU, 32,
        wt_l0l, 96, wt_l0u, 96, nullptr, z);

    (void)hipMemsetAsync(stats, 0, 128 * sizeof(double), stream);
    bn_stats_kernel<<<1024, 256, 0, stream>>>(z, stats);
    bn_elu_bf16_kernel<<<1024, 256, 0, stream>>>(z, stats, bn0_g, bn0_b, h0bf);

    // ---------------- layer 1 (H=64 -> H=64), 64-wide chains ----------------
    combine_bias_kernel<<<1, 64, 0, stream>>>(l1_bh, l1_bl, l1_bu, cbias);

    // u1 = L h0 -> g1 ; u2 = L u1 -> g2
    spmm64_kernel<<<SP64_BLOCKS, 256, 0, stream>>>(rpL, edgeL, h0bf, g1);
    spmm64_kernel<<<SP64_BLOCKS, 256, 0, stream>>>(rpL, edgeL, g1, g2);
    // gemm A (INIT): h0 (wt_l1h), u1+u2 (wt_l1l K 0-127), + bias
    mfma_gemm_kernel<6, 2, true><<<MF_BLOCKS, 256, 0, stream>>>(
        h0u, 64, h0u + 32, 64, g1u, 64, g1u + 32, 64, g2u, 64, g2u + 32, 64,
        wt_l1h, 64, wt_l1l, 192, cbias, z);
    // u3 = L u2 -> g1 ; v1 = U h0 -> g2
    spmm64_kernel<<<SP64_BLOCKS, 256, 0, stream>>>(rpL, edgeL, g2, g1);
    spmm64_kernel<<<SP64_BLOCKS, 256, 0, stream>>>(rpU, edgeU, h0bf, g2);
    // gemm B: u3 (wt_l1l K 128-191), v1 (wt_l1u K 0-63)
    mfma_gemm_kernel<4, 2, false><<<MF_BLOCKS, 256, 0, stream>>>(
        g1u, 64, g1u + 32, 64, g2u, 64, g2u + 32, 64, nullptr, 0, nullptr, 0,
        wt_l1l + 128, 192, wt_l1u, 192, nullptr, z);
    // v2 = U v1 -> g1 ; v3 = U v2 -> g2
    spmm64_kernel<<<SP64_BLOCKS, 256, 0, stream>>>(rpU, edgeU, g2, g1);
    spmm64_kernel<<<SP64_BLOCKS, 256, 0, stream>>>(rpU, edgeU, g1, g2);
    // gemm C: v2 (K 64-127), v3 (K 128-191) of wt_l1u
    mfma_gemm_kernel<4, 4, false><<<MF_BLOCKS, 256, 0, stream>>>(
        g1u, 64, g1u + 32, 64, g2u, 64, g2u + 32, 64, nullptr, 0, nullptr, 0,
        wt_l1u + 64, 192, wt_l1u + 64, 192, nullptr, z);

    (void)hipMemsetAsync(stats, 0, 128 * sizeof(double), stream);
    bn_stats_kernel<<<1024, 256, 0, stream>>>(z, stats);

    // ---------------- fused bn1+elu+pool, then MLP ----------------
    pool_bn_kernel<<<G_NUM, 256, 0, stream>>>(z, bidx, stats, bn1_g, bn1_b, gbuf);
    mlp_kernel<<<G_NUM, 64, 0, stream>>>(gbuf, mW1, mb1, mW2, mb2, out);
}

// Round 8
// 1196.759 us; speedup vs baseline: 1.5726x; 1.1067x over previous
//
#include <hip/hip_runtime.h>
#include <hip/hip_bf16.h>
#include <math.h>

#define N_SIMP 400000
#define E_NNZ  2400000
#define FIN    32
#define HDIM   64
#define KAPPA  3
#define G_NUM  512
#define NOUT   8
#define BN_EPS 1e-5

// ---- CSR build (two-level LDS counting sort; pass-1 sorts fully in LDS) ----
#define NDIG_HALF 391             // ceil(400000/1024) coarse buckets per matrix
#define NDIG      782             // L + U
#define P1_EDGES  16384           // edges per pass-1 block (16/thread @ 1024 thr)
#define P1_BLOCKS 293             // ceil(4.8M / 16384)
#define P1_T      1024
#define P1_EPT    16
#define P2_CAP    7168            // bucket capacity (avg 6144, +13 sigma headroom)
#define P2_T      512
#define P2_ITERS  14              // P2_CAP / P2_T

typedef __hip_bfloat16 bf16;
typedef _Float16 f16;
typedef short s8v __attribute__((ext_vector_type(8)));    // 8 bf16 in 4 VGPRs
typedef ushort u8v __attribute__((ext_vector_type(8)));   // 8 bf16 raw
typedef _Float16 h8v __attribute__((ext_vector_type(8))); // 8 f16
typedef float f4v __attribute__((ext_vector_type(4)));

__device__ __forceinline__ float elu_f(float x) {
    return x > 0.f ? x : expm1f(x);
}
__device__ __forceinline__ float bf2f(ushort u) {
    return __uint_as_float(((unsigned int)u) << 16);
}
__device__ __forceinline__ ushort f2bf(float f) {
    bf16 h = (bf16)f;
    return *(ushort*)&h;
}

// ---------------- CSR build: pass 1 (full in-LDS counting sort per block) -------

__global__ __launch_bounds__(P1_T, 1) void p1_sort_kernel(
        const int* __restrict__ eiL, const float* __restrict__ lv,
        const int* __restrict__ eiU, const float* __restrict__ uv,
        int* __restrict__ ccnt, int* __restrict__ bofsv,
        int2* __restrict__ coarse) {
    __shared__ int2 rec[P1_EDGES];   // 128 KB
    __shared__ int h[NDIG];          // counts -> running offsets
    __shared__ int hscan[P1_T];      // scan scratch
    int t = threadIdx.x;
    for (int j = t; j < NDIG; j += P1_T) h[j] = 0;
    __syncthreads();
    int base_i = blockIdx.x * P1_EDGES;
    int key[P1_EPT], val[P1_EPT], dg[P1_EPT];
#pragma unroll
    for (int k = 0; k < P1_EPT; ++k) {
        int i = base_i + k * P1_T + t;
        int dd = -1;
        if (i < 2 * E_NNZ) {
            int row, col;
            float v;
            if (i < E_NNZ) {
                row = eiL[i]; col = eiL[E_NNZ + i]; v = lv[i];
                dd = row >> 10;
            } else {
                int e = i - E_NNZ;
                row = eiU[e]; col = eiU[E_NNZ + e]; v = uv[e];
                dd = NDIG_HALF + (row >> 10);
            }
            key[k] = ((row & 1023) << 22) | col;
            val[k] = __float_as_int(v);
            atomicAdd(&h[dd], 1);
        }
        dg[k] = dd;
    }
    __syncthreads();
    // scan the 782 counts (1024-thread Hillis-Steele); emit ccnt/bofs; h := excl.
    int cv = (t < NDIG) ? h[t] : 0;
    hscan[t] = cv;
    __syncthreads();
    for (int off = 1; off < P1_T; off <<= 1) {
        int x = (t >= off) ? hscan[t - off] : 0;
        __syncthreads();
        hscan[t] += x;
        __syncthreads();
    }
    if (t < NDIG) {
        int ex = hscan[t] - cv;
        ccnt[blockIdx.x * NDIG + t] = cv;
        bofsv[blockIdx.x * NDIG + t] = ex;
        h[t] = ex;
    }
    __syncthreads();
    // placement into digit-sorted LDS buffer
#pragma unroll
    for (int k = 0; k < P1_EPT; ++k) {
        if (dg[k] >= 0) {
            int pos = atomicAdd(&h[dg[k]], 1);
            rec[pos] = make_int2(key[k], val[k]);
        }
    }
    __syncthreads();
    // contiguous stream-out: full-line writes only
    int2* dst = coarse + (size_t)blockIdx.x * P1_EDGES;
    int nrec = 2 * E_NNZ - base_i;
    if (nrec > P1_EDGES) nrec = P1_EDGES;
    for (int j = t; j < nrec; j += P1_T) dst[j] = rec[j];
}

// per-digit totals over blocks
__global__ void digit_total_kernel(const int* __restrict__ cnt, int* __restrict__ tot) {
    int d = blockIdx.x * 256 + threadIdx.x;
    if (d >= NDIG) return;
    int run = 0;
    for (int b = 0; b < P1_BLOCKS; ++b) run += cnt[b * NDIG + d];
    tot[d] = run;
}

// exclusive scan of tot[NDIG] in place (becomes digit global base)
__global__ __launch_bounds__(1024) void scan_base_kernel(int* __restrict__ tot) {
    __shared__ int s[1024];
    int t = threadIdx.x;
    int v = (t < NDIG) ? tot[t] : 0;
    s[t] = v;
    __syncthreads();
    for (int off = 1; off < 1024; off <<= 1) {
        int x = (t >= off) ? s[t - off] : 0;
        __syncthreads();
        s[t] += x;
        __syncthreads();
    }
    if (t < NDIG) tot[t] = s[t] - v;
    if (t == 1023) tot[NDIG] = s[1023];   // = 2*E_NNZ
}

// ---------------- CSR build: pass 2 (fragment gather + LDS counting sort) -------

__global__ __launch_bounds__(P2_T) void p2_build_kernel(
        const int2* __restrict__ coarse, const int* __restrict__ ccnt,
        const int* __restrict__ bofsv, const int* __restrict__ basev,
        int* __restrict__ rpL, int* __restrict__ rpU,
        int2* __restrict__ edgeL, int2* __restrict__ edgeU) {
    __shared__ int pk[P2_CAP];
    __shared__ int vl[P2_CAP];
    __shared__ int hist[1024];
    __shared__ int sc[P2_T];
    __shared__ int fo[P1_BLOCKS];
    __shared__ int stot;
    int d = blockIdx.x;
    int t = threadIdx.x;
    // fragment table: len/ofs per pass-1 block
    int len = 0, ofs = 0;
    if (t < P1_BLOCKS) { len = ccnt[t * NDIG + d]; ofs = bofsv[t * NDIG + d]; }
    sc[t] = len;
    __syncthreads();
    for (int off = 1; off < P2_T; off <<= 1) {
        int x = (t >= off) ? sc[t - off] : 0;
        __syncthreads();
        sc[t] += x;
        __syncthreads();
    }
    if (t < P1_BLOCKS) { fo[t] = sc[t] - len; hist[t] = len; hist[512 + t] = ofs; }
    if (t == P1_BLOCKS - 1) stot = sc[t];
    __syncthreads();
    int sz = stot;
    if (sz > P2_CAP) sz = P2_CAP;   // never expected
    // cooperative fragment copy: wave w handles fragments b = w, w+8, ...
    int wv = t >> 6, lane = t & 63;
    for (int b = wv; b < P1_BLOCKS; b += P2_T / 64) {
        int L = hist[b], O = hist[512 + b], F = fo[b];
        const int2* sp = coarse + (size_t)b * P1_EDGES + O;
        for (int j = lane; j < L; j += 64) {
            int dst2 = F + j;
            if (dst2 < P2_CAP) {
                int2 r = sp[j];
                pk[dst2] = r.x;
                vl[dst2] = r.y;
            }
        }
    }
    __syncthreads();
    hist[t] = 0;
    hist[t + P2_T] = 0;
    __syncthreads();
    int myrank[P2_ITERS];
#pragma unroll
    for (int k = 0; k < P2_ITERS; ++k) {
        int j = k * P2_T + t;
        myrank[k] = (j < sz) ? atomicAdd(&hist[((unsigned)pk[j]) >> 22], 1) : 0;
    }
    __syncthreads();
    int h0 = hist[2 * t], h1 = hist[2 * t + 1];
    sc[t] = h0 + h1;
    __syncthreads();
    for (int off = 1; off < P2_T; off <<= 1) {
        int x = (t >= off) ? sc[t - off] : 0;
        __syncthreads();
        sc[t] += x;
        __syncthreads();
    }
    int pbase = sc[t] - (h0 + h1);   // exclusive prefix of bin pair
    __syncthreads();
    hist[2 * t] = pbase;
    hist[2 * t + 1] = pbase + h0;
    // rp write (2 rows per thread)
    int which = (d >= NDIG_HALF);
    int lbase = basev[d] - (which ? E_NNZ : 0);
    int rowbase = (which ? d - NDIG_HALF : d) << 10;
    int* rp = which ? rpU : rpL;
    int r0 = rowbase + 2 * t, r1 = r0 + 1;
    if (r0 < N_SIMP) rp[r0] = lbase + pbase;
    if (r1 < N_SIMP) rp[r1] = lbase + pbase + h0;
    __syncthreads();
    int2* eout = which ? edgeU : edgeL;
#pragma unroll
    for (int k = 0; k < P2_ITERS; ++k) {
        int j = k * P2_T + t;
        if (j < sz) {
            unsigned p = (unsigned)pk[j];
            int pos = lbase + hist[p >> 22] + myrank[k];
            eout[pos] = make_int2((int)(p & 0x3FFFFF), vl[j]);
        }
    }
}

// ---------------- small prep kernels ----------------

__global__ void combine_bias_kernel(const float* __restrict__ bh,
                                    const float* __restrict__ bl,
                                    const float* __restrict__ bu,
                                    float* __restrict__ out) {
    int h = threadIdx.x;
    float acc = bh[h];
    for (int k = 0; k < KAPPA; ++k) acc += bl[k * HDIM + h] + bu[k * HDIM + h];
    out[h] = acc;
}

__global__ void f32_to_bf16_kernel(const float* __restrict__ in, bf16* __restrict__ out) {
    int idx = blockIdx.x * 256 + threadIdx.x;   // per float4
    float4 v = ((const float4*)in)[idx];
    ushort4 w;
    w.x = f2bf(v.x); w.y = f2bf(v.y); w.z = f2bf(v.z); w.w = f2bf(v.w);
    ((ushort4*)out)[idx] = w;
}

// all 6 weight transposes -> MFMA FRAGMENT layout, one dispatch.
// wfrag[(ch*4+nblk)*512 + lane*8 + j] = W[k = ch*32 + (lane>>4)*8 + j][nblk*16 + (lane&15)]
// => every B-load in the GEMM is a dense 1KB contiguous wave-read (L1-resident).
__global__ void wtrans_all_kernel(const float* __restrict__ s0, const float* __restrict__ s1,
                                  const float* __restrict__ s2, const float* __restrict__ s3,
                                  const float* __restrict__ s4, const float* __restrict__ s5,
                                  ushort* __restrict__ wt) {
    int idx = blockIdx.x * 256 + threadIdx.x;   // 0..43007
    const float* src; int off;
    if (idx < 2048)       { src = s0; off = 0; }
    else if (idx < 6144)  { src = s1; off = 2048; }
    else if (idx < 12288) { src = s2; off = 6144; }
    else if (idx < 18432) { src = s3; off = 12288; }
    else if (idx < 30720) { src = s4; off = 18432; }
    else                  { src = s5; off = 30720; }
    int rel = idx - off;
    int frag = rel >> 9;          // ch*4 + nblk
    int r = rel & 511;
    int lane = r >> 3, j = r & 7;
    int q = lane >> 4, n = lane & 15;
    int ch = frag >> 2, nblk = frag & 3;
    int k = ch * 32 + q * 8 + j;
    int nout = nblk * 16 + n;
    wt[idx] = f2bf(src[k * 64 + nout]);
}

// ---------------- SpMM (CSR gather) --------
// rp holds EXCLUSIVE row starts: s = rp[row], e = rp[row+1] (guarded at N-1)

// 32-wide: 4 lanes/row (8 ch each), 16 rows/wave, 64 rows/block
__global__ void spmm32_kernel(const int* __restrict__ rp, const int2* __restrict__ edge,
                              const bf16* __restrict__ srcb, int src_stride,
                              bf16* __restrict__ dstb) {
    const ushort* src = (const ushort*)srcb;
    ushort* dst = (ushort*)dstb;
    int tid = threadIdx.x;
    int lane = tid & 63;
    int wv = tid >> 6;
    int grp = lane >> 2;      // 0..15: row within wave
    int li = lane & 3;        // channels li*8 .. li*8+7
    int row = blockIdx.x * 64 + wv * 16 + grp;
    int s = rp[row];
    int e = (row == N_SIMP - 1) ? E_NNZ : rp[row + 1];
    int deg = e - s;
    float a[8] = {0.f, 0.f, 0.f, 0.f, 0.f, 0.f, 0.f, 0.f};
    if (deg > 0) {
        int2 ed[8];
#pragma unroll
        for (int t = 0; t < 8; ++t) {
            int j = s + t;
            ed[t] = edge[(j < e) ? j : (e - 1)];
        }
        u8v xs[8];
#pragma unroll
        for (int t = 0; t < 8; ++t)
            xs[t] = *(const u8v*)(src + (size_t)ed[t].x * src_stride + li * 8);
#pragma unroll
        for (int t = 0; t < 8; ++t) {
            float v = (t < deg) ? __int_as_float(ed[t].y) : 0.f;
#pragma unroll
            for (int c = 0; c < 8; ++c) a[c] += v * bf2f(xs[t][c]);
        }
        for (int j = s + 8; j < e; j += 4) {
            int2 e2[4];
#pragma unroll
            for (int t = 0; t < 4; ++t) {
                int jj = j + t;
                e2[t] = edge[(jj < e) ? jj : (e - 1)];
            }
            u8v x2[4];
#pragma unroll
            for (int t = 0; t < 4; ++t)
                x2[t] = *(const u8v*)(src + (size_t)e2[t].x * src_stride + li * 8);
#pragma unroll
            for (int t = 0; t < 4; ++t) {
                float v = (j + t < e) ? __int_as_float(e2[t].y) : 0.f;
#pragma unroll
                for (int c = 0; c < 8; ++c) a[c] += v * bf2f(x2[t][c]);
            }
        }
    }
    u8v w;
#pragma unroll
    for (int c = 0; c < 8; ++c) w[c] = f2bf(a[c]);
    *(u8v*)(dst + (size_t)row * 32 + li * 8) = w;
}

// 64-wide: 8 lanes/row (8 ch each), 8 rows/wave, 32 rows/block; stride 64
__global__ void spmm64_kernel(const int* __restrict__ rp, const int2* __restrict__ edge,
                              const bf16* __restrict__ srcb, bf16* __restrict__ dstb) {
    const ushort* src = (const ushort*)srcb;
    ushort* dst = (ushort*)dstb;
    int tid = threadIdx.x;
    int lane = tid & 63;
    int wv = tid >> 6;
    int grp = lane >> 3;      // 0..7: row within wave
    int li = lane & 7;        // channels li*8 .. li*8+7
    int row = blockIdx.x * 32 + wv * 8 + grp;
    int s = rp[row];
    int e = (row == N_SIMP - 1) ? E_NNZ : rp[row + 1];
    int deg = e - s;
    float a[8] = {0.f, 0.f, 0.f, 0.f, 0.f, 0.f, 0.f, 0.f};
    if (deg > 0) {
        int2 ed[8];
#pragma unroll
        for (int t = 0; t < 8; ++t) {
            int j = s + t;
            ed[t] = edge[(j < e) ? j : (e - 1)];
        }
        u8v xs[8];
#pragma unroll
        for (int t = 0; t < 8; ++t)
            xs[t] = *(const u8v*)(src + (size_t)ed[t].x * 64 + li * 8);
#pragma unroll
        for (int t = 0; t < 8; ++t) {
            float v = (t < deg) ? __int_as_float(ed[t].y) : 0.f;
#pragma unroll
            for (int c = 0; c < 8; ++c) a[c] += v * bf2f(xs[t][c]);
        }
        for (int j = s + 8; j < e; j += 4) {
            int2 e2[4];
#pragma unroll
            for (int t = 0; t < 4; ++t) {
                int jj = j + t;
                e2[t] = edge[(jj < e) ? jj : (e - 1)];
            }
            u8v x2[4];
#pragma unroll
            for (int t = 0; t < 4; ++t)
                x2[t] = *(const u8v*)(src + (size_t)e2[t].x * 64 + li * 8);
#pragma unroll
            for (int t = 0; t < 4; ++t) {
                float v = (j + t < e) ? __int_as_float(e2[t].y) : 0.f;
#pragma unroll
                for (int c = 0; c < 8; ++c) a[c] += v * bf2f(x2[t][c]);
            }
        }
    }
    u8v w;
#pragma unroll
    for (int c = 0; c < 8; ++c) w[c] = f2bf(a[c]);
    *(u8v*)(dst + (size_t)row * 64 + li * 8) = w;
}

// ---------------- MFMA GEMM: z[N,64] (fp16) (=bias+ / +=) A[N, NCH*32] @ W -------
// up to 6 A-channel sources; W in FRAGMENT layout (2048 ushorts per channel),
// split into two groups (Wt1 for ch<NCH1, Wt2 rest).

template <int NCH, int NCH1, bool INIT>
__global__ __launch_bounds__(256) void mfma_gemm_kernel(
        const ushort* __restrict__ s0, int st0,
        const ushort* __restrict__ s1, int st1,
        const ushort* __restrict__ s2, int st2,
        const ushort* __restrict__ s3, int st3,
        const ushort* __restrict__ s4, int st4,
        const ushort* __restrict__ s5, int st5,
        const ushort* __restrict__ Wt1,
        const ushort* __restrict__ Wt2,
        const float* __restrict__ bias,
        f16* __restrict__ z) {
    int tid = threadIdx.x;
    int wv = tid >> 6, lane = tid & 63;
    int quad = lane >> 4, n = lane & 15;
    int rowbase = blockIdx.x * 64 + wv * 16;
    int arow = rowbase + n;  // A-operand row m = lane&15

    f4v acc0 = {0.f, 0.f, 0.f, 0.f};
    f4v acc1 = {0.f, 0.f, 0.f, 0.f};
    f4v acc2 = {0.f, 0.f, 0.f, 0.f};
    f4v acc3 = {0.f, 0.f, 0.f, 0.f};

#pragma unroll
    for (int ch = 0; ch < NCH; ++ch) {
        const ushort* sp = (ch == 0) ? s0 : (ch == 1) ? s1 : (ch == 2) ? s2
                         : (ch == 3) ? s3 : (ch == 4) ? s4 : s5;
        int st = (ch == 0) ? st0 : (ch == 1) ? st1 : (ch == 2) ? st2
               : (ch == 3) ? st3 : (ch == 4) ? st4 : st5;
        const ushort* wb = (ch < NCH1) ? (Wt1 + (size_t)ch * 2048)
                                       : (Wt2 + (size_t)(ch - NCH1) * 2048);
        s8v a = *(const s8v*)(sp + (size_t)arow * st + quad * 8);
        const ushort* wq = wb + lane * 8;
        s8v b0 = *(const s8v*)(wq + 0 * 512);
        s8v b1 = *(const s8v*)(wq + 1 * 512);
        s8v b2 = *(const s8v*)(wq + 2 * 512);
        s8v b3 = *(const s8v*)(wq + 3 * 512);
        acc0 = __builtin_amdgcn_mfma_f32_16x16x32_bf16(a, b0, acc0, 0, 0, 0);
        acc1 = __builtin_amdgcn_mfma_f32_16x16x32_bf16(a, b1, acc1, 0, 0, 0);
        acc2 = __builtin_amdgcn_mfma_f32_16x16x32_bf16(a, b2, acc2, 0, 0, 0);
        acc3 = __builtin_amdgcn_mfma_f32_16x16x32_bf16(a, b3, acc3, 0, 0, 0);
    }
    // C/D layout: col = lane&15, row = quad*4 + reg
#pragma unroll
    for (int r = 0; r < 4; ++r) {
        int orow = rowbase + quad * 4 + r;
        f16* zp = z + (size_t)orow * 64 + n;
        if (INIT) {
            zp[0]  = (f16)(bias[n]      + acc0[r]);
            zp[16] = (f16)(bias[16 + n] + acc1[r]);
            zp[32] = (f16)(bias[32 + n] + acc2[r]);
            zp[48] = (f16)(bias[48 + n] + acc3[r]);
        } else {
            zp[0]  = (f16)((float)zp[0]  + acc0[r]);
            zp[16] = (f16)((float)zp[16] + acc1[r]);
            zp[32] = (f16)((float)zp[32] + acc2[r]);
            zp[48] = (f16)((float)zp[48] + acc3[r]);
        }
    }
}

// ---------------- BN / pool / MLP (vectorized) ----------------

__global__ void bn_stats_kernel(const f16* __restrict__ z, double* __restrict__ stats) {
    __shared__ float ss[256 * 8], qq[256 * 8];
    int tid = threadIdx.x;
    const h8v* z8 = (const h8v*)z;
    const int total8 = N_SIMP * HDIM / 8;
    float fs[8] = {0, 0, 0, 0, 0, 0, 0, 0};
    float fq[8] = {0, 0, 0, 0, 0, 0, 0, 0};
    for (int i = blockIdx.x * 256 + tid; i < total8; i += (int)gridDim.x * 256) {
        h8v v = z8[i];
#pragma unroll
        for (int c = 0; c < 8; ++c) {
            float f = (float)v[c];
            fs[c] += f;
            fq[c] += f * f;
        }
    }
#pragma unroll
    for (int c = 0; c < 8; ++c) { ss[tid * 8 + c] = fs[c]; qq[tid * 8 + c] = fq[c]; }
    __syncthreads();
    if (tid < 64) {
        // channel tid: contributions from threads t with (t&7)==tid>>3, slot tid&7
        int sel = tid >> 3, slot = tid & 7;
        double a = 0.0, b = 0.0;
#pragma unroll 8
        for (int k = 0; k < 32; ++k) {
            int t = sel + (k << 3);
            a += (double)ss[t * 8 + slot];
            b += (double)qq[t * 8 + slot];
        }
        atomicAdd(&stats[tid], a);
        atomicAdd(&stats[64 + tid], b);
    }
}

// layer-0: h0bf = bf16(elu(bn(z)))
__global__ void bn_elu_bf16_kernel(const f16* __restrict__ z, const double* __restrict__ stats,
                                   const float* __restrict__ gamma, const float* __restrict__ beta,
                                   bf16* __restrict__ out) {
    __shared__ float scale_s[64], shift_s[64];
    int tid = threadIdx.x;
    if (tid < 64) {
        double mean = stats[tid] / (double)N_SIMP;
        double var = stats[64 + tid] / (double)N_SIMP - mean * mean;
        double sc = (double)gamma[tid] / sqrt(var + BN_EPS);
        scale_s[tid] = (float)sc;
        shift_s[tid] = (float)((double)beta[tid] - mean * sc);
    }
    __syncthreads();
    const h8v* z8 = (const h8v*)z;
    u8v* o8 = (u8v*)out;
    const int total8 = N_SIMP * HDIM / 8;
    int hb = (tid & 7) * 8;
    for (int i = blockIdx.x * 256 + tid; i < total8; i += (int)gridDim.x * 256) {
        h8v v = z8[i];
        u8v w;
#pragma unroll
        for (int c = 0; c < 8; ++c)
            w[c] = f2bf(elu_f((float)v[c] * scale_s[hb + c] + shift_s[hb + c]));
        o8[i] = w;
    }
}

// fused bn1 + elu + global max/mean pool: reads raw z, applies elu(bn(z)) inline.
// 8 lanes/row (h8v = 16B each), 32 rows in flight per 256-thread block.
__global__ void pool_bn_kernel(const f16* __restrict__ zbuf, const int* __restrict__ bidx,
                               const double* __restrict__ stats,
                               const float* __restrict__ gamma, const float* __restrict__ beta,
                               float* __restrict__ gbuf) {
    __shared__ float scale_s[64], shift_s[64];
    __shared__ float pmax[256 * 8], psum[256 * 8];
    int tid = threadIdx.x;
    if (tid < 64) {
        double mean = stats[tid] / (double)N_SIMP;
        double var = stats[64 + tid] / (double)N_SIMP - mean * mean;
        double sc = (double)gamma[tid] / sqrt(var + BN_EPS);
        scale_s[tid] = (float)sc;
        shift_s[tid] = (float)((double)beta[tid] - mean * sc);
    }
    __syncthreads();
    int g = blockIdx.x;
    int lo = 0, hi = N_SIMP;
    while (lo < hi) { int mid = (lo + hi) >> 1; if (bidx[mid] < g) lo = mid + 1; else hi = mid; }
    int start = lo;
    hi = N_SIMP;
    while (lo < hi) { int mid = (lo + hi) >> 1; if (bidx[mid] < g + 1) lo = mid + 1; else hi = mid; }
    int end = lo;
    int li = tid & 7;        // channel block: li*8 .. li*8+7
    int rr = tid >> 3;       // row offset 0..31
    const h8v* z8 = (const h8v*)zbuf;
    float mx[8], sm[8];
#pragma unroll
    for (int c = 0; c < 8; ++c) { mx[c] = -INFINITY; sm[c] = 0.f; }
    float sc8[8], sh8[8];
#pragma unroll
    for (int c = 0; c < 8; ++c) { sc8[c] = scale_s[li * 8 + c]; sh8[c] = shift_s[li * 8 + c]; }
    for (int i = start + rr; i < end; i += 32) {
        h8v v = z8[(size_t)i * 8 + li];
#pragma unroll
        for (int c = 0; c < 8; ++c) {
            float y = elu_f((float)v[c] * sc8[c] + sh8[c]);
            mx[c] = fmaxf(mx[c], y);
            sm[c] += y;
        }
    }
#pragma unroll
    for (int c = 0; c < 8; ++c) { pmax[tid * 8 + c] = mx[c]; psum[tid * 8 + c] = sm[c]; }
    __syncthreads();
    if (tid < 64) {
        int sel = tid >> 3, slot = tid & 7;   // li = sel, c = slot
        float m = -INFINITY, s = 0.f;
#pragma unroll 8
        for (int k = 0; k < 32; ++k) {
            int t = k * 8 + sel;
            m = fmaxf(m, pmax[t * 8 + slot]);
            s += psum[t * 8 + slot];
        }
        int cnt = end - start;
        float mean = s / fmaxf((float)cnt, 1.f);
        gbuf[g * 128 + tid] = elu_f(m);
        gbuf[g * 128 + 64 + tid] = elu_f(mean);
    }
}

__global__ void mlp_kernel(const float* __restrict__ gbuf, const float* __restrict__ W1,
                           const float* __restrict__ b1, const float* __restrict__ W2,
                           const float* __restrict__ b2, float* __restrict__ out) {
    __shared__ float gs[128];
    __shared__ float hs[64];
    int g = blockIdx.x, tid = threadIdx.x;
    gs[tid] = gbuf[g * 128 + tid];
    gs[64 + tid] = gbuf[g * 128 + 64 + tid];
    __syncthreads();
    float acc = b1[tid];
#pragma unroll
    for (int k = 0; k < 128; ++k) acc += gs[k] * W1[k * 64 + tid];
    hs[tid] = fmaxf(acc, 0.f);
    __syncthreads();
    if (tid < 8) {
        float o = b2[tid];
#pragma unroll
        for (int k = 0; k < 64; ++k) o += hs[k] * W2[k * 8 + tid];
        out[g * 8 + tid] = o;
    }
}

// ---------------- host side ----------------

extern "C" void kernel_launch(void* const* d_in, const int* in_sizes, int n_in,
                              void* d_out, int out_size, void* d_ws, size_t ws_size,
                              hipStream_t stream) {
    const float* x     = (const float*)d_in[0];
    const int*   li    = (const int*)d_in[1];
    const float* lv    = (const float*)d_in[2];
    const int*   ui    = (const int*)d_in[3];
    const float* uv    = (const float*)d_in[4];
    const int*   bidx  = (const int*)d_in[5];
    const float* l0_Wl = (const float*)d_in[6];
    const float* l0_bl = (const float*)d_in[7];
    const float* l0_Wu = (const float*)d_in[8];
    const float* l0_bu = (const float*)d_in[9];
    const float* l0_Wh = (const float*)d_in[10];
    const float* l0_bh = (const float*)d_in[11];
    const float* l1_Wl = (const float*)d_in[12];
    const float* l1_bl = (const float*)d_in[13];
    const float* l1_Wu = (const float*)d_in[14];
    const float* l1_bu = (const float*)d_in[15];
    const float* l1_Wh = (const float*)d_in[16];
    const float* l1_bh = (const float*)d_in[17];
    const float* bn0_g = (const float*)d_in[18];
    const float* bn0_b = (const float*)d_in[19];
    const float* bn1_g = (const float*)d_in[20];
    const float* bn1_b = (const float*)d_in[21];
    const float* mW1   = (const float*)d_in[22];
    const float* mb1   = (const float*)d_in[23];
    const float* mW2   = (const float*)d_in[24];
    const float* mb2   = (const float*)d_in[25];
    float* out = (float*)d_out;

    // ---- workspace layout (total ~246.8 MB <= 256 MiB) ----
    char* base = (char*)d_ws;
    f16*   z     = (f16*)base;                                    //  51,200,000
    bf16*  h0bf  = (bf16*)(base + 51200000ull);                   //  51,200,000
    bf16*  g1    = (bf16*)(base + 102400000ull);                  //  51,200,000
    bf16*  g2    = (bf16*)(base + 153600000ull);                  //  51,200,000
    int2*  edgeL = (int2*)(base + 204800000ull);                  //  19,200,000
    int2*  edgeU = (int2*)(base + 224000000ull);                  //  19,200,000
    int*   rpL   = (int*)(base + 243200000ull);                   //   1,600,032
    int*   rpU   = (int*)(base + 244800032ull);                   //   1,600,032
    double* stats = (double*)(base + 246404160ull);               //   1 KB
    float* cbias  = (float*)(base + 246405184ull);                //   256 B
    float* gbuf   = (float*)(base + 246405440ull);                //   262,144
    ushort* wt    = (ushort*)(base + 246667584ull);               //   86,016

    // CSR-build scratch aliases (regions dead during build):
    //  z region   : coarse 38.4 MB + basev 3.1 KB
    //  h0bf region: ccnt 916 KB + bofs 916 KB
    int2* coarse = (int2*)base;                                   // 38,404,096
    int*  basev  = (int*)(base + 38500000ull);                    // (NDIG+1)*4
    int*  ccnt   = (int*)(base + 51200000ull);                    // 916,504
    int*  bofsv  = (int*)(base + 52200000ull);                    // 916,504

    // layer-0 scratch: 6 slots of N*32 bf16 in g1/g2/h0bf regions
    bf16* xbf  = g1;                                 // g1 slot 0 (later cCU)
    bf16* cAL  = g1 + (size_t)N_SIMP * 32;           // g1 slot 1
    bf16* cBL  = g2;                                 // g2 slot 0
    bf16* cCL  = g2 + (size_t)N_SIMP * 32;           // g2 slot 1
    bf16* cAU  = h0bf;                               // h0 slot 0
    bf16* cBU  = h0bf + (size_t)N_SIMP * 32;         // h0 slot 1
    bf16* cCU  = g1;                                 // reuses xbf slot (xbf dead)

    // weight-fragment sub-buffers (ushort elements; 2048 ushorts per channel)
    ushort* wt_l0h = wt;            // 1 ch  (K=32)
    ushort* wt_l1h = wt + 2048;     // 2 ch  (K=64)
    ushort* wt_l0l = wt + 6144;     // 3 ch  (K=96)
    ushort* wt_l0u = wt + 12288;    // 3 ch  (K=96)
    ushort* wt_l1l = wt + 18432;    // 6 ch  (K=192)
    ushort* wt_l1u = wt + 30720;    // 6 ch  (K=192)

    const int SP32_BLOCKS = N_SIMP / 64;   // 6,250
    const int SP64_BLOCKS = N_SIMP / 32;   // 12,500
    const int MF_BLOCKS   = N_SIMP / 64;   // 6,250

    // ---- prep: weight transposes (one dispatch) + x->bf16 ----
    wtrans_all_kernel<<<168, 256, 0, stream>>>(l0_Wh, l1_Wh, l0_Wl, l0_Wu, l1_Wl, l1_Wu, wt);
    f32_to_bf16_kernel<<<N_SIMP * 32 / 4 / 256, 256, 0, stream>>>(x, xbf);

    // ---- CSR builds: in-LDS block sort + fragment-gather bucket sort ----
    p1_sort_kernel<<<P1_BLOCKS, P1_T, 0, stream>>>(li, lv, ui, uv, ccnt, bofsv, coarse);
    digit_total_kernel<<<(NDIG + 255) / 256, 256, 0, stream>>>(ccnt, basev);
    scan_base_kernel<<<1, 1024, 0, stream>>>(basev);
    p2_build_kernel<<<NDIG, P2_T, 0, stream>>>(coarse, ccnt, bofsv, basev,
                                               rpL, rpU, edgeL, edgeU);

    const ushort* xbfu = (const ushort*)xbf;
    const ushort* h0u  = (const ushort*)h0bf;
    const ushort* g1u  = (const ushort*)g1;
    const ushort* g2u  = (const ushort*)g2;

    // ---------------- layer 0 (F_IN=32 -> H=64) ----------------
    combine_bias_kernel<<<1, 64, 0, stream>>>(l0_bh, l0_bl, l0_bu, cbias);
    mfma_gemm_kernel<1, 1, true><<<MF_BLOCKS, 256, 0, stream>>>(
        xbfu, 32, nullptr, 0, nullptr, 0, nullptr, 0, nullptr, 0, nullptr, 0,
        wt_l0h, wt_l0h, cbias, z);

    // lower chain
    spmm32_kernel<<<SP32_BLOCKS, 256, 0, stream>>>(rpL, edgeL, xbf, 32, cAL);
    spmm32_kernel<<<SP32_BLOCKS, 256, 0, stream>>>(rpL, edgeL, cAL, 32, cBL);
    spmm32_kernel<<<SP32_BLOCKS, 256, 0, stream>>>(rpL, edgeL, cBL, 32, cCL);
    // upper chain (cAU spmm reads xbf before cCU overwrites that slot)
    spmm32_kernel<<<SP32_BLOCKS, 256, 0, stream>>>(rpU, edgeU, xbf, 32, cAU);
    spmm32_kernel<<<SP32_BLOCKS, 256, 0, stream>>>(rpU, edgeU, cAU, 32, cBU);
    spmm32_kernel<<<SP32_BLOCKS, 256, 0, stream>>>(rpU, edgeU, cBU, 32, cCU);
    // single accumulate-GEMM over all 6 chain outputs
    mfma_gemm_kernel<6, 3, false><<<MF_BLOCKS, 256, 0, stream>>>(
        (const ushort*)cAL, 32, (const ushort*)cBL, 32, (const ushort*)cCL, 32,
        (const ushort*)cAU, 32, (const ushort*)cBU, 32, (const ushort*)cCU, 32,
        wt_l0l, wt_l0u, nullptr, z);

    (void)hipMemsetAsync(stats, 0, 128 * sizeof(double), stream);
    bn_stats_kernel<<<1024, 256, 0, stream>>>(z, stats);
    bn_elu_bf16_kernel<<<1024, 256, 0, stream>>>(z, stats, bn0_g, bn0_b, h0bf);

    // ---------------- layer 1 (H=64 -> H=64), 64-wide chains ----------------
    combine_bias_kernel<<<1, 64, 0, stream>>>(l1_bh, l1_bl, l1_bu, cbias);

    // u1 = L h0 -> g1 ; u2 = L u1 -> g2
    spmm64_kernel<<<SP64_BLOCKS, 256, 0, stream>>>(rpL, edgeL, h0bf, g1);
    spmm64_kernel<<<SP64_BLOCKS, 256, 0, stream>>>(rpL, edgeL, g1, g2);
    // gemm A (INIT): h0 (wt_l1h ch 0-1), u1+u2 (wt_l1l ch 0-3), + bias
    mfma_gemm_kernel<6, 2, true><<<MF_BLOCKS, 256, 0, stream>>>(
        h0u, 64, h0u + 32, 64, g1u, 64, g1u + 32, 64, g2u, 64, g2u + 32, 64,
        wt_l1h, wt_l1l, cbias, z);
    // u3 = L u2 -> g1 ; v1 = U h0 -> g2
    spmm64_kernel<<<SP64_BLOCKS, 256, 0, stream>>>(rpL, edgeL, g2, g1);
    spmm64_kernel<<<SP64_BLOCKS, 256, 0, stream>>>(rpU, edgeU, h0bf, g2);
    // gemm B: u3 (wt_l1l ch 4-5), v1 (wt_l1u ch 0-1)
    mfma_gemm_kernel<4, 2, false><<<MF_BLOCKS, 256, 0, stream>>>(
        g1u, 64, g1u + 32, 64, g2u, 64, g2u + 32, 64, nullptr, 0, nullptr, 0,
        wt_l1l + 4 * 2048, wt_l1u, nullptr, z);
    // v2 = U v1 -> g1 ; v3 = U v2 -> g2
    spmm64_kernel<<<SP64_BLOCKS, 256, 0, stream>>>(rpU, edgeU, g2, g1);
    spmm64_kernel<<<SP64_BLOCKS, 256, 0, stream>>>(rpU, edgeU, g1, g2);
    // gemm C: v2+v3 (wt_l1u ch 2-5)
    mfma_gemm_kernel<4, 4, false><<<MF_BLOCKS, 256, 0, stream>>>(
        g1u, 64, g1u + 32, 64, g2u, 64, g2u + 32, 64, nullptr, 0, nullptr, 0,
        wt_l1u + 2 * 2048, wt_l1u + 2 * 2048, nullptr, z);

    (void)hipMemsetAsync(stats, 0, 128 * sizeof(double), stream);
    bn_stats_kernel<<<1024, 256, 0, stream>>>(z, stats);

    // ---------------- fused bn1+elu+pool, then MLP ----------------
    pool_bn_kernel<<<G_NUM, 256, 0, stream>>>(z, bidx, stats, bn1_g, bn1_b, gbuf);
    mlp_kernel<<<G_NUM, 64, 0, stream>>>(gbuf, mW1, mb1, mW2, mb2, out);
}